// Round 1
// baseline (11261.243 us; speedup 1.0000x reference)
//
#include <hip/hip_runtime.h>
#include <cstddef>
#include <cstdint>

// Problem constants
#define BB   512
#define TT   128
#define DD   512
#define HH   4
#define HDIM 128
#define FFD  2048
#define NROWS (BB * TT)                 // 65536 rows
#define SLOT ((size_t)NROWS * DD)       // 33554432 floats = 128 MiB

// ---------------------------------------------------------------------------
// Workspace plan (4 slots of 128 MiB in d_ws; x1 lives in d_out):
//  W0: q -> o_out -> local_hist -> acc/states
//  W1: k -> attn_out -> ema/global_sum -> seq_guidance -> ffn_out
//  W2: v -> gate_acc -> deltas -> ffn_in
//  W3: scores -> delta_acc -> h-chunk (16384 x 2048)
//  d_out[0..SLOT): x1 (until final in-place LN2)   d_out[SLOT..): rope tables
//  (consumed early) then final_state.
// ---------------------------------------------------------------------------

// ------------------------- SGEMM (fp32, 128x128x8) -------------------------
__global__ __launch_bounds__(256)
void sgemm_nn(const float* __restrict__ A, const float* __restrict__ B,
              const float* __restrict__ bias, float* __restrict__ C,
              int N, int K, int M, int accumulate)
{
    __shared__ float As[8][128];
    __shared__ float Bs[8][128];
    const int tid  = threadIdx.x;
    const int row0 = blockIdx.x * 128;
    const int col0 = blockIdx.y * 128;
    const int tx = tid & 15;     // 0..15 -> cols tx*8..
    const int ty = tid >> 4;     // 0..15 -> rows ty*8..

    float acc[8][8];
#pragma unroll
    for (int i = 0; i < 8; ++i)
#pragma unroll
        for (int j = 0; j < 8; ++j) acc[i][j] = 0.f;

    const int a_row = tid >> 1;          // 0..127
    const int a_col = (tid & 1) << 2;    // 0 or 4
    const int b_row = tid >> 5;          // 0..7
    const int b_col = (tid & 31) << 2;   // 0..124

    const float* Ap = A + (size_t)(row0 + a_row) * K + a_col;
    const float* Bp = B + (size_t)b_row * M + col0 + b_col;

    for (int k0 = 0; k0 < K; k0 += 8) {
        float4 av = *reinterpret_cast<const float4*>(Ap + k0);
        As[a_col + 0][a_row] = av.x;
        As[a_col + 1][a_row] = av.y;
        As[a_col + 2][a_row] = av.z;
        As[a_col + 3][a_row] = av.w;
        *reinterpret_cast<float4*>(&Bs[b_row][b_col]) =
            *reinterpret_cast<const float4*>(Bp + (size_t)k0 * M);
        __syncthreads();
#pragma unroll
        for (int kk = 0; kk < 8; ++kk) {
            float4 a0 = *reinterpret_cast<const float4*>(&As[kk][ty * 8]);
            float4 a1 = *reinterpret_cast<const float4*>(&As[kk][ty * 8 + 4]);
            float4 b0 = *reinterpret_cast<const float4*>(&Bs[kk][tx * 8]);
            float4 b1 = *reinterpret_cast<const float4*>(&Bs[kk][tx * 8 + 4]);
            float a[8] = {a0.x, a0.y, a0.z, a0.w, a1.x, a1.y, a1.z, a1.w};
            float b[8] = {b0.x, b0.y, b0.z, b0.w, b1.x, b1.y, b1.z, b1.w};
#pragma unroll
            for (int i = 0; i < 8; ++i)
#pragma unroll
                for (int j = 0; j < 8; ++j)
                    acc[i][j] = fmaf(a[i], b[j], acc[i][j]);
        }
        __syncthreads();
    }

#pragma unroll
    for (int i = 0; i < 8; ++i) {
        float* Cp = C + (size_t)(row0 + ty * 8 + i) * M + col0 + tx * 8;
#pragma unroll
        for (int j = 0; j < 8; ++j) {
            float v = acc[i][j];
            if (bias)       v += bias[col0 + tx * 8 + j];
            if (accumulate) v += Cp[j];
            Cp[j] = v;
        }
    }
}

// ------------------------- RoPE -------------------------
__global__ void rope_table_kernel(float* __restrict__ tabc, float* __restrict__ tabs)
{
    int idx = blockIdx.x * blockDim.x + threadIdx.x;
    if (idx >= TT * 64) return;
    int t = idx >> 6, j = idx & 63;
    // inv_freq = 10000^(-j/64)
    float invf = expf(-(float)j * (9.210340371976184f / 64.f));
    float ang  = (float)t * invf;
    tabc[idx] = cosf(ang);
    tabs[idx] = sinf(ang);
}

__global__ void rope_apply_kernel(float* __restrict__ p,
                                  const float* __restrict__ tabc,
                                  const float* __restrict__ tabs)
{
    int idx = blockIdx.x * blockDim.x + threadIdx.x;   // B*T*H*64 = 16777216
    if (idx >= BB * TT * HH * 64) return;
    int j = idx & 63;
    int h = (idx >> 6) & (HH - 1);
    int t = (idx >> 8) & (TT - 1);
    int b = idx >> 15;
    float c  = tabc[t * 64 + j];
    float sn = tabs[t * 64 + j];
    float* q = p + ((size_t)(b * TT + t)) * DD + h * HDIM + j;
    float x1 = q[0], x2 = q[64];
    q[0]  = x1 * c - x2 * sn;
    q[64] = x2 * c + x1 * sn;
}

// ------------------------- Attention -------------------------
__global__ __launch_bounds__(128)
void attn_scores_kernel(const float* __restrict__ q, const float* __restrict__ k,
                        float* __restrict__ p)
{
    const int t = blockIdx.x, h = blockIdx.y, b = blockIdx.z;
    const int s = threadIdx.x;
    __shared__ float qrow[HDIM];
    __shared__ float redm[2], reds[2];
    qrow[s] = q[((size_t)(b * TT + t)) * DD + h * HDIM + s];
    __syncthreads();

    float score = -1e30f;
    if (s <= t) {
        const float4* k4 = reinterpret_cast<const float4*>(
            k + ((size_t)(b * TT + s)) * DD + h * HDIM);
        float acc = 0.f;
#pragma unroll
        for (int dd = 0; dd < HDIM / 4; ++dd) {
            float4 kv = k4[dd];
            acc += qrow[4 * dd] * kv.x + qrow[4 * dd + 1] * kv.y +
                   qrow[4 * dd + 2] * kv.z + qrow[4 * dd + 3] * kv.w;
        }
        score = acc * 0.08838834764831845f;   // 1/sqrt(128)
    }
    float m = score;
#pragma unroll
    for (int off = 1; off < 64; off <<= 1) m = fmaxf(m, __shfl_xor(m, off));
    if ((s & 63) == 0) redm[s >> 6] = m;
    __syncthreads();
    m = fmaxf(redm[0], redm[1]);

    float e = (s <= t) ? expf(score - m) : 0.f;
    float sum = e;
#pragma unroll
    for (int off = 1; off < 64; off <<= 1) sum += __shfl_xor(sum, off);
    if ((s & 63) == 0) reds[s >> 6] = sum;
    __syncthreads();
    sum = reds[0] + reds[1];

    p[(((size_t)(b * HH + h)) * TT + t) * TT + s] = e / sum;
}

__global__ __launch_bounds__(128)
void attn_pv_kernel(const float* __restrict__ p, const float* __restrict__ v,
                    float* __restrict__ o)
{
    const int t = blockIdx.x, h = blockIdx.y, b = blockIdx.z;
    const int d = threadIdx.x;
    __shared__ float prow[TT];
    prow[d] = p[(((size_t)(b * HH + h)) * TT + t) * TT + d];
    __syncthreads();
    const float* vp = v + (size_t)(b * TT) * DD + h * HDIM + d;
    float acc = 0.f;
    for (int s = 0; s <= t; ++s) acc += prow[s] * vp[(size_t)s * DD];
    o[((size_t)(b * TT + t)) * DD + h * HDIM + d] = acc;
}

// ------------------------- LayerNorm (D=512, block=256, 1 row/block) -------
// b_mode: 0 = none, 1 = per-row add (badd[row*D+i]), 2 = broadcast (badd[(row/T)*D+i])
__global__ __launch_bounds__(256)
void ln_kernel(const float* __restrict__ a, size_t a_stride,
               const float* __restrict__ badd, int b_mode,
               const float* __restrict__ g, const float* __restrict__ bb,
               float* __restrict__ out, size_t out_stride)
{
    const int row = blockIdx.x;
    const int tid = threadIdx.x;
    const float* ap = a + (size_t)row * a_stride;
    float v0 = ap[tid];
    float v1 = ap[tid + 256];
    if (b_mode == 1) {
        const float* bp = badd + (size_t)row * DD;
        v0 += bp[tid]; v1 += bp[tid + 256];
    } else if (b_mode == 2) {
        const float* bp = badd + (size_t)(row / TT) * DD;
        v0 += bp[tid]; v1 += bp[tid + 256];
    }
    float s  = v0 + v1;
    float ss = v0 * v0 + v1 * v1;
#pragma unroll
    for (int off = 1; off < 64; off <<= 1) {
        s  += __shfl_xor(s, off);
        ss += __shfl_xor(ss, off);
    }
    __shared__ float sm1[4], sm2[4];
    const int wid = tid >> 6;
    if ((tid & 63) == 0) { sm1[wid] = s; sm2[wid] = ss; }
    __syncthreads();
    s  = sm1[0] + sm1[1] + sm1[2] + sm1[3];
    ss = sm2[0] + sm2[1] + sm2[2] + sm2[3];
    const float mu  = s * (1.f / DD);
    const float var = ss * (1.f / DD) - mu * mu;
    const float r   = rsqrtf(var + 1e-5f);
    float* op = out + (size_t)row * out_stride;
    op[tid]       = (v0 - mu) * r * g[tid]       + bb[tid];
    op[tid + 256] = (v1 - mu) * r * g[tid + 256] + bb[tid + 256];
}

// ------------------------- Depthwise convs / scans -------------------------
__global__ void local_conv_kernel(const float* __restrict__ x, const float* __restrict__ w,
                                  const float* __restrict__ b, float* __restrict__ y,
                                  size_t n)
{
    size_t idx = (size_t)blockIdx.x * blockDim.x + threadIdx.x;
    if (idx >= n) return;
    int d = idx & (DD - 1);
    int t = (int)(idx >> 9) & (TT - 1);
    float acc = b[d];
#pragma unroll
    for (int kk = 0; kk < 4; ++kk) {
        int ts = t - 3 + kk;
        if (ts >= 0) acc += w[d * 4 + kk] * x[idx - (size_t)(3 - kk) * DD];
    }
    y[idx] = acc;
}

__global__ void ema_scan_kernel(const float* __restrict__ x, float* __restrict__ y)
{
    int idx = blockIdx.x * blockDim.x + threadIdx.x;   // B*D
    if (idx >= BB * DD) return;
    int b = idx >> 9, d = idx & (DD - 1);
    const float* xp = x + (size_t)b * TT * DD + d;
    float* yp = y + (size_t)b * TT * DD + d;
    float acc = 0.f;
    for (int t = 0; t < TT; ++t) {
        acc = 0.9f * acc + 0.1f * xp[(size_t)t * DD];
        yp[(size_t)t * DD] = acc;
    }
}

__global__ void cumsum_kernel(const float* __restrict__ x, float* __restrict__ y)
{
    int idx = blockIdx.x * blockDim.x + threadIdx.x;   // B*D
    if (idx >= BB * DD) return;
    int b = idx >> 9, d = idx & (DD - 1);
    const float* xp = x + (size_t)b * TT * DD + d;
    float* yp = y + (size_t)b * TT * DD + d;
    float acc = 0.f;
    for (int t = 0; t < TT; ++t) {
        acc += xp[(size_t)t * DD];
        yp[(size_t)t * DD] = acc * 0.25f;   // STEP
    }
}

// ------------------------- Elementwise -------------------------
__global__ void deltas_act_kernel(float* __restrict__ gate, const float* __restrict__ delta,
                                  size_t n)
{
    size_t idx = (size_t)blockIdx.x * blockDim.x + threadIdx.x;
    if (idx >= n) return;
    float gv = gate[idx];
    float dv = delta[idx];
    gate[idx] = (1.f / (1.f + expf(-gv))) * tanhf(dv);
}

__global__ void ffn_in_kernel(const float* __restrict__ x1, const float* __restrict__ sg,
                              float* __restrict__ y, size_t n)
{
    size_t idx = (size_t)blockIdx.x * blockDim.x + threadIdx.x;
    if (idx >= n) return;
    y[idx] = x1[idx] + 0.3f * sg[idx];
}

__global__ void gelu_kernel(float* __restrict__ x, size_t n)
{
    size_t idx = (size_t)blockIdx.x * blockDim.x + threadIdx.x;
    if (idx >= n) return;
    float v = x[idx];
    x[idx] = 0.5f * v * (1.f + erff(v * 0.70710678118654752f));
}

// ---------------------------------------------------------------------------
extern "C" void kernel_launch(void* const* d_in, const int* in_sizes, int n_in,
                              void* d_out, int out_size, void* d_ws, size_t ws_size,
                              hipStream_t stream)
{
    const float* x       = (const float*)d_in[0];
    const float* seqst   = (const float*)d_in[1];
    const float* q_w     = (const float*)d_in[2];
    const float* q_b     = (const float*)d_in[3];
    const float* k_w     = (const float*)d_in[4];
    const float* k_b     = (const float*)d_in[5];
    const float* v_w     = (const float*)d_in[6];
    const float* v_b     = (const float*)d_in[7];
    const float* o_w     = (const float*)d_in[8];
    const float* o_b     = (const float*)d_in[9];
    const float* local_w = (const float*)d_in[10];
    const float* local_b = (const float*)d_in[11];
    const float* delta_w = (const float*)d_in[12];
    const float* delta_b = (const float*)d_in[13];
    const float* gate_w  = (const float*)d_in[14];
    const float* gate_b  = (const float*)d_in[15];
    const float* dn_g    = (const float*)d_in[16];
    const float* dn_b    = (const float*)d_in[17];
    const float* ln1_g   = (const float*)d_in[18];
    const float* ln1_b   = (const float*)d_in[19];
    const float* ln2_g   = (const float*)d_in[20];
    const float* ln2_b   = (const float*)d_in[21];
    const float* ln3_g   = (const float*)d_in[22];
    const float* ln3_b   = (const float*)d_in[23];
    const float* ln4_g   = (const float*)d_in[24];
    const float* ln4_b   = (const float*)d_in[25];
    const float* seq_w   = (const float*)d_in[26];
    const float* seq_b   = (const float*)d_in[27];
    const float* ffn_w1  = (const float*)d_in[28];
    const float* ffn_b1  = (const float*)d_in[29];
    const float* ffn_w2  = (const float*)d_in[30];
    const float* ffn_b2  = (const float*)d_in[31];
    const float* ema_w   = (const float*)d_in[32];  // replaced by exact recurrence
    (void)ema_w; (void)in_sizes; (void)n_in; (void)out_size; (void)ws_size;

    float* out = (float*)d_out;
    float* W0 = (float*)d_ws;
    float* W1 = W0 + SLOT;
    float* W2 = W1 + SLOT;
    float* W3 = W2 + SLOT;

    float* X1     = out;          // x1 lives in d_out until final in-place LN
    float* tabc   = out + SLOT;   // rope tables in final_state tail (consumed early)
    float* tabs   = tabc + TT * 64;
    float* fstate = out + SLOT;   // final_state (written after tables are dead)

    auto gemm = [&](const float* A, const float* Bw, const float* bias, float* C,
                    int N, int K, int M, int accum) {
        dim3 g(N / 128, M / 128);
        sgemm_nn<<<g, 256, 0, stream>>>(A, Bw, bias, C, N, K, M, accum);
    };

    const size_t NE = (size_t)NROWS * DD;             // 33554432
    const int EB = 256;
    const int NBLK = (int)((NE + EB - 1) / EB);

    // 1. RoPE tables
    rope_table_kernel<<<(TT * 64 + 255) / 256, 256, 0, stream>>>(tabc, tabs);

    // 2-4. q,k,v projections
    gemm(x, q_w, q_b, W0, NROWS, DD, DD, 0);
    gemm(x, k_w, k_b, W1, NROWS, DD, DD, 0);
    gemm(x, v_w, v_b, W2, NROWS, DD, DD, 0);

    // 5. RoPE on q,k
    {
        int n = BB * TT * HH * 64;
        rope_apply_kernel<<<(n + 255) / 256, 256, 0, stream>>>(W0, tabc, tabs);
        rope_apply_kernel<<<(n + 255) / 256, 256, 0, stream>>>(W1, tabc, tabs);
    }

    // 6. scores+softmax -> W3 ; 7. PV -> W1 (k dead)
    {
        dim3 g(TT, HH, BB);
        attn_scores_kernel<<<g, 128, 0, stream>>>(W0, W1, W3);
        attn_pv_kernel<<<g, 128, 0, stream>>>(W3, W2, W1);
    }

    // 8. o-proj: W1 @ o_w -> W0 (q dead)
    gemm(W1, o_w, o_b, W0, NROWS, DD, DD, 0);

    // 9. x1 = LN1(x + o_out) -> X1 (d_out)
    ln_kernel<<<NROWS, 256, 0, stream>>>(x, DD, W0, 1, ln1_g, ln1_b, X1, DD);

    // 10. local conv -> W0 ; 11. EMA -> W1
    local_conv_kernel<<<NBLK, EB, 0, stream>>>(X1, local_w, local_b, W0, NE);
    ema_scan_kernel<<<(BB * DD + 255) / 256, 256, 0, stream>>>(X1, W1);

    // 12. gate_acc -> W2 (v dead): x1@gw0 + local@gw1 + glob@gw2 + gate_b
    gemm(X1, gate_w,                 gate_b, W2, NROWS, DD, DD, 0);
    gemm(W0, gate_w + (size_t)DD * DD,  nullptr, W2, NROWS, DD, DD, 1);
    gemm(W1, gate_w + (size_t)2 * DD * DD, nullptr, W2, NROWS, DD, DD, 1);

    // 13. delta_acc -> W3 (scores dead)
    gemm(X1, delta_w,                 delta_b, W3, NROWS, DD, DD, 0);
    gemm(W0, delta_w + (size_t)DD * DD,  nullptr, W3, NROWS, DD, DD, 1);
    gemm(W1, delta_w + (size_t)2 * DD * DD, nullptr, W3, NROWS, DD, DD, 1);

    // 14. deltas = sigmoid(gate)*tanh(delta) -> W2 (in place), then LN(dn) in place
    deltas_act_kernel<<<NBLK, EB, 0, stream>>>(W2, W3, NE);
    ln_kernel<<<NROWS, 256, 0, stream>>>(W2, DD, nullptr, 0, dn_g, dn_b, W2, DD);

    // 16. acc = cumsum * STEP -> W0 (local dead) ; states = LN3(seq + acc) in place
    cumsum_kernel<<<(BB * DD + 255) / 256, 256, 0, stream>>>(W2, W0);
    ln_kernel<<<NROWS, 256, 0, stream>>>(W0, DD, seqst, 2, ln3_g, ln3_b, W0, DD);

    // 18. final_state = LN4(states[:, -1, :]) -> out tail
    ln_kernel<<<BB, 256, 0, stream>>>(W0 + (size_t)(TT - 1) * DD, (size_t)TT * DD,
                                      nullptr, 0, ln4_g, ln4_b, fstate, DD);

    // 19. seq_guidance = states @ seq_w + seq_b -> W1 (ema dead)
    gemm(W0, seq_w, seq_b, W1, NROWS, DD, DD, 0);

    // 20. ffn_in = x1 + 0.3*sg -> W2 (deltas dead)
    ffn_in_kernel<<<NBLK, EB, 0, stream>>>(X1, W1, W2, NE);

    // 21. FFN in 4 row-chunks of 16384 (h chunk = 128 MiB in W3)
    {
        const int CH = 16384;
        const size_t HN = (size_t)CH * FFD;
        const int HBLK = (int)((HN + EB - 1) / EB);
        for (int c = 0; c < 4; ++c) {
            const float* Ain = W2 + (size_t)c * CH * DD;
            float* Cout = W1 + (size_t)c * CH * DD;   // sg consumed
            gemm(Ain, ffn_w1, ffn_b1, W3, CH, DD, FFD, 0);
            gelu_kernel<<<HBLK, EB, 0, stream>>>(W3, HN);
            gemm(W3, ffn_w2, ffn_b2, Cout, CH, FFD, DD, 0);
        }
    }

    // 22. out = LN2(x1 + ffn_out) -> d_out (in place over X1)
    ln_kernel<<<NROWS, 256, 0, stream>>>(X1, DD, W1, 1, ln2_g, ln2_b, out, DD);
}

// Round 2
// 9374.667 us; speedup vs baseline: 1.2012x; 1.2012x over previous
//
#include <hip/hip_runtime.h>
#include <cstddef>
#include <cstdint>

// Problem constants
#define BB   512
#define TT   128
#define DD   512
#define HH   4
#define HDIM 128
#define FFD  2048
#define NROWS (BB * TT)                 // 65536 rows
#define SLOT ((size_t)NROWS * DD)       // 33554432 floats = 128 MiB

// ---------------------------------------------------------------------------
// Workspace plan (4 slots of 128 MiB in d_ws; x1 lives in d_out):
//  W0: q -> o_out -> local_hist -> acc/states
//  W1: k -> attn_out(in-place over k) -> ema -> seq_guidance -> ffn_out
//  W2: v -> gate_acc -> deltas -> ffn_in
//  W3: scores(dead) -> delta_acc -> h-chunk
// ---------------------------------------------------------------------------

// ------------------------- SGEMM (fp32, 128x128x8) -------------------------
__global__ __launch_bounds__(256)
void sgemm_nn(const float* __restrict__ A, const float* __restrict__ B,
              const float* __restrict__ bias, float* __restrict__ C,
              int N, int K, int M, int accumulate)
{
    __shared__ float As[8][128];
    __shared__ float Bs[8][128];
    const int tid  = threadIdx.x;
    const int row0 = blockIdx.x * 128;
    const int col0 = blockIdx.y * 128;
    const int tx = tid & 15;     // 0..15 -> cols tx*8..
    const int ty = tid >> 4;     // 0..15 -> rows ty*8..

    float acc[8][8];
#pragma unroll
    for (int i = 0; i < 8; ++i)
#pragma unroll
        for (int j = 0; j < 8; ++j) acc[i][j] = 0.f;

    const int a_row = tid >> 1;          // 0..127
    const int a_col = (tid & 1) << 2;    // 0 or 4
    const int b_row = tid >> 5;          // 0..7
    const int b_col = (tid & 31) << 2;   // 0..124

    const float* Ap = A + (size_t)(row0 + a_row) * K + a_col;
    const float* Bp = B + (size_t)b_row * M + col0 + b_col;

    for (int k0 = 0; k0 < K; k0 += 8) {
        float4 av = *reinterpret_cast<const float4*>(Ap + k0);
        As[a_col + 0][a_row] = av.x;
        As[a_col + 1][a_row] = av.y;
        As[a_col + 2][a_row] = av.z;
        As[a_col + 3][a_row] = av.w;
        *reinterpret_cast<float4*>(&Bs[b_row][b_col]) =
            *reinterpret_cast<const float4*>(Bp + (size_t)k0 * M);
        __syncthreads();
#pragma unroll
        for (int kk = 0; kk < 8; ++kk) {
            float4 a0 = *reinterpret_cast<const float4*>(&As[kk][ty * 8]);
            float4 a1 = *reinterpret_cast<const float4*>(&As[kk][ty * 8 + 4]);
            float4 b0 = *reinterpret_cast<const float4*>(&Bs[kk][tx * 8]);
            float4 b1 = *reinterpret_cast<const float4*>(&Bs[kk][tx * 8 + 4]);
            float a[8] = {a0.x, a0.y, a0.z, a0.w, a1.x, a1.y, a1.z, a1.w};
            float b[8] = {b0.x, b0.y, b0.z, b0.w, b1.x, b1.y, b1.z, b1.w};
#pragma unroll
            for (int i = 0; i < 8; ++i)
#pragma unroll
                for (int j = 0; j < 8; ++j)
                    acc[i][j] = fmaf(a[i], b[j], acc[i][j]);
        }
        __syncthreads();
    }

#pragma unroll
    for (int i = 0; i < 8; ++i) {
        float* Cp = C + (size_t)(row0 + ty * 8 + i) * M + col0 + tx * 8;
#pragma unroll
        for (int j = 0; j < 8; ++j) {
            float v = acc[i][j];
            if (bias)       v += bias[col0 + tx * 8 + j];
            if (accumulate) v += Cp[j];
            Cp[j] = v;
        }
    }
}

// ------------------------- RoPE -------------------------
__global__ void rope_table_kernel(float* __restrict__ tabc, float* __restrict__ tabs)
{
    int idx = blockIdx.x * blockDim.x + threadIdx.x;
    if (idx >= TT * 64) return;
    int t = idx >> 6, j = idx & 63;
    float invf = expf(-(float)j * (9.210340371976184f / 64.f));
    float ang  = (float)t * invf;
    tabc[idx] = cosf(ang);
    tabs[idx] = sinf(ang);
}

__global__ void rope_apply_kernel(float* __restrict__ p,
                                  const float* __restrict__ tabc,
                                  const float* __restrict__ tabs)
{
    int idx = blockIdx.x * blockDim.x + threadIdx.x;   // B*T*H*64
    if (idx >= BB * TT * HH * 64) return;
    int j = idx & 63;
    int h = (idx >> 6) & (HH - 1);
    int t = (idx >> 8) & (TT - 1);
    int b = idx >> 15;
    float c  = tabc[t * 64 + j];
    float sn = tabs[t * 64 + j];
    float* q = p + ((size_t)(b * TT + t)) * DD + h * HDIM + j;
    float x1 = q[0], x2 = q[64];
    q[0]  = x1 * c - x2 * sn;
    q[64] = x2 * c + x1 * sn;
}

// ------------------------- Fused attention: one block per (b,h) ------------
// Q,K staged transposed in LDS ([d][row]); softmax per-row via 16-lane
// shfl_xor (tx lanes are consecutive); V reuses K buffer, P reuses Q buffer.
// O written in-place over k's global slice (block-exclusive region).
__global__ __launch_bounds__(256)
void attn_fused_kernel(const float* __restrict__ q, const float* __restrict__ k,
                       const float* __restrict__ v, float* __restrict__ o)
{
    __shared__ float Qs[128][128];   // Q^T [d][row]  -> later P [s][row]
    __shared__ float Ks[128][128];   // K^T [d][col]  -> later V [s][dc]
    const int h = blockIdx.x, b = blockIdx.y;
    const int tid = threadIdx.x;
    const size_t base = ((size_t)b * TT) * DD + (size_t)h * HDIM;

    // ---- load Q,K transposed (row = tid>>1: LDS writes conflict-free) ----
    {
        const int row  = tid >> 1;
        const int half = tid & 1;
        const float* qp = q + base + (size_t)row * DD;
        const float* kp = k + base + (size_t)row * DD;
#pragma unroll
        for (int m = 0; m < 16; ++m) {
            const int qq = 2 * m + half;            // quad 0..31
            float4 qv = *reinterpret_cast<const float4*>(qp + qq * 4);
            float4 kv = *reinterpret_cast<const float4*>(kp + qq * 4);
            Qs[qq * 4 + 0][row] = qv.x; Qs[qq * 4 + 1][row] = qv.y;
            Qs[qq * 4 + 2][row] = qv.z; Qs[qq * 4 + 3][row] = qv.w;
            Ks[qq * 4 + 0][row] = kv.x; Ks[qq * 4 + 1][row] = kv.y;
            Ks[qq * 4 + 2][row] = kv.z; Ks[qq * 4 + 3][row] = kv.w;
        }
    }
    __syncthreads();

    const int tx = tid & 15;     // col group (16 consecutive lanes per ty)
    const int ty = tid >> 4;     // row group

    // ---- S = Q K^T ----
    float acc[8][8];
#pragma unroll
    for (int i = 0; i < 8; ++i)
#pragma unroll
        for (int j = 0; j < 8; ++j) acc[i][j] = 0.f;

    for (int d = 0; d < 128; ++d) {
        float4 a0 = *reinterpret_cast<const float4*>(&Qs[d][8 * ty]);
        float4 a1 = *reinterpret_cast<const float4*>(&Qs[d][8 * ty + 4]);
        float4 b0 = *reinterpret_cast<const float4*>(&Ks[d][8 * tx]);
        float4 b1 = *reinterpret_cast<const float4*>(&Ks[d][8 * tx + 4]);
        float a[8] = {a0.x, a0.y, a0.z, a0.w, a1.x, a1.y, a1.z, a1.w};
        float bb2[8] = {b0.x, b0.y, b0.z, b0.w, b1.x, b1.y, b1.z, b1.w};
#pragma unroll
        for (int i = 0; i < 8; ++i)
#pragma unroll
            for (int j = 0; j < 8; ++j)
                acc[i][j] = fmaf(a[i], bb2[j], acc[i][j]);
    }
    __syncthreads();   // all Qs/Ks reads done; safe to overwrite below

    // ---- load V into Ks buffer (coalesced; issued early to hide latency) --
    {
        const int qi = tid & 31, rg = tid >> 5;
        const float* vp = v + base;
#pragma unroll
        for (int it = 0; it < 16; ++it) {
            const int row = it * 8 + rg;
            float4 vv = *reinterpret_cast<const float4*>(vp + (size_t)row * DD + qi * 4);
            *reinterpret_cast<float4*>(&Ks[row][qi * 4]) = vv;
        }
    }

    // ---- softmax (mask + scale; row reduce over 16 consecutive lanes) ----
    const float SCALE = 0.08838834764831845f;   // 1/sqrt(128)
    float pmax[8];
#pragma unroll
    for (int i = 0; i < 8; ++i) {
        const int r = 8 * ty + i;
        float m = -3.0e38f;
#pragma unroll
        for (int j = 0; j < 8; ++j) {
            const int c = 8 * tx + j;
            acc[i][j] = (c <= r) ? acc[i][j] * SCALE : -3.0e38f;
            m = fmaxf(m, acc[i][j]);
        }
        pmax[i] = m;
    }
#pragma unroll
    for (int off = 1; off < 16; off <<= 1)
#pragma unroll
        for (int i = 0; i < 8; ++i)
            pmax[i] = fmaxf(pmax[i], __shfl_xor(pmax[i], off));

    float psum[8];
#pragma unroll
    for (int i = 0; i < 8; ++i) {
        float s = 0.f;
#pragma unroll
        for (int j = 0; j < 8; ++j) {
            float p = expf(acc[i][j] - pmax[i]);   // masked -> exp(-huge)=0
            acc[i][j] = p;
            s += p;
        }
        psum[i] = s;
    }
#pragma unroll
    for (int off = 1; off < 16; off <<= 1)
#pragma unroll
        for (int i = 0; i < 8; ++i)
            psum[i] += __shfl_xor(psum[i], off);

    // ---- write normalized P into Qs buffer as P[s][row] ----
#pragma unroll
    for (int i = 0; i < 8; ++i) {
        const float inv = 1.0f / psum[i];
#pragma unroll
        for (int j = 0; j < 8; ++j)
            Qs[8 * tx + j][8 * ty + i] = acc[i][j] * inv;
    }
    __syncthreads();   // P and V staged

    // ---- O = P V ----
#pragma unroll
    for (int i = 0; i < 8; ++i)
#pragma unroll
        for (int j = 0; j < 8; ++j) acc[i][j] = 0.f;

    for (int s = 0; s < 128; ++s) {
        float4 a0 = *reinterpret_cast<const float4*>(&Qs[s][8 * ty]);
        float4 a1 = *reinterpret_cast<const float4*>(&Qs[s][8 * ty + 4]);
        float4 b0 = *reinterpret_cast<const float4*>(&Ks[s][8 * tx]);
        float4 b1 = *reinterpret_cast<const float4*>(&Ks[s][8 * tx + 4]);
        float a[8] = {a0.x, a0.y, a0.z, a0.w, a1.x, a1.y, a1.z, a1.w};
        float bb2[8] = {b0.x, b0.y, b0.z, b0.w, b1.x, b1.y, b1.z, b1.w};
#pragma unroll
        for (int i = 0; i < 8; ++i)
#pragma unroll
            for (int j = 0; j < 8; ++j)
                acc[i][j] = fmaf(a[i], bb2[j], acc[i][j]);
    }

#pragma unroll
    for (int i = 0; i < 8; ++i) {
        float* op = o + base + (size_t)(8 * ty + i) * DD + 8 * tx;
        *reinterpret_cast<float4*>(op)     = make_float4(acc[i][0], acc[i][1], acc[i][2], acc[i][3]);
        *reinterpret_cast<float4*>(op + 4) = make_float4(acc[i][4], acc[i][5], acc[i][6], acc[i][7]);
    }
}

// ------------------------- LayerNorm (D=512, block=256, 1 row/block) -------
__global__ __launch_bounds__(256)
void ln_kernel(const float* __restrict__ a, size_t a_stride,
               const float* __restrict__ badd, int b_mode,
               const float* __restrict__ g, const float* __restrict__ bb,
               float* __restrict__ out, size_t out_stride)
{
    const int row = blockIdx.x;
    const int tid = threadIdx.x;
    const float* ap = a + (size_t)row * a_stride;
    float v0 = ap[tid];
    float v1 = ap[tid + 256];
    if (b_mode == 1) {
        const float* bp = badd + (size_t)row * DD;
        v0 += bp[tid]; v1 += bp[tid + 256];
    } else if (b_mode == 2) {
        const float* bp = badd + (size_t)(row / TT) * DD;
        v0 += bp[tid]; v1 += bp[tid + 256];
    }
    float s  = v0 + v1;
    float ss = v0 * v0 + v1 * v1;
#pragma unroll
    for (int off = 1; off < 64; off <<= 1) {
        s  += __shfl_xor(s, off);
        ss += __shfl_xor(ss, off);
    }
    __shared__ float sm1[4], sm2[4];
    const int wid = tid >> 6;
    if ((tid & 63) == 0) { sm1[wid] = s; sm2[wid] = ss; }
    __syncthreads();
    s  = sm1[0] + sm1[1] + sm1[2] + sm1[3];
    ss = sm2[0] + sm2[1] + sm2[2] + sm2[3];
    const float mu  = s * (1.f / DD);
    const float var = ss * (1.f / DD) - mu * mu;
    const float r   = rsqrtf(var + 1e-5f);
    float* op = out + (size_t)row * out_stride;
    op[tid]       = (v0 - mu) * r * g[tid]       + bb[tid];
    op[tid + 256] = (v1 - mu) * r * g[tid + 256] + bb[tid + 256];
}

// ------------------------- Depthwise convs / scans -------------------------
__global__ void local_conv_kernel(const float* __restrict__ x, const float* __restrict__ w,
                                  const float* __restrict__ b, float* __restrict__ y,
                                  size_t n)
{
    size_t idx = (size_t)blockIdx.x * blockDim.x + threadIdx.x;
    if (idx >= n) return;
    int d = idx & (DD - 1);
    int t = (int)(idx >> 9) & (TT - 1);
    float acc = b[d];
#pragma unroll
    for (int kk = 0; kk < 4; ++kk) {
        int ts = t - 3 + kk;
        if (ts >= 0) acc += w[d * 4 + kk] * x[idx - (size_t)(3 - kk) * DD];
    }
    y[idx] = acc;
}

__global__ void ema_scan_kernel(const float* __restrict__ x, float* __restrict__ y)
{
    int idx = blockIdx.x * blockDim.x + threadIdx.x;   // B*D
    if (idx >= BB * DD) return;
    int b = idx >> 9, d = idx & (DD - 1);
    const float* xp = x + (size_t)b * TT * DD + d;
    float* yp = y + (size_t)b * TT * DD + d;
    float acc = 0.f;
    for (int t = 0; t < TT; ++t) {
        acc = 0.9f * acc + 0.1f * xp[(size_t)t * DD];
        yp[(size_t)t * DD] = acc;
    }
}

__global__ void cumsum_kernel(const float* __restrict__ x, float* __restrict__ y)
{
    int idx = blockIdx.x * blockDim.x + threadIdx.x;   // B*D
    if (idx >= BB * DD) return;
    int b = idx >> 9, d = idx & (DD - 1);
    const float* xp = x + (size_t)b * TT * DD + d;
    float* yp = y + (size_t)b * TT * DD + d;
    float acc = 0.f;
    for (int t = 0; t < TT; ++t) {
        acc += xp[(size_t)t * DD];
        yp[(size_t)t * DD] = acc * 0.25f;   // STEP
    }
}

// ------------------------- Elementwise -------------------------
__global__ void deltas_act_kernel(float* __restrict__ gate, const float* __restrict__ delta,
                                  size_t n)
{
    size_t idx = (size_t)blockIdx.x * blockDim.x + threadIdx.x;
    if (idx >= n) return;
    float gv = gate[idx];
    float dv = delta[idx];
    gate[idx] = (1.f / (1.f + expf(-gv))) * tanhf(dv);
}

__global__ void ffn_in_kernel(const float* __restrict__ x1, const float* __restrict__ sg,
                              float* __restrict__ y, size_t n)
{
    size_t idx = (size_t)blockIdx.x * blockDim.x + threadIdx.x;
    if (idx >= n) return;
    y[idx] = x1[idx] + 0.3f * sg[idx];
}

__global__ void gelu_kernel(float* __restrict__ x, size_t n)
{
    size_t idx = (size_t)blockIdx.x * blockDim.x + threadIdx.x;
    if (idx >= n) return;
    float v = x[idx];
    x[idx] = 0.5f * v * (1.f + erff(v * 0.70710678118654752f));
}

// ---------------------------------------------------------------------------
extern "C" void kernel_launch(void* const* d_in, const int* in_sizes, int n_in,
                              void* d_out, int out_size, void* d_ws, size_t ws_size,
                              hipStream_t stream)
{
    const float* x       = (const float*)d_in[0];
    const float* seqst   = (const float*)d_in[1];
    const float* q_w     = (const float*)d_in[2];
    const float* q_b     = (const float*)d_in[3];
    const float* k_w     = (const float*)d_in[4];
    const float* k_b     = (const float*)d_in[5];
    const float* v_w     = (const float*)d_in[6];
    const float* v_b     = (const float*)d_in[7];
    const float* o_w     = (const float*)d_in[8];
    const float* o_b     = (const float*)d_in[9];
    const float* local_w = (const float*)d_in[10];
    const float* local_b = (const float*)d_in[11];
    const float* delta_w = (const float*)d_in[12];
    const float* delta_b = (const float*)d_in[13];
    const float* gate_w  = (const float*)d_in[14];
    const float* gate_b  = (const float*)d_in[15];
    const float* dn_g    = (const float*)d_in[16];
    const float* dn_b    = (const float*)d_in[17];
    const float* ln1_g   = (const float*)d_in[18];
    const float* ln1_b   = (const float*)d_in[19];
    const float* ln2_g   = (const float*)d_in[20];
    const float* ln2_b   = (const float*)d_in[21];
    const float* ln3_g   = (const float*)d_in[22];
    const float* ln3_b   = (const float*)d_in[23];
    const float* ln4_g   = (const float*)d_in[24];
    const float* ln4_b   = (const float*)d_in[25];
    const float* seq_w   = (const float*)d_in[26];
    const float* seq_b   = (const float*)d_in[27];
    const float* ffn_w1  = (const float*)d_in[28];
    const float* ffn_b1  = (const float*)d_in[29];
    const float* ffn_w2  = (const float*)d_in[30];
    const float* ffn_b2  = (const float*)d_in[31];
    const float* ema_w   = (const float*)d_in[32];  // replaced by exact recurrence
    (void)ema_w; (void)in_sizes; (void)n_in; (void)out_size; (void)ws_size;

    float* out = (float*)d_out;
    float* W0 = (float*)d_ws;
    float* W1 = W0 + SLOT;
    float* W2 = W1 + SLOT;
    float* W3 = W2 + SLOT;

    float* X1     = out;          // x1 lives in d_out until final in-place LN
    float* tabc   = out + SLOT;   // rope tables in final_state tail (consumed early)
    float* tabs   = tabc + TT * 64;
    float* fstate = out + SLOT;   // final_state (written after tables are dead)

    auto gemm = [&](const float* A, const float* Bw, const float* bias, float* C,
                    int N, int K, int M, int accum) {
        dim3 g(N / 128, M / 128);
        sgemm_nn<<<g, 256, 0, stream>>>(A, Bw, bias, C, N, K, M, accum);
    };

    const size_t NE = (size_t)NROWS * DD;             // 33554432
    const int EB = 256;
    const int NBLK = (int)((NE + EB - 1) / EB);

    // 1. RoPE tables
    rope_table_kernel<<<(TT * 64 + 255) / 256, 256, 0, stream>>>(tabc, tabs);

    // 2-4. q,k,v projections
    gemm(x, q_w, q_b, W0, NROWS, DD, DD, 0);
    gemm(x, k_w, k_b, W1, NROWS, DD, DD, 0);
    gemm(x, v_w, v_b, W2, NROWS, DD, DD, 0);

    // 5. RoPE on q,k
    {
        int n = BB * TT * HH * 64;
        rope_apply_kernel<<<(n + 255) / 256, 256, 0, stream>>>(W0, tabc, tabs);
        rope_apply_kernel<<<(n + 255) / 256, 256, 0, stream>>>(W1, tabc, tabs);
    }

    // 6. fused attention: Q=W0, K=W1, V=W2 -> attn_out in-place over W1
    attn_fused_kernel<<<dim3(HH, BB), 256, 0, stream>>>(W0, W1, W2, W1);

    // 7. o-proj: W1 @ o_w -> W0 (q dead)
    gemm(W1, o_w, o_b, W0, NROWS, DD, DD, 0);

    // 8. x1 = LN1(x + o_out) -> X1 (d_out)
    ln_kernel<<<NROWS, 256, 0, stream>>>(x, DD, W0, 1, ln1_g, ln1_b, X1, DD);

    // 9. local conv -> W0 ; 10. EMA -> W1
    local_conv_kernel<<<NBLK, EB, 0, stream>>>(X1, local_w, local_b, W0, NE);
    ema_scan_kernel<<<(BB * DD + 255) / 256, 256, 0, stream>>>(X1, W1);

    // 11. gate_acc -> W2 (v dead): x1@gw0 + local@gw1 + glob@gw2 + gate_b
    gemm(X1, gate_w,                 gate_b, W2, NROWS, DD, DD, 0);
    gemm(W0, gate_w + (size_t)DD * DD,  nullptr, W2, NROWS, DD, DD, 1);
    gemm(W1, gate_w + (size_t)2 * DD * DD, nullptr, W2, NROWS, DD, DD, 1);

    // 12. delta_acc -> W3
    gemm(X1, delta_w,                 delta_b, W3, NROWS, DD, DD, 0);
    gemm(W0, delta_w + (size_t)DD * DD,  nullptr, W3, NROWS, DD, DD, 1);
    gemm(W1, delta_w + (size_t)2 * DD * DD, nullptr, W3, NROWS, DD, DD, 1);

    // 13. deltas = sigmoid(gate)*tanh(delta) -> W2 (in place), then LN(dn)
    deltas_act_kernel<<<NBLK, EB, 0, stream>>>(W2, W3, NE);
    ln_kernel<<<NROWS, 256, 0, stream>>>(W2, DD, nullptr, 0, dn_g, dn_b, W2, DD);

    // 14. acc = cumsum * STEP -> W0 ; states = LN3(seq + acc) in place
    cumsum_kernel<<<(BB * DD + 255) / 256, 256, 0, stream>>>(W2, W0);
    ln_kernel<<<NROWS, 256, 0, stream>>>(W0, DD, seqst, 2, ln3_g, ln3_b, W0, DD);

    // 15. final_state = LN4(states[:, -1, :]) -> out tail
    ln_kernel<<<BB, 256, 0, stream>>>(W0 + (size_t)(TT - 1) * DD, (size_t)TT * DD,
                                      nullptr, 0, ln4_g, ln4_b, fstate, DD);

    // 16. seq_guidance = states @ seq_w + seq_b -> W1 (ema dead)
    gemm(W0, seq_w, seq_b, W1, NROWS, DD, DD, 0);

    // 17. ffn_in = x1 + 0.3*sg -> W2 (deltas dead)
    ffn_in_kernel<<<NBLK, EB, 0, stream>>>(X1, W1, W2, NE);

    // 18. FFN in 4 row-chunks of 16384 (h chunk = 128 MiB in W3)
    {
        const int CH = 16384;
        const size_t HN = (size_t)CH * FFD;
        const int HBLK = (int)((HN + EB - 1) / EB);
        for (int c = 0; c < 4; ++c) {
            const float* Ain = W2 + (size_t)c * CH * DD;
            float* Cout = W1 + (size_t)c * CH * DD;   // sg consumed
            gemm(Ain, ffn_w1, ffn_b1, W3, CH, DD, FFD, 0);
            gelu_kernel<<<HBLK, EB, 0, stream>>>(W3, HN);
            gemm(W3, ffn_w2, ffn_b2, Cout, CH, FFD, DD, 0);
        }
    }

    // 19. out = LN2(x1 + ffn_out) -> d_out (in place over X1)
    ln_kernel<<<NROWS, 256, 0, stream>>>(X1, DD, W1, 1, ln2_g, ln2_b, out, DD);
}

// Round 3
// 2371.310 us; speedup vs baseline: 4.7490x; 3.9534x over previous
//
#include <hip/hip_runtime.h>
#include <cstddef>
#include <cstdint>

#define BB   512
#define TT   128
#define DD   512
#define HH   4
#define HDIM 128
#define FFD  2048
#define NROWS (BB * TT)                 // 65536 rows
#define SLOT ((size_t)NROWS * DD)       // 33554432 floats = 128 MiB

typedef unsigned short u16;
typedef __bf16 bf16x8 __attribute__((ext_vector_type(8)));
typedef float  f32x4  __attribute__((ext_vector_type(4)));

__device__ __forceinline__ u16 f2b(float x) {
    union { float f; unsigned u; } v; v.f = x;
    unsigned r = v.u + 0x7FFFu + ((v.u >> 16) & 1u);
    return (u16)(r >> 16);
}

__device__ __forceinline__ void glds16(const void* g, void* l) {
    __builtin_amdgcn_global_load_lds(
        (const __attribute__((address_space(1))) void*)g,
        (__attribute__((address_space(3))) void*)l, 16, 0, 0);
}

// ---------------- bf16 MFMA GEMM: 128x128 tile, 4 waves, BK=32 -------------
// A: (N,K) bf16 row-major. BT: (M,K) bf16 row-major (= B^T). bias fp32 (M).
// MODE 0: fp32 out.  MODE 2: bf16 out = addsrc + 0.3*C.  MODE 3: bf16 gelu(C).
template<int MODE>
__global__ __launch_bounds__(256)
void gemm_bf16(const u16* __restrict__ A, const u16* __restrict__ BT,
               const float* __restrict__ bias, void* __restrict__ Cout, int ldc,
               const float* __restrict__ addsrc, int K, int M)
{
    __shared__ u16 As[128 * 32];
    __shared__ u16 Bs[128 * 32];
    const int tid  = threadIdx.x;
    const int row0 = blockIdx.x * 128;
    const int col0 = blockIdx.y * 128;
    const int lane = tid & 63;
    const int w    = tid >> 6;
    const int wr   = (w >> 1) * 64;
    const int wc   = (w & 1) * 64;
    const int fr   = lane & 15;
    const int kg   = (lane >> 4) * 8;   // k offset within BK (elements)

    f32x4 acc[4][4];
#pragma unroll
    for (int m = 0; m < 4; ++m)
#pragma unroll
        for (int n = 0; n < 4; ++n) acc[m][n] = (f32x4){0.f, 0.f, 0.f, 0.f};

    // staging: thread tid moves 16B: LDS elem offset tid*8; row tid>>2, k (tid&3)*8
    const int srow = tid >> 2;
    const int skb  = (tid & 3) * 8;
    const u16* Ag = A  + (size_t)(row0 + srow) * K + skb;
    const u16* Bg = BT + (size_t)(col0 + srow) * K + skb;
    u16* AsP = &As[srow * 32 + skb];
    u16* BsP = &Bs[srow * 32 + skb];

    for (int k0 = 0; k0 < K; k0 += 32) {
        glds16(Ag + k0,               AsP);
        glds16(Ag + (size_t)64 * K + k0, AsP + 64 * 32);
        glds16(Bg + k0,               BsP);
        glds16(Bg + (size_t)64 * K + k0, BsP + 64 * 32);
        __syncthreads();
        bf16x8 af[4], bfr[4];
#pragma unroll
        for (int m = 0; m < 4; ++m)
            af[m] = *reinterpret_cast<const bf16x8*>(&As[(wr + m * 16 + fr) * 32 + kg]);
#pragma unroll
        for (int n = 0; n < 4; ++n)
            bfr[n] = *reinterpret_cast<const bf16x8*>(&Bs[(wc + n * 16 + fr) * 32 + kg]);
#pragma unroll
        for (int m = 0; m < 4; ++m)
#pragma unroll
            for (int n = 0; n < 4; ++n)
                acc[m][n] = __builtin_amdgcn_mfma_f32_16x16x32_bf16(af[m], bfr[n], acc[m][n], 0, 0, 0);
        __syncthreads();
    }

    // epilogue: C/D layout col=lane&15, row=(lane>>4)*4 + j  [m89/m91]
#pragma unroll
    for (int m = 0; m < 4; ++m) {
#pragma unroll
        for (int j = 0; j < 4; ++j) {
            const int r = row0 + wr + m * 16 + (lane >> 4) * 4 + j;
#pragma unroll
            for (int n = 0; n < 4; ++n) {
                const int c = col0 + wc + n * 16 + fr;
                float v = acc[m][n][j] + bias[c];
                if constexpr (MODE == 0) {
                    ((float*)Cout)[(size_t)r * ldc + c] = v;
                } else if constexpr (MODE == 2) {
                    ((u16*)Cout)[(size_t)r * ldc + c] =
                        f2b(addsrc[(size_t)r * M + c] + 0.3f * v);
                } else {  // MODE 3: exact GELU
                    float gv = 0.5f * v * (1.f + erff(v * 0.70710678118654752f));
                    ((u16*)Cout)[(size_t)r * ldc + c] = f2b(gv);
                }
            }
        }
    }
}

// ---------------- weight transpose+cast: W (K,M) f32 -> WT (M,K) bf16 ------
__global__ __launch_bounds__(256)
void wtrans_kernel(const float* __restrict__ W, u16* __restrict__ WT, int K, int M)
{
    __shared__ float t[32][33];
    const int m0 = blockIdx.x * 32;
    const int k0 = blockIdx.y * 32;
    const int tx = threadIdx.x;   // 0..31
    const int ty = threadIdx.y;   // 0..7
#pragma unroll
    for (int i = 0; i < 4; ++i) {
        int k = ty * 4 + i;
        t[k][tx] = W[(size_t)(k0 + k) * M + m0 + tx];
    }
    __syncthreads();
#pragma unroll
    for (int i = 0; i < 4; ++i) {
        int m = ty * 4 + i;
        WT[(size_t)(m0 + m) * K + k0 + tx] = f2b(t[tx][m]);
    }
}

// ---------------- fp32 -> bf16 cast ----------------
__global__ void cast_f2b_kernel(const float* __restrict__ in, u16* __restrict__ out, size_t n4)
{
    size_t i = (size_t)blockIdx.x * blockDim.x + threadIdx.x;
    if (i >= n4) return;
    float4 v = reinterpret_cast<const float4*>(in)[i];
    union { u16 u[4]; uint2 d; } p;
    p.u[0] = f2b(v.x); p.u[1] = f2b(v.y); p.u[2] = f2b(v.z); p.u[3] = f2b(v.w);
    reinterpret_cast<uint2*>(out)[i] = p.d;
}

// ------------------------- RoPE -------------------------
__global__ void rope_table_kernel(float* __restrict__ tabc, float* __restrict__ tabs)
{
    int idx = blockIdx.x * blockDim.x + threadIdx.x;
    if (idx >= TT * 64) return;
    int t = idx >> 6, j = idx & 63;
    float invf = expf(-(float)j * (9.210340371976184f / 64.f));
    float ang  = (float)t * invf;
    tabc[idx] = cosf(ang);
    tabs[idx] = sinf(ang);
}

__global__ void rope_apply_kernel(float* __restrict__ p,
                                  const float* __restrict__ tabc,
                                  const float* __restrict__ tabs)
{
    int idx = blockIdx.x * blockDim.x + threadIdx.x;   // B*T*H*64
    if (idx >= BB * TT * HH * 64) return;
    int j = idx & 63;
    int h = (idx >> 6) & (HH - 1);
    int t = (idx >> 8) & (TT - 1);
    int b = idx >> 15;
    float c  = tabc[t * 64 + j];
    float sn = tabs[t * 64 + j];
    float* q = p + ((size_t)(b * TT + t)) * DD + h * HDIM + j;
    float x1 = q[0], x2 = q[64];
    q[0]  = x1 * c - x2 * sn;
    q[64] = x2 * c + x1 * sn;
}

// ---------------- fused attention (fp32 compute, bf16 output) --------------
__global__ __launch_bounds__(256)
void attn_fused_kernel(const float* __restrict__ q, const float* __restrict__ k,
                       const float* __restrict__ v, u16* __restrict__ ob)
{
    __shared__ float Qs[128][128];   // Q^T [d][row] -> later P [s][row]
    __shared__ float Ks[128][128];   // K^T [d][col] -> later V [s][dc]
    const int h = blockIdx.x, b = blockIdx.y;
    const int tid = threadIdx.x;
    const size_t base = ((size_t)b * TT) * DD + (size_t)h * HDIM;

    {
        const int row  = tid >> 1;
        const int half = tid & 1;
        const float* qp = q + base + (size_t)row * DD;
        const float* kp = k + base + (size_t)row * DD;
#pragma unroll
        for (int m = 0; m < 16; ++m) {
            const int qq = 2 * m + half;
            float4 qv = *reinterpret_cast<const float4*>(qp + qq * 4);
            float4 kv = *reinterpret_cast<const float4*>(kp + qq * 4);
            Qs[qq * 4 + 0][row] = qv.x; Qs[qq * 4 + 1][row] = qv.y;
            Qs[qq * 4 + 2][row] = qv.z; Qs[qq * 4 + 3][row] = qv.w;
            Ks[qq * 4 + 0][row] = kv.x; Ks[qq * 4 + 1][row] = kv.y;
            Ks[qq * 4 + 2][row] = kv.z; Ks[qq * 4 + 3][row] = kv.w;
        }
    }
    __syncthreads();

    const int tx = tid & 15;
    const int ty = tid >> 4;

    float acc[8][8];
#pragma unroll
    for (int i = 0; i < 8; ++i)
#pragma unroll
        for (int j = 0; j < 8; ++j) acc[i][j] = 0.f;

    for (int d = 0; d < 128; ++d) {
        float4 a0 = *reinterpret_cast<const float4*>(&Qs[d][8 * ty]);
        float4 a1 = *reinterpret_cast<const float4*>(&Qs[d][8 * ty + 4]);
        float4 b0 = *reinterpret_cast<const float4*>(&Ks[d][8 * tx]);
        float4 b1 = *reinterpret_cast<const float4*>(&Ks[d][8 * tx + 4]);
        float a[8] = {a0.x, a0.y, a0.z, a0.w, a1.x, a1.y, a1.z, a1.w};
        float bb2[8] = {b0.x, b0.y, b0.z, b0.w, b1.x, b1.y, b1.z, b1.w};
#pragma unroll
        for (int i = 0; i < 8; ++i)
#pragma unroll
            for (int j = 0; j < 8; ++j)
                acc[i][j] = fmaf(a[i], bb2[j], acc[i][j]);
    }
    __syncthreads();

    {   // V into Ks
        const int qi = tid & 31, rg = tid >> 5;
        const float* vp = v + base;
#pragma unroll
        for (int it = 0; it < 16; ++it) {
            const int row = it * 8 + rg;
            float4 vv = *reinterpret_cast<const float4*>(vp + (size_t)row * DD + qi * 4);
            *reinterpret_cast<float4*>(&Ks[row][qi * 4]) = vv;
        }
    }

    const float SCALE = 0.08838834764831845f;
    float pmax[8];
#pragma unroll
    for (int i = 0; i < 8; ++i) {
        const int r = 8 * ty + i;
        float m = -3.0e38f;
#pragma unroll
        for (int j = 0; j < 8; ++j) {
            const int c = 8 * tx + j;
            acc[i][j] = (c <= r) ? acc[i][j] * SCALE : -3.0e38f;
            m = fmaxf(m, acc[i][j]);
        }
        pmax[i] = m;
    }
#pragma unroll
    for (int off = 1; off < 16; off <<= 1)
#pragma unroll
        for (int i = 0; i < 8; ++i)
            pmax[i] = fmaxf(pmax[i], __shfl_xor(pmax[i], off));

    float psum[8];
#pragma unroll
    for (int i = 0; i < 8; ++i) {
        float s = 0.f;
#pragma unroll
        for (int j = 0; j < 8; ++j) {
            float p = expf(acc[i][j] - pmax[i]);
            acc[i][j] = p;
            s += p;
        }
        psum[i] = s;
    }
#pragma unroll
    for (int off = 1; off < 16; off <<= 1)
#pragma unroll
        for (int i = 0; i < 8; ++i)
            psum[i] += __shfl_xor(psum[i], off);

#pragma unroll
    for (int i = 0; i < 8; ++i) {
        const float inv = 1.0f / psum[i];
#pragma unroll
        for (int j = 0; j < 8; ++j)
            Qs[8 * tx + j][8 * ty + i] = acc[i][j] * inv;
    }
    __syncthreads();

#pragma unroll
    for (int i = 0; i < 8; ++i)
#pragma unroll
        for (int j = 0; j < 8; ++j) acc[i][j] = 0.f;

    for (int s = 0; s < 128; ++s) {
        float4 a0 = *reinterpret_cast<const float4*>(&Qs[s][8 * ty]);
        float4 a1 = *reinterpret_cast<const float4*>(&Qs[s][8 * ty + 4]);
        float4 b0 = *reinterpret_cast<const float4*>(&Ks[s][8 * tx]);
        float4 b1 = *reinterpret_cast<const float4*>(&Ks[s][8 * tx + 4]);
        float a[8] = {a0.x, a0.y, a0.z, a0.w, a1.x, a1.y, a1.z, a1.w};
        float bb2[8] = {b0.x, b0.y, b0.z, b0.w, b1.x, b1.y, b1.z, b1.w};
#pragma unroll
        for (int i = 0; i < 8; ++i)
#pragma unroll
            for (int j = 0; j < 8; ++j)
                acc[i][j] = fmaf(a[i], bb2[j], acc[i][j]);
    }

#pragma unroll
    for (int i = 0; i < 8; ++i) {
        u16* op = ob + base + (size_t)(8 * ty + i) * DD + 8 * tx;
        union { u16 u[8]; uint4 v4; } pk;
#pragma unroll
        for (int j = 0; j < 8; ++j) pk.u[j] = f2b(acc[i][j]);
        *reinterpret_cast<uint4*>(op) = pk.v4;
    }
}

// ---------------- LayerNorm (dual fp32 + optional bf16 out) ----------------
__global__ __launch_bounds__(256)
void ln_kernel(const float* __restrict__ a, size_t a_stride,
               const float* __restrict__ badd, int b_mode,
               const float* __restrict__ g, const float* __restrict__ bb,
               float* __restrict__ out, size_t out_stride,
               u16* __restrict__ out2, size_t out2_stride)
{
    const int row = blockIdx.x;
    const int tid = threadIdx.x;
    const float* ap = a + (size_t)row * a_stride;
    float v0 = ap[tid];
    float v1 = ap[tid + 256];
    if (b_mode == 1) {
        const float* bp = badd + (size_t)row * DD;
        v0 += bp[tid]; v1 += bp[tid + 256];
    } else if (b_mode == 2) {
        const float* bp = badd + (size_t)(row / TT) * DD;
        v0 += bp[tid]; v1 += bp[tid + 256];
    }
    float s  = v0 + v1;
    float ss = v0 * v0 + v1 * v1;
#pragma unroll
    for (int off = 1; off < 64; off <<= 1) {
        s  += __shfl_xor(s, off);
        ss += __shfl_xor(ss, off);
    }
    __shared__ float sm1[4], sm2[4];
    const int wid = tid >> 6;
    if ((tid & 63) == 0) { sm1[wid] = s; sm2[wid] = ss; }
    __syncthreads();
    s  = sm1[0] + sm1[1] + sm1[2] + sm1[3];
    ss = sm2[0] + sm2[1] + sm2[2] + sm2[3];
    const float mu  = s * (1.f / DD);
    const float var = ss * (1.f / DD) - mu * mu;
    const float r   = rsqrtf(var + 1e-5f);
    const float o0 = (v0 - mu) * r * g[tid]       + bb[tid];
    const float o1 = (v1 - mu) * r * g[tid + 256] + bb[tid + 256];
    if (out) {
        float* op = out + (size_t)row * out_stride;
        op[tid] = o0; op[tid + 256] = o1;
    }
    if (out2) {
        u16* op2 = out2 + (size_t)row * out2_stride;
        op2[tid] = f2b(o0); op2[tid + 256] = f2b(o1);
    }
}

// ---------------- depthwise convs / scans ----------------
__global__ void local_conv_kernel(const float* __restrict__ x, const float* __restrict__ w,
                                  const float* __restrict__ b, u16* __restrict__ y, size_t n)
{
    size_t idx = (size_t)blockIdx.x * blockDim.x + threadIdx.x;
    if (idx >= n) return;
    int d = idx & (DD - 1);
    int t = (int)(idx >> 9) & (TT - 1);
    size_t row = idx >> 9;
    float acc = b[d];
#pragma unroll
    for (int kk = 0; kk < 4; ++kk) {
        int ts = t - 3 + kk;
        if (ts >= 0) acc += w[d * 4 + kk] * x[idx - (size_t)(3 - kk) * DD];
    }
    y[row * 1536 + d] = f2b(acc);
}

__global__ void ema_scan_kernel(const float* __restrict__ x, u16* __restrict__ y)
{
    int idx = blockIdx.x * blockDim.x + threadIdx.x;   // B*D
    if (idx >= BB * DD) return;
    int b = idx >> 9, d = idx & (DD - 1);
    const float* xp = x + (size_t)b * TT * DD + d;
    u16* yp = y + (size_t)(b * TT) * 1536 + d;
    float acc = 0.f;
    for (int t = 0; t < TT; ++t) {
        acc = 0.9f * acc + 0.1f * xp[(size_t)t * DD];
        yp[(size_t)t * 1536] = f2b(acc);
    }
}

__global__ void cumsum_kernel(const float* __restrict__ x, float* __restrict__ y)
{
    int idx = blockIdx.x * blockDim.x + threadIdx.x;   // B*D
    if (idx >= BB * DD) return;
    int b = idx >> 9, d = idx & (DD - 1);
    const float* xp = x + (size_t)b * TT * DD + d;
    float* yp = y + (size_t)b * TT * DD + d;
    float acc = 0.f;
    for (int t = 0; t < TT; ++t) {
        acc += xp[(size_t)t * DD];
        yp[(size_t)t * DD] = acc * 0.25f;   // STEP
    }
}

__global__ void deltas_act_kernel(float* __restrict__ gate, const float* __restrict__ delta,
                                  size_t n)
{
    size_t idx = (size_t)blockIdx.x * blockDim.x + threadIdx.x;
    if (idx >= n) return;
    float gv = gate[idx];
    float dv = delta[idx];
    gate[idx] = (1.f / (1.f + expf(-gv))) * tanhf(dv);
}

// ---------------------------------------------------------------------------
extern "C" void kernel_launch(void* const* d_in, const int* in_sizes, int n_in,
                              void* d_out, int out_size, void* d_ws, size_t ws_size,
                              hipStream_t stream)
{
    const float* x       = (const float*)d_in[0];
    const float* seqst   = (const float*)d_in[1];
    const float* q_w     = (const float*)d_in[2];
    const float* q_b     = (const float*)d_in[3];
    const float* k_w     = (const float*)d_in[4];
    const float* k_b     = (const float*)d_in[5];
    const float* v_w     = (const float*)d_in[6];
    const float* v_b     = (const float*)d_in[7];
    const float* o_w     = (const float*)d_in[8];
    const float* o_b     = (const float*)d_in[9];
    const float* local_w = (const float*)d_in[10];
    const float* local_b = (const float*)d_in[11];
    const float* delta_w = (const float*)d_in[12];
    const float* delta_b = (const float*)d_in[13];
    const float* gate_w  = (const float*)d_in[14];
    const float* gate_b  = (const float*)d_in[15];
    const float* dn_g    = (const float*)d_in[16];
    const float* dn_b    = (const float*)d_in[17];
    const float* ln1_g   = (const float*)d_in[18];
    const float* ln1_b   = (const float*)d_in[19];
    const float* ln2_g   = (const float*)d_in[20];
    const float* ln2_b   = (const float*)d_in[21];
    const float* ln3_g   = (const float*)d_in[22];
    const float* ln3_b   = (const float*)d_in[23];
    const float* ln4_g   = (const float*)d_in[24];
    const float* ln4_b   = (const float*)d_in[25];
    const float* seq_w   = (const float*)d_in[26];
    const float* seq_b   = (const float*)d_in[27];
    const float* ffn_w1  = (const float*)d_in[28];
    const float* ffn_b1  = (const float*)d_in[29];
    const float* ffn_w2  = (const float*)d_in[30];
    const float* ffn_b2  = (const float*)d_in[31];
    (void)in_sizes; (void)n_in; (void)out_size; (void)ws_size;

    float* out = (float*)d_out;
    char*  ws  = (char*)d_ws;
    const size_t MB = (size_t)1 << 20;

    // ---- region map (byte offsets in d_ws) ----
    float* Qf   = (float*)(ws + 0);            // [0,128M): Q -> o_out -> deltas -> F
    float* Kf   = (float*)(ws + 128 * MB);     // [128,256M): K
    float* Vf   = (float*)(ws + 256 * MB);     // [256,384M): V
    u16*   xb   = (u16*)(ws + 384 * MB);       // [384,448M): xb -> attnb
    u16*   WSa  = (u16*)(ws + 448 * MB);       // [448,450M): rotating weight^T
    u16*   WSb  = (u16*)(ws + 450 * MB);       // [450,452M): second (FFN)
    u16*   attnb   = xb;
    u16*   Cb      = (u16*)(ws + 128 * MB);    // [128,320M): (N,1536) bf16
    float* Dl      = (float*)(ws + 320 * MB);  // [320,448M): delta acc -> states
    float* Sst     = Dl;
    u16*   statesb = (u16*)(ws + 0);           // [0,64M)
    u16*   ffn_inb = (u16*)(ws + 64 * MB);     // [64,128M)
    u16*   hb      = (u16*)(ws + 128 * MB);    // [128,384M): (N,2048) bf16
    float* Fo      = (float*)(ws + 0);         // [0,128M): ffn_out

    float* X1     = out;
    float* tabc   = out + SLOT;
    float* tabs   = tabc + TT * 64;
    float* fstate = out + SLOT;

    auto wtrans = [&](const float* W, u16* WT, int K, int M) {
        wtrans_kernel<<<dim3(M / 32, K / 32), dim3(32, 8), 0, stream>>>(W, WT, K, M);
    };
    auto gemm0 = [&](const u16* A, const u16* BT, const float* bias, float* C,
                     int K, int M) {
        gemm_bf16<0><<<dim3(NROWS / 128, M / 128), 256, 0, stream>>>(
            A, BT, bias, C, M, nullptr, K, M);
    };

    const size_t NE = (size_t)NROWS * DD;
    const int EB = 256;
    const int NBLK = (int)((NE + EB - 1) / EB);

    // 0. rope tables; cast x -> xb
    rope_table_kernel<<<(TT * 64 + 255) / 256, 256, 0, stream>>>(tabc, tabs);
    cast_f2b_kernel<<<(unsigned)((NE / 4 + 255) / 256), 256, 0, stream>>>(x, xb, NE / 4);

    // 1. q,k,v projections (bf16 MFMA)
    wtrans(q_w, WSa, DD, DD); gemm0(xb, WSa, q_b, Qf, DD, DD);
    wtrans(k_w, WSa, DD, DD); gemm0(xb, WSa, k_b, Kf, DD, DD);
    wtrans(v_w, WSa, DD, DD); gemm0(xb, WSa, v_b, Vf, DD, DD);

    // 2. RoPE on q,k
    {
        int n = BB * TT * HH * 64;
        rope_apply_kernel<<<(n + 255) / 256, 256, 0, stream>>>(Qf, tabc, tabs);
        rope_apply_kernel<<<(n + 255) / 256, 256, 0, stream>>>(Kf, tabc, tabs);
    }

    // 3. fused attention -> attnb (bf16, overwrites xb region)
    attn_fused_kernel<<<dim3(HH, BB), 256, 0, stream>>>(Qf, Kf, Vf, attnb);

    // 4. o-proj -> Qf region (fp32)
    wtrans(o_w, WSa, DD, DD); gemm0(attnb, WSa, o_b, Qf, DD, DD);

    // 5. x1 = LN1(x + o_out) -> X1 fp32 + Cb[:,0:512] bf16
    ln_kernel<<<NROWS, 256, 0, stream>>>(x, DD, Qf, 1, ln1_g, ln1_b, X1, DD, Cb, 1536);

    // 6. local conv -> Cb[:,512:1024] ; EMA -> Cb[:,1024:1536]
    local_conv_kernel<<<NBLK, EB, 0, stream>>>(X1, local_w, local_b, Cb + 512, NE);
    ema_scan_kernel<<<(BB * DD + 255) / 256, 256, 0, stream>>>(X1, Cb + 1024);

    // 7. gate -> Qf(G), delta -> Dl  (single K=1536 GEMMs)
    wtrans(gate_w, WSa, 3 * DD, DD);
    gemm0(Cb, WSa, gate_b, Qf, 3 * DD, DD);
    wtrans(delta_w, WSa, 3 * DD, DD);
    gemm0(Cb, WSa, delta_b, Dl, 3 * DD, DD);

    // 8. deltas = sigmoid(gate)*tanh(delta) in-place on Qf, then LN(dn)
    deltas_act_kernel<<<NBLK, EB, 0, stream>>>(Qf, Dl, NE);
    ln_kernel<<<NROWS, 256, 0, stream>>>(Qf, DD, nullptr, 0, dn_g, dn_b, Qf, DD, nullptr, 0);

    // 9. acc = cumsum*STEP -> Sst ; states = LN3(seq + acc) in-place + statesb bf16
    cumsum_kernel<<<(BB * DD + 255) / 256, 256, 0, stream>>>(Qf, Sst);
    ln_kernel<<<NROWS, 256, 0, stream>>>(Sst, DD, seqst, 2, ln3_g, ln3_b, Sst, DD, statesb, DD);

    // 10. final_state = LN4(states[:,-1,:]) -> out tail
    ln_kernel<<<BB, 256, 0, stream>>>(Sst + (size_t)(TT - 1) * DD, (size_t)TT * DD,
                                      nullptr, 0, ln4_g, ln4_b, fstate, DD, nullptr, 0);

    // 11. ffn_in = x1 + 0.3*(states@seq_w + seq_b) -> ffn_inb (bf16, fused)
    wtrans(seq_w, WSa, DD, DD);
    gemm_bf16<2><<<dim3(NROWS / 128, 4), 256, 0, stream>>>(
        statesb, WSa, seq_b, ffn_inb, DD, X1, DD, DD);

    // 12. FFN: h = gelu(ffn_in@w1 + b1) bf16 -> hb ; ffn_out = h@w2 + b2 -> Fo
    wtrans(ffn_w1, WSa, DD, FFD);
    wtrans(ffn_w2, WSb, FFD, DD);
    gemm_bf16<3><<<dim3(NROWS / 128, FFD / 128), 256, 0, stream>>>(
        ffn_inb, WSa, ffn_b1, hb, FFD, nullptr, DD, FFD);
    gemm0(hb, WSb, ffn_b2, Fo, FFD, DD);

    // 13. out = LN2(x1 + ffn_out) -> d_out in-place
    ln_kernel<<<NROWS, 256, 0, stream>>>(X1, DD, Fo, 1, ln2_g, ln2_b, out, DD, nullptr, 0);
}

// Round 4
// 1975.624 us; speedup vs baseline: 5.7001x; 1.2003x over previous
//
#include <hip/hip_runtime.h>
#include <cstddef>
#include <cstdint>

#define BB   512
#define TT   128
#define DD   512
#define HH   4
#define HDIM 128
#define FFD  2048
#define NROWS (BB * TT)                 // 65536 rows
#define SLOT ((size_t)NROWS * DD)       // 33554432 floats = 128 MiB

typedef unsigned short u16;
typedef __bf16 bf16x8 __attribute__((ext_vector_type(8)));
typedef float  f32x4  __attribute__((ext_vector_type(4)));

__device__ __forceinline__ u16 f2b(float x) {
    union { float f; unsigned u; } v; v.f = x;
    unsigned r = v.u + 0x7FFFu + ((v.u >> 16) & 1u);
    return (u16)(r >> 16);
}
__device__ __forceinline__ float b2f(u16 u) {
    union { unsigned u; float f; } v; v.u = (unsigned)u << 16; return v.f;
}

__device__ __forceinline__ void glds16(const void* g, void* l) {
    __builtin_amdgcn_global_load_lds(
        (const __attribute__((address_space(1))) void*)g,
        (__attribute__((address_space(3))) void*)l, 16, 0, 0);
}

// ---------------- bf16 MFMA GEMM: 128x128 tile, 4 waves, BK=32 -------------
// A: (N,K) bf16 row-major. BT: (M,K) bf16 row-major (= B^T). bias fp32 (M).
// MODE 0: fp32 out. MODE 2: bf16 out = addsrc + 0.3*C. MODE 3: bf16 gelu(C).
// MODE 4: bf16 out. MODE 5: bf16 V^T tiles [tile][dc][t] XOR-swizzled rows.
template<int MODE>
__global__ __launch_bounds__(256)
void gemm_bf16(const u16* __restrict__ A, const u16* __restrict__ BT,
               const float* __restrict__ bias, void* __restrict__ Cout, int ldc,
               const float* __restrict__ addsrc, int K, int M)
{
    __shared__ u16 As[128 * 32];
    __shared__ u16 Bs[128 * 32];
    __shared__ u16 Ct[(MODE == 5) ? 128 * 128 : 8];
    const int tid = threadIdx.x;
    // XCD-aware swizzle: contiguous logical tiles per XCD (grid always %8==0 here)
    const int gx  = gridDim.x;
    const int nwg = gx * gridDim.y;
    int orig = blockIdx.y * gx + blockIdx.x;
    if ((nwg & 7) == 0) orig = (orig & 7) * (nwg >> 3) + (orig >> 3);
    const int row0 = (orig / gx) * 128;
    const int col0 = (orig % gx) * 128;

    const int lane = tid & 63;
    const int w    = tid >> 6;
    const int wr   = (w >> 1) * 64;
    const int wc   = (w & 1) * 64;
    const int fr   = lane & 15;
    const int kg   = (lane >> 4) * 8;

    f32x4 acc[4][4];
#pragma unroll
    for (int m = 0; m < 4; ++m)
#pragma unroll
        for (int n = 0; n < 4; ++n) acc[m][n] = (f32x4){0.f, 0.f, 0.f, 0.f};

    const int srow = tid >> 2;
    const int skb  = (tid & 3) * 8;
    const u16* Ag = A  + (size_t)(row0 + srow) * K + skb;
    const u16* Bg = BT + (size_t)(col0 + srow) * K + skb;
    u16* AsP = &As[srow * 32 + skb];
    u16* BsP = &Bs[srow * 32 + skb];

    for (int k0 = 0; k0 < K; k0 += 32) {
        glds16(Ag + k0,                  AsP);
        glds16(Ag + (size_t)64 * K + k0, AsP + 64 * 32);
        glds16(Bg + k0,                  BsP);
        glds16(Bg + (size_t)64 * K + k0, BsP + 64 * 32);
        __syncthreads();
        bf16x8 af[4], bfr[4];
#pragma unroll
        for (int m = 0; m < 4; ++m)
            af[m] = *reinterpret_cast<const bf16x8*>(&As[(wr + m * 16 + fr) * 32 + kg]);
#pragma unroll
        for (int n = 0; n < 4; ++n)
            bfr[n] = *reinterpret_cast<const bf16x8*>(&Bs[(wc + n * 16 + fr) * 32 + kg]);
#pragma unroll
        for (int m = 0; m < 4; ++m)
#pragma unroll
            for (int n = 0; n < 4; ++n)
                acc[m][n] = __builtin_amdgcn_mfma_f32_16x16x32_bf16(af[m], bfr[n], acc[m][n], 0, 0, 0);
        __syncthreads();
    }

    if constexpr (MODE == 5) {
        // transposed bf16 tile: Ct[dc][t] rows of 256B, byte ^= ((dc&7)<<4)
#pragma unroll
        for (int m = 0; m < 4; ++m)
#pragma unroll
            for (int j = 0; j < 4; ++j) {
                const int tl = wr + m * 16 + (lane >> 4) * 4 + j;
#pragma unroll
                for (int n = 0; n < 4; ++n) {
                    const int dc = wc + n * 16 + fr;
                    float v = acc[m][n][j] + bias[col0 + dc];
                    *(u16*)((char*)Ct + dc * 256 + ((tl * 2) ^ ((dc & 7) << 4))) = f2b(v);
                }
            }
        __syncthreads();
        u16* dst = (u16*)Cout + (((size_t)(row0 >> 7) * (M >> 7) + (col0 >> 7)) << 14);
#pragma unroll
        for (int i = 0; i < 8; ++i)
            *(uint4*)(dst + (size_t)(i * 256 + tid) * 8) =
                *(const uint4*)((char*)Ct + (size_t)(i * 256 + tid) * 16);
    } else {
#pragma unroll
        for (int m = 0; m < 4; ++m) {
#pragma unroll
            for (int j = 0; j < 4; ++j) {
                const int r = row0 + wr + m * 16 + (lane >> 4) * 4 + j;
#pragma unroll
                for (int n = 0; n < 4; ++n) {
                    const int c = col0 + wc + n * 16 + fr;
                    float v = acc[m][n][j] + bias[c];
                    if constexpr (MODE == 0) {
                        ((float*)Cout)[(size_t)r * ldc + c] = v;
                    } else if constexpr (MODE == 2) {
                        ((u16*)Cout)[(size_t)r * ldc + c] =
                            f2b(addsrc[(size_t)r * M + c] + 0.3f * v);
                    } else if constexpr (MODE == 3) {
                        float gv = 0.5f * v * (1.f + erff(v * 0.70710678118654752f));
                        ((u16*)Cout)[(size_t)r * ldc + c] = f2b(gv);
                    } else {  // MODE 4
                        ((u16*)Cout)[(size_t)r * ldc + c] = f2b(v);
                    }
                }
            }
        }
    }
}

// ---------------- weight transpose+cast: W (K,M) f32 -> WT (M,K) bf16 ------
__global__ __launch_bounds__(256)
void wtrans_kernel(const float* __restrict__ W, u16* __restrict__ WT, int K, int M)
{
    __shared__ float t[32][33];
    const int m0 = blockIdx.x * 32;
    const int k0 = blockIdx.y * 32;
    const int tx = threadIdx.x;
    const int ty = threadIdx.y;
#pragma unroll
    for (int i = 0; i < 4; ++i) {
        int k = ty * 4 + i;
        t[k][tx] = W[(size_t)(k0 + k) * M + m0 + tx];
    }
    __syncthreads();
#pragma unroll
    for (int i = 0; i < 4; ++i) {
        int m = ty * 4 + i;
        WT[(size_t)(m0 + m) * K + k0 + tx] = f2b(t[tx][m]);
    }
}

__global__ void cast_f2b_kernel(const float* __restrict__ in, u16* __restrict__ out, size_t n4)
{
    size_t i = (size_t)blockIdx.x * blockDim.x + threadIdx.x;
    if (i >= n4) return;
    float4 v = reinterpret_cast<const float4*>(in)[i];
    union { u16 u[4]; uint2 d; } p;
    p.u[0] = f2b(v.x); p.u[1] = f2b(v.y); p.u[2] = f2b(v.z); p.u[3] = f2b(v.w);
    reinterpret_cast<uint2*>(out)[i] = p.d;
}

__global__ void rope_table_kernel(float* __restrict__ tabc, float* __restrict__ tabs)
{
    int idx = blockIdx.x * blockDim.x + threadIdx.x;
    if (idx >= TT * 64) return;
    int t = idx >> 6, j = idx & 63;
    float invf = expf(-(float)j * (9.210340371976184f / 64.f));
    float ang  = (float)t * invf;
    tabc[idx] = cosf(ang);
    tabs[idx] = sinf(ang);
}

// ---------------- MFMA attention: one block per (b,h), RoPE inline ---------
// Q,K bf16 (b,t,D); VT bf16 pre-transposed+swizzled tiles [(b*H+h)][dc][t].
// LDS tiles: rows of 256B (128 bf16), byte-col ^= ((row&7)<<4).
__global__ __launch_bounds__(256)
void attn_mfma_kernel(const u16* __restrict__ Qg, const u16* __restrict__ Kg,
                      const u16* __restrict__ VTg, u16* __restrict__ Og,
                      const float* __restrict__ tabc, const float* __restrict__ tabs)
{
    __shared__ u16 SA[128 * 128];   // Q -> P
    __shared__ u16 SB[128 * 128];   // K -> V^T
    const int h = blockIdx.x, b = blockIdx.y;
    const int tid  = threadIdx.x;
    const int lane = tid & 63;
    const int w    = tid >> 6;
    const int fr   = lane & 15;
    const int kq   = lane >> 4;          // 0..3
    const size_t base = ((size_t)(b * TT)) * DD + (size_t)h * HDIM;

    // ---- stage Q,K with inline RoPE (pairs d, d+64 via shfl_xor 8) ----
    {
        const int tg = tid >> 4;         // row in group of 16
        const int dg = tid & 15;         // 16B chunk (8 bf16)
        const int j0 = (dg & 7) * 8;
        const bool hi = (dg & 8) != 0;
        for (int r = 0; r < 8; ++r) {
            const int t = r * 16 + tg;
            uint4 qv = *(const uint4*)(Qg + base + (size_t)t * DD + dg * 8);
            uint4 kv = *(const uint4*)(Kg + base + (size_t)t * DD + dg * 8);
            unsigned qa[4] = {qv.x, qv.y, qv.z, qv.w};
            unsigned ka[4] = {kv.x, kv.y, kv.z, kv.w};
            unsigned qb[4], kb[4];
#pragma unroll
            for (int i = 0; i < 4; ++i) {
                qb[i] = __shfl_xor((int)qa[i], 8);
                kb[i] = __shfl_xor((int)ka[i], 8);
            }
            const float* cp = tabc + t * 64 + j0;
            const float* sp = tabs + t * 64 + j0;
            u16 oq[8], ok[8];
#pragma unroll
            for (int e = 0; e < 8; ++e) {
                float fq = b2f((u16)(qa[e >> 1] >> ((e & 1) * 16)));
                float gq = b2f((u16)(qb[e >> 1] >> ((e & 1) * 16)));
                float fk = b2f((u16)(ka[e >> 1] >> ((e & 1) * 16)));
                float gk = b2f((u16)(kb[e >> 1] >> ((e & 1) * 16)));
                float c = cp[e], s = sp[e];
                oq[e] = f2b(hi ? fq * c + gq * s : fq * c - gq * s);
                ok[e] = f2b(hi ? fk * c + gk * s : fk * c - gk * s);
            }
            const int cb = (dg * 16) ^ ((t & 7) << 4);
            *(uint4*)((char*)SA + t * 256 + cb) = *(const uint4*)oq;
            *(uint4*)((char*)SB + t * 256 + cb) = *(const uint4*)ok;
        }
    }
    __syncthreads();

    // ---- S = Q K^T : wave w owns rows w*32..+31, all 128 cols ----
    f32x4 acc[2][8];
#pragma unroll
    for (int m = 0; m < 2; ++m)
#pragma unroll
        for (int n = 0; n < 8; ++n) acc[m][n] = (f32x4){0.f, 0.f, 0.f, 0.f};

    for (int k0 = 0; k0 < 128; k0 += 32) {
        const int cb = (k0 + kq * 8) * 2;
        bf16x8 af[2];
#pragma unroll
        for (int m = 0; m < 2; ++m) {
            const int row = w * 32 + m * 16 + fr;
            af[m] = *(const bf16x8*)((char*)SA + row * 256 + (cb ^ ((row & 7) << 4)));
        }
#pragma unroll
        for (int n = 0; n < 8; ++n) {
            const int row = n * 16 + fr;
            bf16x8 bf = *(const bf16x8*)((char*)SB + row * 256 + (cb ^ ((row & 7) << 4)));
            acc[0][n] = __builtin_amdgcn_mfma_f32_16x16x32_bf16(af[0], bf, acc[0][n], 0, 0, 0);
            acc[1][n] = __builtin_amdgcn_mfma_f32_16x16x32_bf16(af[1], bf, acc[1][n], 0, 0, 0);
        }
    }
    __syncthreads();   // all Q/K reads done

    // ---- V^T -> SB via global_load_lds (linear dest, pre-swizzled source) --
    {
        const u16* vsrc = VTg + ((size_t)(b * HH + h) << 14);
#pragma unroll
        for (int i = 0; i < 8; ++i)
            glds16(vsrc + (size_t)(i * 256 + tid) * 8,
                   SB + (size_t)(i * 256 + tid) * 8);
    }

    // ---- softmax (wave-local rows; reduce over 16 consecutive lanes) ----
    const float SC = 0.08838834764831845f;   // 1/sqrt(128)
#pragma unroll
    for (int m = 0; m < 2; ++m) {
#pragma unroll
        for (int j = 0; j < 4; ++j) {
            const int t = w * 32 + m * 16 + kq * 4 + j;
            float mx = -3.0e38f;
#pragma unroll
            for (int n = 0; n < 8; ++n) {
                const int s = n * 16 + fr;
                float v = acc[m][n][j];
                v = (s <= t) ? v * SC : -3.0e38f;
                acc[m][n][j] = v;
                mx = fmaxf(mx, v);
            }
            mx = fmaxf(mx, __shfl_xor(mx, 1));
            mx = fmaxf(mx, __shfl_xor(mx, 2));
            mx = fmaxf(mx, __shfl_xor(mx, 4));
            mx = fmaxf(mx, __shfl_xor(mx, 8));
            float sum = 0.f;
#pragma unroll
            for (int n = 0; n < 8; ++n) {
                float e = __expf(acc[m][n][j] - mx);
                acc[m][n][j] = e; sum += e;
            }
            sum += __shfl_xor(sum, 1); sum += __shfl_xor(sum, 2);
            sum += __shfl_xor(sum, 4); sum += __shfl_xor(sum, 8);
            const float inv = 1.f / sum;
#pragma unroll
            for (int n = 0; n < 8; ++n) {
                const int s = n * 16 + fr;
                *(u16*)((char*)SA + t * 256 + ((s * 2) ^ ((t & 7) << 4))) =
                    f2b(acc[m][n][j] * inv);
            }
        }
    }
    __syncthreads();   // P written + V^T landed

    // ---- O = P V ----
    f32x4 oa[2][8];
#pragma unroll
    for (int m = 0; m < 2; ++m)
#pragma unroll
        for (int n = 0; n < 8; ++n) oa[m][n] = (f32x4){0.f, 0.f, 0.f, 0.f};

    for (int k0 = 0; k0 < 128; k0 += 32) {
        const int cb = (k0 + kq * 8) * 2;
        bf16x8 pa[2];
#pragma unroll
        for (int m = 0; m < 2; ++m) {
            const int row = w * 32 + m * 16 + fr;
            pa[m] = *(const bf16x8*)((char*)SA + row * 256 + (cb ^ ((row & 7) << 4)));
        }
#pragma unroll
        for (int n = 0; n < 8; ++n) {
            const int row = n * 16 + fr;
            bf16x8 vb = *(const bf16x8*)((char*)SB + row * 256 + (cb ^ ((row & 7) << 4)));
            oa[0][n] = __builtin_amdgcn_mfma_f32_16x16x32_bf16(pa[0], vb, oa[0][n], 0, 0, 0);
            oa[1][n] = __builtin_amdgcn_mfma_f32_16x16x32_bf16(pa[1], vb, oa[1][n], 0, 0, 0);
        }
    }

#pragma unroll
    for (int m = 0; m < 2; ++m)
#pragma unroll
        for (int j = 0; j < 4; ++j) {
            const int t = w * 32 + m * 16 + kq * 4 + j;
            u16* orow = Og + base + (size_t)t * DD;
#pragma unroll
            for (int n = 0; n < 8; ++n)
                orow[n * 16 + fr] = f2b(oa[m][n][j]);
        }
}

// ---------------- LayerNorm (dual fp32 + optional bf16 out) ----------------
__global__ __launch_bounds__(256)
void ln_kernel(const float* __restrict__ a, size_t a_stride,
               const float* __restrict__ badd, int b_mode,
               const float* __restrict__ g, const float* __restrict__ bb,
               float* __restrict__ out, size_t out_stride,
               u16* __restrict__ out2, size_t out2_stride)
{
    const int row = blockIdx.x;
    const int tid = threadIdx.x;
    const float* ap = a + (size_t)row * a_stride;
    float v0 = ap[tid];
    float v1 = ap[tid + 256];
    if (b_mode == 1) {
        const float* bp = badd + (size_t)row * DD;
        v0 += bp[tid]; v1 += bp[tid + 256];
    } else if (b_mode == 2) {
        const float* bp = badd + (size_t)(row / TT) * DD;
        v0 += bp[tid]; v1 += bp[tid + 256];
    }
    float s  = v0 + v1;
    float ss = v0 * v0 + v1 * v1;
#pragma unroll
    for (int off = 1; off < 64; off <<= 1) {
        s  += __shfl_xor(s, off);
        ss += __shfl_xor(ss, off);
    }
    __shared__ float sm1[4], sm2[4];
    const int wid = tid >> 6;
    if ((tid & 63) == 0) { sm1[wid] = s; sm2[wid] = ss; }
    __syncthreads();
    s  = sm1[0] + sm1[1] + sm1[2] + sm1[3];
    ss = sm2[0] + sm2[1] + sm2[2] + sm2[3];
    const float mu  = s * (1.f / DD);
    const float var = ss * (1.f / DD) - mu * mu;
    const float r   = rsqrtf(var + 1e-5f);
    const float o0 = (v0 - mu) * r * g[tid]       + bb[tid];
    const float o1 = (v1 - mu) * r * g[tid + 256] + bb[tid + 256];
    if (out) {
        float* op = out + (size_t)row * out_stride;
        op[tid] = o0; op[tid + 256] = o1;
    }
    if (out2) {
        u16* op2 = out2 + (size_t)row * out2_stride;
        op2[tid] = f2b(o0); op2[tid + 256] = f2b(o1);
    }
}

// ---------------- depthwise convs / scans ----------------
__global__ void local_conv_kernel(const float* __restrict__ x, const float* __restrict__ w,
                                  const float* __restrict__ b, u16* __restrict__ y, size_t n)
{
    size_t idx = (size_t)blockIdx.x * blockDim.x + threadIdx.x;
    if (idx >= n) return;
    int d = idx & (DD - 1);
    int t = (int)(idx >> 9) & (TT - 1);
    size_t row = idx >> 9;
    float acc = b[d];
#pragma unroll
    for (int kk = 0; kk < 4; ++kk) {
        int ts = t - 3 + kk;
        if (ts >= 0) acc += w[d * 4 + kk] * x[idx - (size_t)(3 - kk) * DD];
    }
    y[row * 1536 + d] = f2b(acc);
}

__global__ void ema_scan_kernel(const float* __restrict__ x, u16* __restrict__ y)
{
    int idx = blockIdx.x * blockDim.x + threadIdx.x;   // B*D
    if (idx >= BB * DD) return;
    int b = idx >> 9, d = idx & (DD - 1);
    const float* xp = x + (size_t)b * TT * DD + d;
    u16* yp = y + (size_t)(b * TT) * 1536 + d;
    float acc = 0.f;
    for (int t = 0; t < TT; ++t) {
        acc = 0.9f * acc + 0.1f * xp[(size_t)t * DD];
        yp[(size_t)t * 1536] = f2b(acc);
    }
}

__global__ void cumsum_kernel(const float* __restrict__ x, float* __restrict__ y)
{
    int idx = blockIdx.x * blockDim.x + threadIdx.x;   // B*D
    if (idx >= BB * DD) return;
    int b = idx >> 9, d = idx & (DD - 1);
    const float* xp = x + (size_t)b * TT * DD + d;
    float* yp = y + (size_t)b * TT * DD + d;
    float acc = 0.f;
    for (int t = 0; t < TT; ++t) {
        acc += xp[(size_t)t * DD];
        yp[(size_t)t * DD] = acc * 0.25f;   // STEP
    }
}

__global__ void deltas_act_kernel(float* __restrict__ gate, const float* __restrict__ delta,
                                  size_t n)
{
    size_t idx = (size_t)blockIdx.x * blockDim.x + threadIdx.x;
    if (idx >= n) return;
    float gv = gate[idx];
    float dv = delta[idx];
    gate[idx] = (1.f / (1.f + expf(-gv))) * tanhf(dv);
}

// ---------------------------------------------------------------------------
extern "C" void kernel_launch(void* const* d_in, const int* in_sizes, int n_in,
                              void* d_out, int out_size, void* d_ws, size_t ws_size,
                              hipStream_t stream)
{
    const float* x       = (const float*)d_in[0];
    const float* seqst   = (const float*)d_in[1];
    const float* q_w     = (const float*)d_in[2];
    const float* q_b     = (const float*)d_in[3];
    const float* k_w     = (const float*)d_in[4];
    const float* k_b     = (const float*)d_in[5];
    const float* v_w     = (const float*)d_in[6];
    const float* v_b     = (const float*)d_in[7];
    const float* o_w     = (const float*)d_in[8];
    const float* o_b     = (const float*)d_in[9];
    const float* local_w = (const float*)d_in[10];
    const float* local_b = (const float*)d_in[11];
    const float* delta_w = (const float*)d_in[12];
    const float* delta_b = (const float*)d_in[13];
    const float* gate_w  = (const float*)d_in[14];
    const float* gate_b  = (const float*)d_in[15];
    const float* dn_g    = (const float*)d_in[16];
    const float* dn_b    = (const float*)d_in[17];
    const float* ln1_g   = (const float*)d_in[18];
    const float* ln1_b   = (const float*)d_in[19];
    const float* ln2_g   = (const float*)d_in[20];
    const float* ln2_b   = (const float*)d_in[21];
    const float* ln3_g   = (const float*)d_in[22];
    const float* ln3_b   = (const float*)d_in[23];
    const float* ln4_g   = (const float*)d_in[24];
    const float* ln4_b   = (const float*)d_in[25];
    const float* seq_w   = (const float*)d_in[26];
    const float* seq_b   = (const float*)d_in[27];
    const float* ffn_w1  = (const float*)d_in[28];
    const float* ffn_b1  = (const float*)d_in[29];
    const float* ffn_w2  = (const float*)d_in[30];
    const float* ffn_b2  = (const float*)d_in[31];
    (void)in_sizes; (void)n_in; (void)out_size; (void)ws_size;

    float* out = (float*)d_out;
    char*  ws  = (char*)d_ws;
    const size_t MB = (size_t)1 << 20;

    // ---- region map (byte offsets in d_ws) ----
    u16*   xb   = (u16*)(ws + 0);            // [0,64M)
    u16*   Qb   = (u16*)(ws + 64 * MB);      // [64,128M)
    u16*   Kb   = (u16*)(ws + 128 * MB);     // [128,192M)
    u16*   VTb  = (u16*)(ws + 192 * MB);     // [192,256M): V^T swizzled tiles
    u16*   attnb = (u16*)(ws + 256 * MB);    // [256,320M)
    u16*   WSa  = (u16*)(ws + 448 * MB);     // weight scratch (6.25MB max)
    u16*   WSb  = (u16*)(ws + 456 * MB);
    float* Oo   = (float*)(ws + 0);          // [0,128M): o_out -> gate -> Fo
    u16*   Cb   = (u16*)(ws + 128 * MB);     // [128,320M): (N,1536) bf16
    float* Dl   = (float*)(ws + 320 * MB);   // [320,448M): delta -> states
    float* Sst  = Dl;
    u16*   statesb = (u16*)(ws + 0);         // [0,64M)
    u16*   ffn_inb = (u16*)(ws + 64 * MB);   // [64,128M)
    u16*   hb      = (u16*)(ws + 128 * MB);  // [128,384M): (N,2048) bf16
    float* Fo      = (float*)(ws + 0);       // [0,128M)

    float* X1     = out;
    float* tabc   = out + SLOT;
    float* tabs   = tabc + TT * 64;
    float* fstate = out + SLOT;

    auto wtrans = [&](const float* W, u16* WT, int K, int M) {
        wtrans_kernel<<<dim3(M / 32, K / 32), dim3(32, 8), 0, stream>>>(W, WT, K, M);
    };

    const size_t NE = (size_t)NROWS * DD;
    const int EB = 256;
    const int NBLK = (int)((NE + EB - 1) / EB);

    // 0. rope tables; cast x -> xb
    rope_table_kernel<<<(TT * 64 + 255) / 256, 256, 0, stream>>>(tabc, tabs);
    cast_f2b_kernel<<<(unsigned)((NE / 4 + 255) / 256), 256, 0, stream>>>(x, xb, NE / 4);

    // 1. q,k,v projections: bf16 out; V transposed+swizzled per (b,h)
    wtrans(q_w, WSa, DD, DD);
    gemm_bf16<4><<<dim3(4, 512), 256, 0, stream>>>(xb, WSa, q_b, Qb, DD, nullptr, DD, DD);
    wtrans(k_w, WSa, DD, DD);
    gemm_bf16<4><<<dim3(4, 512), 256, 0, stream>>>(xb, WSa, k_b, Kb, DD, nullptr, DD, DD);
    wtrans(v_w, WSa, DD, DD);
    gemm_bf16<5><<<dim3(4, 512), 256, 0, stream>>>(xb, WSa, v_b, VTb, 0, nullptr, DD, DD);

    // 2. fused MFMA attention (RoPE inline) -> attnb
    attn_mfma_kernel<<<dim3(HH, BB), 256, 0, stream>>>(Qb, Kb, VTb, attnb, tabc, tabs);

    // 3. o-proj -> Oo fp32
    wtrans(o_w, WSa, DD, DD);
    gemm_bf16<0><<<dim3(4, 512), 256, 0, stream>>>(attnb, WSa, o_b, Oo, DD, nullptr, DD, DD);

    // 4. x1 = LN1(x + o_out) -> X1 fp32 + Cb[:,0:512] bf16
    ln_kernel<<<NROWS, 256, 0, stream>>>(x, DD, Oo, 1, ln1_g, ln1_b, X1, DD, Cb, 1536);

    // 5. local conv -> Cb[:,512:1024] ; EMA -> Cb[:,1024:1536]
    local_conv_kernel<<<NBLK, EB, 0, stream>>>(X1, local_w, local_b, Cb + 512, NE);
    ema_scan_kernel<<<(BB * DD + 255) / 256, 256, 0, stream>>>(X1, Cb + 1024);

    // 6. gate -> Oo, delta -> Dl (single K=1536 GEMMs)
    wtrans(gate_w, WSa, 3 * DD, DD);
    gemm_bf16<0><<<dim3(4, 512), 256, 0, stream>>>(Cb, WSa, gate_b, Oo, DD, nullptr, 3 * DD, DD);
    wtrans(delta_w, WSa, 3 * DD, DD);
    gemm_bf16<0><<<dim3(4, 512), 256, 0, stream>>>(Cb, WSa, delta_b, Dl, DD, nullptr, 3 * DD, DD);

    // 7. deltas = sigmoid(gate)*tanh(delta) in-place on Oo, then LN(dn)
    deltas_act_kernel<<<NBLK, EB, 0, stream>>>(Oo, Dl, NE);
    ln_kernel<<<NROWS, 256, 0, stream>>>(Oo, DD, nullptr, 0, dn_g, dn_b, Oo, DD, nullptr, 0);

    // 8. acc = cumsum*STEP -> Sst ; states = LN3(seq + acc) in place + statesb bf16
    cumsum_kernel<<<(BB * DD + 255) / 256, 256, 0, stream>>>(Oo, Sst);
    ln_kernel<<<NROWS, 256, 0, stream>>>(Sst, DD, seqst, 2, ln3_g, ln3_b, Sst, DD, statesb, DD);

    // 9. final_state = LN4(states[:,-1,:]) -> out tail
    ln_kernel<<<BB, 256, 0, stream>>>(Sst + (size_t)(TT - 1) * DD, (size_t)TT * DD,
                                      nullptr, 0, ln4_g, ln4_b, fstate, DD, nullptr, 0);

    // 10. ffn_in = x1 + 0.3*(states@seq_w + seq_b) -> ffn_inb (bf16, fused)
    wtrans(seq_w, WSa, DD, DD);
    gemm_bf16<2><<<dim3(4, 512), 256, 0, stream>>>(statesb, WSa, seq_b, ffn_inb, DD, X1, DD, DD);

    // 11. FFN: h = gelu(ffn_in@w1+b1) -> hb ; ffn_out = h@w2+b2 -> Fo
    wtrans(ffn_w1, WSa, DD, FFD);
    wtrans(ffn_w2, WSb, FFD, DD);
    gemm_bf16<3><<<dim3(16, 512), 256, 0, stream>>>(ffn_inb, WSa, ffn_b1, hb, FFD, nullptr, DD, FFD);
    gemm_bf16<0><<<dim3(4, 512), 256, 0, stream>>>(hb, WSb, ffn_b2, Fo, DD, nullptr, FFD, DD);

    // 12. out = LN2(x1 + ffn_out) -> d_out in-place
    ln_kernel<<<NROWS, 256, 0, stream>>>(X1, DD, Fo, 1, ln2_g, ln2_b, out, DD, nullptr, 0);
}

// Round 5
// 1770.083 us; speedup vs baseline: 6.3620x; 1.1161x over previous
//
#include <hip/hip_runtime.h>
#include <cstddef>
#include <cstdint>

#define BB   512
#define TT   128
#define DD   512
#define HH   4
#define HDIM 128
#define FFD  2048
#define NROWS (BB * TT)                 // 65536 rows
#define SLOT ((size_t)NROWS * DD)       // 33554432 floats = 128 MiB

typedef unsigned short u16;
typedef __bf16 bf16x8 __attribute__((ext_vector_type(8)));
typedef float  f32x4  __attribute__((ext_vector_type(4)));

__device__ __forceinline__ u16 f2b(float x) {
    union { float f; unsigned u; } v; v.f = x;
    unsigned r = v.u + 0x7FFFu + ((v.u >> 16) & 1u);
    return (u16)(r >> 16);
}
__device__ __forceinline__ float b2f(u16 u) {
    union { unsigned u; float f; } v; v.u = (unsigned)u << 16; return v.f;
}
__device__ __forceinline__ float fast_gelu(float v) {
    float t = v * (0.7978845608028654f + 0.0356774081f * v * v);
    float e = __expf(2.f * t);
    float th = 1.f - 2.f / (e + 1.f);          // tanh(t)
    return 0.5f * v * (1.f + th);
}
__device__ __forceinline__ void glds16(const void* g, void* l) {
    __builtin_amdgcn_global_load_lds(
        (const __attribute__((address_space(1))) void*)g,
        (__attribute__((address_space(3))) void*)l, 16, 0, 0);
}

// ---------------- bf16 MFMA GEMM: 128x128 tile, 4 waves, BK=32, 2-phase ----
// A: (N,K) bf16. BT: (M,K) bf16 (= B^T). bias fp32 (M).
// MODE 0: f32 out. MODE 2: bf16 out = addsrc + 0.3*C. MODE 3: bf16 gelu(C).
// MODE 4: bf16 out. MODE 6: gate/delta interleaved -> act -> bf16 (ldc).
// MODE 7: qkv -> cols<1024 bf16 to Cout (ld 1024); cols>=1024 V^T tiles to aux.
template<int MODE>
__global__ __launch_bounds__(256)
void gemm_bf16(const u16* __restrict__ A, const u16* __restrict__ BT,
               const float* __restrict__ bias, void* __restrict__ Cout, int ldc,
               const float* __restrict__ addsrc, void* __restrict__ aux,
               int K, int M)
{
    // LDS: [buf0 A][buf0 B][buf1 A][buf1 B], 4096 u16 each = 32 KiB total.
    __shared__ u16 smem[16384];
    const int tid = threadIdx.x;
    const int gx  = gridDim.x;
    const int nwg = gx * gridDim.y;
    int orig = blockIdx.y * gx + blockIdx.x;
    if ((nwg & 7) == 0) orig = (orig & 7) * (nwg >> 3) + (orig >> 3);
    const int row0 = (orig / gx) * 128;
    const int col0 = (orig % gx) * 128;

    const int lane = tid & 63;
    const int w    = tid >> 6;
    const int wr   = (w >> 1) * 64;
    const int wc   = (w & 1) * 64;
    const int fr   = lane & 15;
    const int kg   = (lane >> 4) * 8;

    f32x4 acc[4][4];
#pragma unroll
    for (int m = 0; m < 4; ++m)
#pragma unroll
        for (int n = 0; n < 4; ++n) acc[m][n] = (f32x4){0.f, 0.f, 0.f, 0.f};

    const int srow = tid >> 2;
    const int skb  = (tid & 3) * 8;
    const u16* Ag = A  + (size_t)(row0 + srow) * K + skb;
    const u16* Bg = BT + (size_t)(col0 + srow) * K + skb;
    const int soff = srow * 32 + skb;

    auto stage = [&](int kt, int buf) {
        const int ko = kt * 32;
        u16* as = smem + buf * 8192 + soff;
        u16* bs = smem + buf * 8192 + 4096 + soff;
        glds16(Ag + ko,                  as);
        glds16(Ag + (size_t)64 * K + ko, as + 2048);
        glds16(Bg + ko,                  bs);
        glds16(Bg + (size_t)64 * K + ko, bs + 2048);
    };

    const int nk = K >> 5;
    stage(0, 0);
    for (int k = 0; k < nk; ++k) {
        if (k + 1 < nk) {
            stage(k + 1, (k + 1) & 1);
            asm volatile("s_waitcnt vmcnt(4)" ::: "memory");
        } else {
            asm volatile("s_waitcnt vmcnt(0)" ::: "memory");
        }
        __syncthreads();
        const u16* As = smem + (k & 1) * 8192;
        const u16* Bs = As + 4096;
        bf16x8 af[4], bfr[4];
#pragma unroll
        for (int m = 0; m < 4; ++m)
            af[m] = *reinterpret_cast<const bf16x8*>(&As[(wr + m * 16 + fr) * 32 + kg]);
#pragma unroll
        for (int n = 0; n < 4; ++n)
            bfr[n] = *reinterpret_cast<const bf16x8*>(&Bs[(wc + n * 16 + fr) * 32 + kg]);
#pragma unroll
        for (int m = 0; m < 4; ++m)
#pragma unroll
            for (int n = 0; n < 4; ++n)
                acc[m][n] = __builtin_amdgcn_mfma_f32_16x16x32_bf16(af[m], bfr[n], acc[m][n], 0, 0, 0);
        __syncthreads();
    }

    if constexpr (MODE == 7) {
        if (col0 >= 1024) {
            // V^T swizzled tile: Ct[dc][t] rows of 256B, byte ^= ((dc&7)<<4)
#pragma unroll
            for (int m = 0; m < 4; ++m)
#pragma unroll
                for (int j = 0; j < 4; ++j) {
                    const int tl = wr + m * 16 + (lane >> 4) * 4 + j;
#pragma unroll
                    for (int n = 0; n < 4; ++n) {
                        const int dc = wc + n * 16 + fr;
                        float v = acc[m][n][j] + bias[col0 + dc];
                        *(u16*)((char*)smem + dc * 256 + ((tl * 2) ^ ((dc & 7) << 4))) = f2b(v);
                    }
                }
            __syncthreads();
            u16* dst = (u16*)aux + ((size_t)((row0 >> 7) * 4 + ((col0 - 1024) >> 7)) << 14);
#pragma unroll
            for (int i = 0; i < 8; ++i)
                *(uint4*)(dst + (size_t)(i * 256 + tid) * 8) =
                    *(const uint4*)((char*)smem + (size_t)(i * 256 + tid) * 16);
        } else {
#pragma unroll
            for (int m = 0; m < 4; ++m)
#pragma unroll
                for (int j = 0; j < 4; ++j) {
                    const int r = row0 + wr + m * 16 + (lane >> 4) * 4 + j;
#pragma unroll
                    for (int n = 0; n < 4; ++n) {
                        const int c = col0 + wc + n * 16 + fr;
                        ((u16*)Cout)[(size_t)r * 1024 + c] = f2b(acc[m][n][j] + bias[c]);
                    }
                }
        }
    } else if constexpr (MODE == 6) {
        // interleaved gate(even col)/delta(odd col); lane pairs share rows
#pragma unroll
        for (int m = 0; m < 4; ++m)
#pragma unroll
            for (int j = 0; j < 4; ++j) {
                const int r = row0 + wr + m * 16 + (lane >> 4) * 4 + j;
#pragma unroll
                for (int n = 0; n < 4; ++n) {
                    const int c = col0 + wc + n * 16 + fr;
                    float v = acc[m][n][j] + bias[c];
                    float p = __shfl_xor(v, 1);
                    if ((fr & 1) == 0) {
                        float sg = 1.f / (1.f + __expf(-v));
                        float e  = __expf(2.f * p);
                        float th = 1.f - 2.f / (e + 1.f);
                        ((u16*)Cout)[(size_t)r * ldc + (c >> 1)] = f2b(sg * th);
                    }
                }
            }
    } else {
#pragma unroll
        for (int m = 0; m < 4; ++m) {
#pragma unroll
            for (int j = 0; j < 4; ++j) {
                const int r = row0 + wr + m * 16 + (lane >> 4) * 4 + j;
#pragma unroll
                for (int n = 0; n < 4; ++n) {
                    const int c = col0 + wc + n * 16 + fr;
                    float v = acc[m][n][j] + bias[c];
                    if constexpr (MODE == 0) {
                        ((float*)Cout)[(size_t)r * ldc + c] = v;
                    } else if constexpr (MODE == 2) {
                        ((u16*)Cout)[(size_t)r * ldc + c] =
                            f2b(addsrc[(size_t)r * M + c] + 0.3f * v);
                    } else if constexpr (MODE == 3) {
                        ((u16*)Cout)[(size_t)r * ldc + c] = f2b(fast_gelu(v));
                    } else {  // MODE 4
                        ((u16*)Cout)[(size_t)r * ldc + c] = f2b(v);
                    }
                }
            }
        }
    }
}

// ------- weight transpose+cast: W (K,M) f32 -> WT rows (m*rmul+roff) -------
__global__ __launch_bounds__(256)
void wtrans_kernel(const float* __restrict__ W, u16* __restrict__ WT, int K, int M,
                   int rmul, int roff)
{
    __shared__ float t[32][33];
    const int m0 = blockIdx.x * 32;
    const int k0 = blockIdx.y * 32;
    const int tx = threadIdx.x;
    const int ty = threadIdx.y;
#pragma unroll
    for (int i = 0; i < 4; ++i) {
        int k = ty * 4 + i;
        t[k][tx] = W[(size_t)(k0 + k) * M + m0 + tx];
    }
    __syncthreads();
#pragma unroll
    for (int i = 0; i < 4; ++i) {
        int m = ty * 4 + i;
        WT[(size_t)((m0 + m) * rmul + roff) * K + k0 + tx] = f2b(t[tx][m]);
    }
}

__global__ void cast_f2b_kernel(const float* __restrict__ in, u16* __restrict__ out, size_t n4)
{
    size_t i = (size_t)blockIdx.x * blockDim.x + threadIdx.x;
    if (i >= n4) return;
    float4 v = reinterpret_cast<const float4*>(in)[i];
    union { u16 u[4]; uint2 d; } p;
    p.u[0] = f2b(v.x); p.u[1] = f2b(v.y); p.u[2] = f2b(v.z); p.u[3] = f2b(v.w);
    reinterpret_cast<uint2*>(out)[i] = p.d;
}

__global__ void rope_table_kernel(float* __restrict__ tabc, float* __restrict__ tabs)
{
    int idx = blockIdx.x * blockDim.x + threadIdx.x;
    if (idx >= TT * 64) return;
    int t = idx >> 6, j = idx & 63;
    float invf = expf(-(float)j * (9.210340371976184f / 64.f));
    float ang  = (float)t * invf;
    tabc[idx] = cosf(ang);
    tabs[idx] = sinf(ang);
}

__global__ void bias_build_kernel(const float* qb, const float* kb, const float* vb,
                                  const float* gb, const float* db,
                                  float* qkvb, float* gdb)
{
    int i = blockIdx.x * blockDim.x + threadIdx.x;
    if (i >= 512) return;
    qkvb[i] = qb[i]; qkvb[512 + i] = kb[i]; qkvb[1024 + i] = vb[i];
    gdb[2 * i] = gb[i]; gdb[2 * i + 1] = db[i];
}

// ---------------- MFMA attention: one block per (b,h), RoPE inline ---------
// QK bf16 (b,t,1024): Q cols 0-511 (h*128+d), K cols 512-1023.
// VT bf16 pre-transposed+swizzled tiles [(b*H+h)][dc][t].
__global__ __launch_bounds__(256)
void attn_mfma_kernel(const u16* __restrict__ QKg, const u16* __restrict__ VTg,
                      u16* __restrict__ Og,
                      const float* __restrict__ tabc, const float* __restrict__ tabs)
{
    __shared__ u16 SA[128 * 128];   // Q -> P
    __shared__ u16 SB[128 * 128];   // K -> V^T
    const int h = blockIdx.x, b = blockIdx.y;
    const int tid  = threadIdx.x;
    const int lane = tid & 63;
    const int w    = tid >> 6;
    const int fr   = lane & 15;
    const int kq   = lane >> 4;
    const size_t baseq = ((size_t)(b * TT)) * 1024 + (size_t)h * HDIM;
    const size_t baseo = ((size_t)(b * TT)) * DD + (size_t)h * HDIM;

    {
        const int tg = tid >> 4;
        const int dg = tid & 15;
        const int j0 = (dg & 7) * 8;
        const bool hi = (dg & 8) != 0;
        for (int r = 0; r < 8; ++r) {
            const int t = r * 16 + tg;
            uint4 qv = *(const uint4*)(QKg + baseq + (size_t)t * 1024 + dg * 8);
            uint4 kv = *(const uint4*)(QKg + baseq + 512 + (size_t)t * 1024 + dg * 8);
            unsigned qa[4] = {qv.x, qv.y, qv.z, qv.w};
            unsigned ka[4] = {kv.x, kv.y, kv.z, kv.w};
            unsigned qb[4], kb[4];
#pragma unroll
            for (int i = 0; i < 4; ++i) {
                qb[i] = __shfl_xor((int)qa[i], 8);
                kb[i] = __shfl_xor((int)ka[i], 8);
            }
            const float* cp = tabc + t * 64 + j0;
            const float* sp = tabs + t * 64 + j0;
            u16 oq[8], ok[8];
#pragma unroll
            for (int e = 0; e < 8; ++e) {
                float fq = b2f((u16)(qa[e >> 1] >> ((e & 1) * 16)));
                float gq = b2f((u16)(qb[e >> 1] >> ((e & 1) * 16)));
                float fk = b2f((u16)(ka[e >> 1] >> ((e & 1) * 16)));
                float gk = b2f((u16)(kb[e >> 1] >> ((e & 1) * 16)));
                float c = cp[e], s = sp[e];
                oq[e] = f2b(hi ? fq * c + gq * s : fq * c - gq * s);
                ok[e] = f2b(hi ? fk * c + gk * s : fk * c - gk * s);
            }
            const int cb = (dg * 16) ^ ((t & 7) << 4);
            *(uint4*)((char*)SA + t * 256 + cb) = *(const uint4*)oq;
            *(uint4*)((char*)SB + t * 256 + cb) = *(const uint4*)ok;
        }
    }
    __syncthreads();

    f32x4 acc[2][8];
#pragma unroll
    for (int m = 0; m < 2; ++m)
#pragma unroll
        for (int n = 0; n < 8; ++n) acc[m][n] = (f32x4){0.f, 0.f, 0.f, 0.f};

    for (int k0 = 0; k0 < 128; k0 += 32) {
        const int cb = (k0 + kq * 8) * 2;
        bf16x8 af[2];
#pragma unroll
        for (int m = 0; m < 2; ++m) {
            const int row = w * 32 + m * 16 + fr;
            af[m] = *(const bf16x8*)((char*)SA + row * 256 + (cb ^ ((row & 7) << 4)));
        }
#pragma unroll
        for (int n = 0; n < 8; ++n) {
            const int row = n * 16 + fr;
            bf16x8 bf = *(const bf16x8*)((char*)SB + row * 256 + (cb ^ ((row & 7) << 4)));
            acc[0][n] = __builtin_amdgcn_mfma_f32_16x16x32_bf16(af[0], bf, acc[0][n], 0, 0, 0);
            acc[1][n] = __builtin_amdgcn_mfma_f32_16x16x32_bf16(af[1], bf, acc[1][n], 0, 0, 0);
        }
    }
    __syncthreads();

    {
        const u16* vsrc = VTg + ((size_t)(b * HH + h) << 14);
#pragma unroll
        for (int i = 0; i < 8; ++i)
            glds16(vsrc + (size_t)(i * 256 + tid) * 8,
                   SB + (size_t)(i * 256 + tid) * 8);
    }

    const float SC = 0.08838834764831845f;
#pragma unroll
    for (int m = 0; m < 2; ++m) {
#pragma unroll
        for (int j = 0; j < 4; ++j) {
            const int t = w * 32 + m * 16 + kq * 4 + j;
            float mx = -3.0e38f;
#pragma unroll
            for (int n = 0; n < 8; ++n) {
                const int s = n * 16 + fr;
                float v = acc[m][n][j];
                v = (s <= t) ? v * SC : -3.0e38f;
                acc[m][n][j] = v;
                mx = fmaxf(mx, v);
            }
            mx = fmaxf(mx, __shfl_xor(mx, 1));
            mx = fmaxf(mx, __shfl_xor(mx, 2));
            mx = fmaxf(mx, __shfl_xor(mx, 4));
            mx = fmaxf(mx, __shfl_xor(mx, 8));
            float sum = 0.f;
#pragma unroll
            for (int n = 0; n < 8; ++n) {
                float e = __expf(acc[m][n][j] - mx);
                acc[m][n][j] = e; sum += e;
            }
            sum += __shfl_xor(sum, 1); sum += __shfl_xor(sum, 2);
            sum += __shfl_xor(sum, 4); sum += __shfl_xor(sum, 8);
            const float inv = 1.f / sum;
#pragma unroll
            for (int n = 0; n < 8; ++n) {
                const int s = n * 16 + fr;
                *(u16*)((char*)SA + t * 256 + ((s * 2) ^ ((t & 7) << 4))) =
                    f2b(acc[m][n][j] * inv);
            }
        }
    }
    __syncthreads();

    f32x4 oa[2][8];
#pragma unroll
    for (int m = 0; m < 2; ++m)
#pragma unroll
        for (int n = 0; n < 8; ++n) oa[m][n] = (f32x4){0.f, 0.f, 0.f, 0.f};

    for (int k0 = 0; k0 < 128; k0 += 32) {
        const int cb = (k0 + kq * 8) * 2;
        bf16x8 pa[2];
#pragma unroll
        for (int m = 0; m < 2; ++m) {
            const int row = w * 32 + m * 16 + fr;
            pa[m] = *(const bf16x8*)((char*)SA + row * 256 + (cb ^ ((row & 7) << 4)));
        }
#pragma unroll
        for (int n = 0; n < 8; ++n) {
            const int row = n * 16 + fr;
            bf16x8 vb = *(const bf16x8*)((char*)SB + row * 256 + (cb ^ ((row & 7) << 4)));
            oa[0][n] = __builtin_amdgcn_mfma_f32_16x16x32_bf16(pa[0], vb, oa[0][n], 0, 0, 0);
            oa[1][n] = __builtin_amdgcn_mfma_f32_16x16x32_bf16(pa[1], vb, oa[1][n], 0, 0, 0);
        }
    }

#pragma unroll
    for (int m = 0; m < 2; ++m)
#pragma unroll
        for (int j = 0; j < 4; ++j) {
            const int t = w * 32 + m * 16 + kq * 4 + j;
            u16* orow = Og + baseo + (size_t)t * DD;
#pragma unroll
            for (int n = 0; n < 8; ++n)
                orow[n * 16 + fr] = f2b(oa[m][n][j]);
        }
}

// ---------------- block reduce over 512 threads (sum, sumsq) ---------------
__device__ __forceinline__ float2 blk_red512(float v, float (*red)[2], int tid)
{
    float s = v, ss = v * v;
#pragma unroll
    for (int off = 1; off < 64; off <<= 1) {
        s  += __shfl_xor(s, off);
        ss += __shfl_xor(ss, off);
    }
    if ((tid & 63) == 0) { red[tid >> 6][0] = s; red[tid >> 6][1] = ss; }
    __syncthreads();
    float S = 0.f, SS = 0.f;
#pragma unroll
    for (int w = 0; w < 8; ++w) { S += red[w][0]; SS += red[w][1]; }
    return make_float2(S, SS);
}

// ------- ln1_chain: per-batch serial LN1 + local conv + EMA ----------------
// reads x f32, o_out bf16; writes X1 f32, Cb[row*1536 + {d, 512+d, 1024+d}]
__global__ __launch_bounds__(512)
void ln1_chain_kernel(const float* __restrict__ x, const u16* __restrict__ oo,
                      const float* __restrict__ g, const float* __restrict__ bb,
                      const float* __restrict__ lw, const float* __restrict__ lb,
                      float* __restrict__ X1, u16* __restrict__ Cb)
{
    __shared__ float red[2][8][2];
    const int b = blockIdx.x, d = threadIdx.x;
    const float g_ = g[d], b_ = bb[d];
    const float w0 = lw[d * 4 + 0], w1 = lw[d * 4 + 1],
                w2 = lw[d * 4 + 2], w3 = lw[d * 4 + 3];
    const float lb_ = lb[d];
    const size_t rb = (size_t)b * TT;
    float h1 = 0.f, h2 = 0.f, h3 = 0.f, ema = 0.f;
    float v = x[(rb + 0) * DD + d] + b2f(oo[(rb + 0) * DD + d]);
    for (int t = 0; t < TT; ++t) {
        const int tn = (t < TT - 1) ? t + 1 : t;
        float vn = x[(rb + tn) * DD + d] + b2f(oo[(rb + tn) * DD + d]);
        float2 r = blk_red512(v, red[t & 1], d);
        float mu  = r.x * (1.f / DD);
        float var = r.y * (1.f / DD) - mu * mu;
        float x1v = (v - mu) * rsqrtf(var + 1e-5f) * g_ + b_;
        const size_t row = rb + t;
        X1[row * DD + d] = x1v;
        u16* crow = Cb + row * 1536;
        crow[d] = f2b(x1v);
        crow[512 + d]  = f2b(lb_ + w3 * x1v + w2 * h1 + w1 * h2 + w0 * h3);
        ema = 0.9f * ema + 0.1f * x1v;
        crow[1024 + d] = f2b(ema);
        h3 = h2; h2 = h1; h1 = x1v;
        v = vn;
    }
}

// ------- state_chain: per-batch serial LN(dn)+cumsum+LN3 (+LN4 at t=127) ---
__global__ __launch_bounds__(512)
void state_chain_kernel(const u16* __restrict__ deltasB, const float* __restrict__ seqst,
                        const float* __restrict__ dng, const float* __restrict__ dnb,
                        const float* __restrict__ g3, const float* __restrict__ b3,
                        const float* __restrict__ g4, const float* __restrict__ b4,
                        u16* __restrict__ statesb, float* __restrict__ fstate)
{
    __shared__ float red[2][8][2];
    const int b = blockIdx.x, d = threadIdx.x;
    const float gd_ = dng[d], bd_ = dnb[d], g3_ = g3[d], b3_ = b3[d];
    const float seq = seqst[(size_t)b * DD + d];
    const size_t rb = (size_t)b * TT;
    float cum = 0.f;
    float v = b2f(deltasB[(rb + 0) * DD + d]);
    for (int t = 0; t < TT; ++t) {
        const int tn = (t < TT - 1) ? t + 1 : t;
        float vn = b2f(deltasB[(rb + tn) * DD + d]);
        float2 r0 = blk_red512(v, red[0], d);
        float mu  = r0.x * (1.f / DD);
        float var = r0.y * (1.f / DD) - mu * mu;
        float nd  = (v - mu) * rsqrtf(var + 1e-5f) * gd_ + bd_;
        cum += nd;
        float sv = seq + cum * 0.25f;
        float2 r1 = blk_red512(sv, red[1], d);
        mu  = r1.x * (1.f / DD);
        var = r1.y * (1.f / DD) - mu * mu;
        float o = (sv - mu) * rsqrtf(var + 1e-5f) * g3_ + b3_;
        statesb[(rb + t) * DD + d] = f2b(o);
        if (t == TT - 1) {
            float2 r2 = blk_red512(o, red[0], d);
            float mu4  = r2.x * (1.f / DD);
            float var4 = r2.y * (1.f / DD) - mu4 * mu4;
            fstate[(size_t)b * DD + d] = (o - mu4) * rsqrtf(var4 + 1e-5f) * g4[d] + b4[d];
        }
        v = vn;
    }
}

// ---------------- final LN2 (row per block; bf16 row-add) ------------------
__global__ __launch_bounds__(256)
void ln2_kernel(const float* __restrict__ a, const u16* __restrict__ badd,
                const float* __restrict__ g, const float* __restrict__ bb,
                float* __restrict__ out)
{
    const int row = blockIdx.x;
    const int tid = threadIdx.x;
    const float* ap = a + (size_t)row * DD;
    const u16*   bp = badd + (size_t)row * DD;
    float v0 = ap[tid]       + b2f(bp[tid]);
    float v1 = ap[tid + 256] + b2f(bp[tid + 256]);
    float s  = v0 + v1;
    float ss = v0 * v0 + v1 * v1;
#pragma unroll
    for (int off = 1; off < 64; off <<= 1) {
        s  += __shfl_xor(s, off);
        ss += __shfl_xor(ss, off);
    }
    __shared__ float sm1[4], sm2[4];
    const int wid = tid >> 6;
    if ((tid & 63) == 0) { sm1[wid] = s; sm2[wid] = ss; }
    __syncthreads();
    s  = sm1[0] + sm1[1] + sm1[2] + sm1[3];
    ss = sm2[0] + sm2[1] + sm2[2] + sm2[3];
    const float mu  = s * (1.f / DD);
    const float var = ss * (1.f / DD) - mu * mu;
    const float r   = rsqrtf(var + 1e-5f);
    float* op = out + (size_t)row * DD;
    op[tid]       = (v0 - mu) * r * g[tid]       + bb[tid];
    op[tid + 256] = (v1 - mu) * r * g[tid + 256] + bb[tid + 256];
}

// ---------------------------------------------------------------------------
extern "C" void kernel_launch(void* const* d_in, const int* in_sizes, int n_in,
                              void* d_out, int out_size, void* d_ws, size_t ws_size,
                              hipStream_t stream)
{
    const float* x       = (const float*)d_in[0];
    const float* seqst   = (const float*)d_in[1];
    const float* q_w     = (const float*)d_in[2];
    const float* q_b     = (const float*)d_in[3];
    const float* k_w     = (const float*)d_in[4];
    const float* k_b     = (const float*)d_in[5];
    const float* v_w     = (const float*)d_in[6];
    const float* v_b     = (const float*)d_in[7];
    const float* o_w     = (const float*)d_in[8];
    const float* o_b     = (const float*)d_in[9];
    const float* local_w = (const float*)d_in[10];
    const float* local_b = (const float*)d_in[11];
    const float* delta_w = (const float*)d_in[12];
    const float* delta_b = (const float*)d_in[13];
    const float* gate_w  = (const float*)d_in[14];
    const float* gate_b  = (const float*)d_in[15];
    const float* dn_g    = (const float*)d_in[16];
    const float* dn_b    = (const float*)d_in[17];
    const float* ln1_g   = (const float*)d_in[18];
    const float* ln1_b   = (const float*)d_in[19];
    const float* ln2_g   = (const float*)d_in[20];
    const float* ln2_b   = (const float*)d_in[21];
    const float* ln3_g   = (const float*)d_in[22];
    const float* ln3_b   = (const float*)d_in[23];
    const float* ln4_g   = (const float*)d_in[24];
    const float* ln4_b   = (const float*)d_in[25];
    const float* seq_w   = (const float*)d_in[26];
    const float* seq_b   = (const float*)d_in[27];
    const float* ffn_w1  = (const float*)d_in[28];
    const float* ffn_b1  = (const float*)d_in[29];
    const float* ffn_w2  = (const float*)d_in[30];
    const float* ffn_b2  = (const float*)d_in[31];
    (void)in_sizes; (void)n_in; (void)out_size; (void)ws_size;

    float* out = (float*)d_out;
    char*  ws  = (char*)d_ws;
    const size_t MB = (size_t)1 << 20;

    // ---- region map (byte offsets in d_ws) ----
    u16*   xb      = (u16*)(ws + 0);          // [0,64M): x bf16 (dead after qkv)
    u16*   QKb     = (u16*)(ws + 64 * MB);    // [64,192M): (N,1024) q|k
    u16*   VTb     = (u16*)(ws + 192 * MB);   // [192,256M): V^T tiles
    u16*   attnb   = (u16*)(ws + 256 * MB);   // [256,320M)
    u16*   Oob     = (u16*)(ws + 0);          // [0,64M): o_out bf16 (over xb)
    u16*   Cb      = (u16*)(ws + 64 * MB);    // [64,256M): (N,1536) (over QK/VT)
    u16*   deltasB = (u16*)(ws + 256 * MB);   // [256,320M) (over attnb)
    u16*   statesb = (u16*)(ws + 320 * MB);   // [320,384M)
    u16*   ffn_inb = (u16*)(ws + 0);          // [0,64M) (over Oob)
    u16*   hb      = (u16*)(ws + 64 * MB);    // [64,320M): (N,2048) (over Cb+deltas)
    u16*   Fob     = (u16*)(ws + 320 * MB);   // [320,384M) (over statesb)
    u16*   WSq  = (u16*)(ws + 448 * MB);      // 1536x512  = 1.5M
    u16*   WSo  = (u16*)(ws + 450 * MB);      // 512x512   = 0.5M
    u16*   WSgd = (u16*)(ws + 451 * MB);      // 1024x1536 = 3M
    u16*   WSs  = (u16*)(ws + 455 * MB);      // 512x512
    u16*   WSf1 = (u16*)(ws + 456 * MB);      // 2048x512  = 2M
    u16*   WSf2 = (u16*)(ws + 458 * MB);      // 512x2048  = 2M
    float* qkvb = (float*)(ws + 460 * MB);    // 1536 f32
    float* gdb  = (float*)(ws + 461 * MB);    // 1024 f32

    float* X1     = out;
    float* tabc   = out + SLOT;
    float* tabs   = tabc + TT * 64;
    float* fstate = out + SLOT;

    const size_t NE = (size_t)NROWS * DD;

    // 0. tables, casts, weight prep (all independent)
    rope_table_kernel<<<(TT * 64 + 255) / 256, 256, 0, stream>>>(tabc, tabs);
    cast_f2b_kernel<<<(unsigned)((NE / 4 + 255) / 256), 256, 0, stream>>>(x, xb, NE / 4);
    bias_build_kernel<<<2, 256, 0, stream>>>(q_b, k_b, v_b, gate_b, delta_b, qkvb, gdb);
    auto wt = [&](const float* W, u16* WT, int K, int M, int rmul, int roff) {
        wtrans_kernel<<<dim3(M / 32, K / 32), dim3(32, 8), 0, stream>>>(W, WT, K, M, rmul, roff);
    };
    wt(q_w, WSq, DD, DD, 1, 0);
    wt(k_w, WSq + (size_t)512 * DD, DD, DD, 1, 0);
    wt(v_w, WSq + (size_t)1024 * DD, DD, DD, 1, 0);
    wt(o_w, WSo, DD, DD, 1, 0);
    wt(gate_w,  WSgd, 3 * DD, DD, 2, 0);
    wt(delta_w, WSgd, 3 * DD, DD, 2, 1);
    wt(seq_w, WSs, DD, DD, 1, 0);
    wt(ffn_w1, WSf1, DD, FFD, 1, 0);
    wt(ffn_w2, WSf2, FFD, DD, 1, 0);

    // 1. fused QKV GEMM (M=1536): q|k -> QKb, v -> VTb transposed tiles
    gemm_bf16<7><<<dim3(12, 512), 256, 0, stream>>>(
        xb, WSq, qkvb, QKb, 1024, nullptr, VTb, DD, 1536);

    // 2. fused MFMA attention (RoPE inline) -> attnb
    attn_mfma_kernel<<<dim3(HH, BB), 256, 0, stream>>>(QKb, VTb, attnb, tabc, tabs);

    // 3. o-proj -> Oob bf16
    gemm_bf16<4><<<dim3(4, 512), 256, 0, stream>>>(
        attnb, WSo, o_b, Oob, DD, nullptr, nullptr, DD, DD);

    // 4. ln1_chain: x1=LN1(x+o_out) -> X1 f32 + Cb[:,0:512]; conv -> Cb[:,512:1024];
    //    ema -> Cb[:,1024:1536]
    ln1_chain_kernel<<<BB, 512, 0, stream>>>(x, Oob, ln1_g, ln1_b, local_w, local_b, X1, Cb);

    // 5. fused gate/delta GEMM (M=1024 interleaved) + act -> deltasB bf16
    gemm_bf16<6><<<dim3(8, 512), 256, 0, stream>>>(
        Cb, WSgd, gdb, deltasB, DD, nullptr, nullptr, 3 * DD, 1024);

    // 6. state_chain: LN(dn) + cumsum*STEP + seq-add + LN3 -> statesb; LN4 -> fstate
    state_chain_kernel<<<BB, 512, 0, stream>>>(
        deltasB, seqst, dn_g, dn_b, ln3_g, ln3_b, ln4_g, ln4_b, statesb, fstate);

    // 7. ffn_in = x1 + 0.3*(states@seq_w + seq_b) -> ffn_inb bf16
    gemm_bf16<2><<<dim3(4, 512), 256, 0, stream>>>(
        statesb, WSs, seq_b, ffn_inb, DD, X1, nullptr, DD, DD);

    // 8. FFN: h = gelu(ffn_in@w1+b1) -> hb ; ffn_out = h@w2+b2 -> Fob bf16
    gemm_bf16<3><<<dim3(16, 512), 256, 0, stream>>>(
        ffn_inb, WSf1, ffn_b1, hb, FFD, nullptr, nullptr, DD, FFD);
    gemm_bf16<4><<<dim3(4, 512), 256, 0, stream>>>(
        hb, WSf2, ffn_b2, Fob, DD, nullptr, nullptr, FFD, DD);

    // 9. out = LN2(x1 + ffn_out) -> d_out (in place over X1)
    ln2_kernel<<<NROWS, 256, 0, stream>>>(X1, Fob, ln2_g, ln2_b, out);
}

// Round 6
// 1668.298 us; speedup vs baseline: 6.7501x; 1.0610x over previous
//
#include <hip/hip_runtime.h>
#include <cstddef>
#include <cstdint>

#define BB   512
#define TT   128
#define DD   512
#define HH   4
#define HDIM 128
#define FFD  2048
#define NROWS (BB * TT)                 // 65536 rows
#define SLOT ((size_t)NROWS * DD)       // 33554432 floats = 128 MiB

typedef unsigned short u16;
typedef __bf16 bf16x8 __attribute__((ext_vector_type(8)));
typedef float  f32x4  __attribute__((ext_vector_type(4)));

__device__ __forceinline__ u16 f2b(float x) {
    union { float f; unsigned u; } v; v.f = x;
    unsigned r = v.u + 0x7FFFu + ((v.u >> 16) & 1u);
    return (u16)(r >> 16);
}
__device__ __forceinline__ float b2f(u16 u) {
    union { unsigned u; float f; } v; v.u = (unsigned)u << 16; return v.f;
}
__device__ __forceinline__ float fast_gelu(float v) {
    float t = v * (0.7978845608028654f + 0.0356774081f * v * v);
    float e = __expf(2.f * t);
    float th = 1.f - 2.f / (e + 1.f);          // tanh(t)
    return 0.5f * v * (1.f + th);
}
__device__ __forceinline__ void glds16(const void* g, void* l) {
    __builtin_amdgcn_global_load_lds(
        (const __attribute__((address_space(1))) void*)g,
        (__attribute__((address_space(3))) void*)l, 16, 0, 0);
}

#define PH_BAR() do { __builtin_amdgcn_sched_barrier(0); \
                      __builtin_amdgcn_s_barrier(); \
                      __builtin_amdgcn_sched_barrier(0); } while (0)

// ============ 256x256 8-phase bf16 GEMM (T1+T2+T3+T4+T5) ====================
// A: (N,K) bf16. BT: (M,K) bf16 (=B^T). bias f32 (M). 512 thr, 8 waves (2Mx4N),
// BK=64 split into 2 k-slabs of 32; LDS 128 KiB: A/B x dbuf x kslab (16 KiB).
// st_16x32 swizzle: byte L ^= ((L>>9)&1)<<5; staging via inverse-swizzled
// global source + linear global_load_lds dest (involution on 16B chunks).
// MODE 2: bf16 = addsrc + 0.3*C. MODE 3: bf16 gelu(C). MODE 4: bf16 C.
// MODE 6: gate/delta interleaved -> sigmoid*tanh -> bf16 at col c>>1.
template<int MODE>
__global__ __launch_bounds__(512, 2)
void gemm256(const u16* __restrict__ A, const u16* __restrict__ BT,
             const float* __restrict__ bias, void* __restrict__ Cout, int ldc,
             const float* __restrict__ addsrc, int K, int M)
{
    __shared__ u16 S[65536];   // 128 KiB
    const int tid = threadIdx.x;
    const int gx  = gridDim.x;               // M/256
    const int nwg = gx * gridDim.y;
    int orig = blockIdx.y * gx + blockIdx.x;
    orig = (orig & 7) * (nwg >> 3) + (orig >> 3);   // XCD swizzle (nwg%8==0)
    const int row0 = (orig / gx) * 256;
    const int col0 = (orig % gx) * 256;

    const int lane = tid & 63;
    const int wid  = tid >> 6;
    const int wm   = wid >> 2;       // row half (0/1)
    const int wn   = wid & 3;        // col quarter (0..3)
    const int fr   = lane & 15;
    const int kq   = lane >> 4;      // 0..3

    // ---- staging constants: phys chunk c -> logical l = c ^ (((c>>5)&1)<<1)
    const int c0 = wid * 128 + lane;
    const int c1 = c0 + 64;
    const int l0 = c0 ^ (((c0 >> 5) & 1) << 1);
    const int l1 = c1 ^ (((c1 >> 5) & 1) << 1);
    const int sr0 = l0 >> 2, sk0 = (l0 & 3) * 8;   // slab row, k-elem offset
    const int sr1 = l1 >> 2, sk1 = (l1 & 3) * 8;
    const u16* ApG = A  + (size_t)row0 * K;
    const u16* BpG = BT + (size_t)col0 * K;

    // slab LDS bases: A: ((p*2+kh)*16384); B: +65536 (bytes)
    auto stA = [&](int kt, int kh) {
        char* slot = (char*)S + ((((kt & 1) << 1) + kh) << 14);
        const u16* g = ApG + kt * 64 + kh * 32;
        glds16(g + (size_t)sr0 * K + sk0, slot + c0 * 16);
        glds16(g + (size_t)sr1 * K + sk1, slot + c1 * 16);
    };
    auto stB = [&](int kt, int kh) {
        char* slot = (char*)S + 65536 + ((((kt & 1) << 1) + kh) << 14);
        const u16* g = BpG + kt * 64 + kh * 32;
        glds16(g + (size_t)sr0 * K + sk0, slot + c0 * 16);
        glds16(g + (size_t)sr1 * K + sk1, slot + c1 * 16);
    };
    // frag reads (swizzled): logical L = row*64 + kq*16, phys ^= ((row>>3)&1)<<5
    auto rdA = [&](int p, int kh, int m) -> bf16x8 {
        const int row = wm * 128 + m * 16 + fr;
        const int L = (row * 64 + kq * 16) ^ (((row >> 3) & 1) << 5);
        return *(const bf16x8*)((char*)S + (((p << 1) + kh) << 14) + L);
    };
    auto rdB = [&](int p, int kh, int n) -> bf16x8 {
        const int col = wn * 64 + n * 16 + fr;
        const int L = (col * 64 + kq * 16) ^ (((col >> 3) & 1) << 5);
        return *(const bf16x8*)((char*)S + 65536 + (((p << 1) + kh) << 14) + L);
    };

    f32x4 acc[8][4];
#pragma unroll
    for (int m = 0; m < 8; ++m)
#pragma unroll
        for (int n = 0; n < 4; ++n) acc[m][n] = (f32x4){0.f, 0.f, 0.f, 0.f};

    const int NKT = K >> 6;     // K-tiles of 64 (NKT >= 2)

    // ---- prologue: tile0 (4 slabs) + 3 slabs of tile1; vmcnt(6) keeps 3 ----
    stA(0, 0); stA(0, 1); stB(0, 0); stB(0, 1);
    stB(1, 0); stA(1, 0); stB(1, 1);
    asm volatile("s_waitcnt vmcnt(6)" ::: "memory");
    __builtin_amdgcn_s_barrier();

    bf16x8 b0, b1, b2, b3;
#define MFMA16(MH, A0, A1, A2, A3)                                              \
    do {                                                                        \
        __builtin_amdgcn_s_setprio(1);                                          \
        bf16x8 aa_[4] = {A0, A1, A2, A3};                                       \
        bf16x8 bb_[4] = {b0, b1, b2, b3};                                       \
        _Pragma("unroll")                                                       \
        for (int m_ = 0; m_ < 4; ++m_)                                          \
            _Pragma("unroll")                                                   \
            for (int n_ = 0; n_ < 4; ++n_)                                      \
                acc[(MH) * 4 + m_][n_] = __builtin_amdgcn_mfma_f32_16x16x32_bf16( \
                    aa_[m_], bb_[n_], acc[(MH) * 4 + m_][n_], 0, 0, 0);         \
        __builtin_amdgcn_s_setprio(0);                                          \
    } while (0)

    for (int kt = 0; kt < NKT; ++kt) {
        const int p = kt & 1;
        const bool s1 = (kt + 1 < NKT);
        const bool s2 = (kt + 2 < NKT);
        // ---- ph1: A[p][k0] m0-3 + B[p][k0]; stage A(kt+1,k1) ----
        {
            bf16x8 a0 = rdA(p, 0, 0), a1 = rdA(p, 0, 1), a2 = rdA(p, 0, 2), a3 = rdA(p, 0, 3);
            b0 = rdB(p, 0, 0); b1 = rdB(p, 0, 1); b2 = rdB(p, 0, 2); b3 = rdB(p, 0, 3);
            if (s1) stA(kt + 1, 1);
            PH_BAR();
            MFMA16(0, a0, a1, a2, a3);
            PH_BAR();
        }
        // ---- ph2: A[p][k0] m4-7; stage B(kt+2,k0) ----
        {
            bf16x8 a0 = rdA(p, 0, 4), a1 = rdA(p, 0, 5), a2 = rdA(p, 0, 6), a3 = rdA(p, 0, 7);
            if (s2) stB(kt + 2, 0);
            PH_BAR();
            MFMA16(1, a0, a1, a2, a3);
            PH_BAR();
        }
        // ---- ph3: A[p][k1] m0-3 + B[p][k1]; stage A(kt+2,k0) ----
        {
            bf16x8 a0 = rdA(p, 1, 0), a1 = rdA(p, 1, 1), a2 = rdA(p, 1, 2), a3 = rdA(p, 1, 3);
            b0 = rdB(p, 1, 0); b1 = rdB(p, 1, 1); b2 = rdB(p, 1, 2); b3 = rdB(p, 1, 3);
            if (s2) stA(kt + 2, 0);
            PH_BAR();
            MFMA16(0, a0, a1, a2, a3);
            PH_BAR();
        }
        // ---- ph4: A[p][k1] m4-7; stage B(kt+2,k1); counted vmcnt ----
        {
            bf16x8 a0 = rdA(p, 1, 4), a1 = rdA(p, 1, 5), a2 = rdA(p, 1, 6), a3 = rdA(p, 1, 7);
            if (s2) stB(kt + 2, 1);
            PH_BAR();
            MFMA16(1, a0, a1, a2, a3);
            if (s2)      asm volatile("s_waitcnt vmcnt(6)" ::: "memory");
            else if (s1) asm volatile("s_waitcnt vmcnt(0)" ::: "memory");
            PH_BAR();
        }
    }
#undef MFMA16

    // ---- epilogue ----
#pragma unroll
    for (int m = 0; m < 8; ++m) {
#pragma unroll
        for (int jj = 0; jj < 4; ++jj) {
            const int r = row0 + wm * 128 + m * 16 + kq * 4 + jj;
#pragma unroll
            for (int n = 0; n < 4; ++n) {
                const int c = col0 + wn * 64 + n * 16 + fr;
                float v = acc[m][n][jj] + bias[c];
                if constexpr (MODE == 2) {
                    ((u16*)Cout)[(size_t)r * ldc + c] =
                        f2b(addsrc[(size_t)r * M + c] + 0.3f * v);
                } else if constexpr (MODE == 3) {
                    ((u16*)Cout)[(size_t)r * ldc + c] = f2b(fast_gelu(v));
                } else if constexpr (MODE == 6) {
                    float pth = __shfl_xor(v, 1);
                    if ((fr & 1) == 0) {
                        float sg = 1.f / (1.f + __expf(-v));
                        float e  = __expf(2.f * pth);
                        float th = 1.f - 2.f / (e + 1.f);
                        ((u16*)Cout)[(size_t)r * ldc + (c >> 1)] = f2b(sg * th);
                    }
                } else {  // MODE 4
                    ((u16*)Cout)[(size_t)r * ldc + c] = f2b(v);
                }
            }
        }
    }
}

// ---------------- 128x128 bf16 GEMM (QKV only, MODE 7) ---------------------
template<int MODE>
__global__ __launch_bounds__(256)
void gemm_bf16(const u16* __restrict__ A, const u16* __restrict__ BT,
               const float* __restrict__ bias, void* __restrict__ Cout, int ldc,
               const float* __restrict__ addsrc, void* __restrict__ aux,
               int K, int M)
{
    __shared__ u16 smem[16384];
    const int tid = threadIdx.x;
    const int gx  = gridDim.x;
    const int nwg = gx * gridDim.y;
    int orig = blockIdx.y * gx + blockIdx.x;
    if ((nwg & 7) == 0) orig = (orig & 7) * (nwg >> 3) + (orig >> 3);
    const int row0 = (orig / gx) * 128;
    const int col0 = (orig % gx) * 128;

    const int lane = tid & 63;
    const int w    = tid >> 6;
    const int wr   = (w >> 1) * 64;
    const int wc   = (w & 1) * 64;
    const int fr   = lane & 15;
    const int kg   = (lane >> 4) * 8;

    f32x4 acc[4][4];
#pragma unroll
    for (int m = 0; m < 4; ++m)
#pragma unroll
        for (int n = 0; n < 4; ++n) acc[m][n] = (f32x4){0.f, 0.f, 0.f, 0.f};

    const int srow = tid >> 2;
    const int skb  = (tid & 3) * 8;
    const u16* Ag = A  + (size_t)(row0 + srow) * K + skb;
    const u16* Bg = BT + (size_t)(col0 + srow) * K + skb;
    const int soff = srow * 32 + skb;

    auto stage = [&](int kt, int buf) {
        const int ko = kt * 32;
        u16* as = smem + buf * 8192 + soff;
        u16* bs = smem + buf * 8192 + 4096 + soff;
        glds16(Ag + ko,                  as);
        glds16(Ag + (size_t)64 * K + ko, as + 2048);
        glds16(Bg + ko,                  bs);
        glds16(Bg + (size_t)64 * K + ko, bs + 2048);
    };

    const int nk = K >> 5;
    stage(0, 0);
    for (int k = 0; k < nk; ++k) {
        if (k + 1 < nk) {
            stage(k + 1, (k + 1) & 1);
            asm volatile("s_waitcnt vmcnt(4)" ::: "memory");
        } else {
            asm volatile("s_waitcnt vmcnt(0)" ::: "memory");
        }
        __syncthreads();
        const u16* As = smem + (k & 1) * 8192;
        const u16* Bs = As + 4096;
        bf16x8 af[4], bfr[4];
#pragma unroll
        for (int m = 0; m < 4; ++m)
            af[m] = *reinterpret_cast<const bf16x8*>(&As[(wr + m * 16 + fr) * 32 + kg]);
#pragma unroll
        for (int n = 0; n < 4; ++n)
            bfr[n] = *reinterpret_cast<const bf16x8*>(&Bs[(wc + n * 16 + fr) * 32 + kg]);
#pragma unroll
        for (int m = 0; m < 4; ++m)
#pragma unroll
            for (int n = 0; n < 4; ++n)
                acc[m][n] = __builtin_amdgcn_mfma_f32_16x16x32_bf16(af[m], bfr[n], acc[m][n], 0, 0, 0);
        __syncthreads();
    }

    if constexpr (MODE == 7) {
        if (col0 >= 1024) {
            // V^T swizzled tile: Ct[dc][t] rows of 256B, byte ^= ((dc&7)<<4)
#pragma unroll
            for (int m = 0; m < 4; ++m)
#pragma unroll
                for (int j = 0; j < 4; ++j) {
                    const int tl = wr + m * 16 + (lane >> 4) * 4 + j;
#pragma unroll
                    for (int n = 0; n < 4; ++n) {
                        const int dc = wc + n * 16 + fr;
                        float v = acc[m][n][j] + bias[col0 + dc];
                        *(u16*)((char*)smem + dc * 256 + ((tl * 2) ^ ((dc & 7) << 4))) = f2b(v);
                    }
                }
            __syncthreads();
            u16* dst = (u16*)aux + ((size_t)((row0 >> 7) * 4 + ((col0 - 1024) >> 7)) << 14);
#pragma unroll
            for (int i = 0; i < 8; ++i)
                *(uint4*)(dst + (size_t)(i * 256 + tid) * 8) =
                    *(const uint4*)((char*)smem + (size_t)(i * 256 + tid) * 16);
        } else {
#pragma unroll
            for (int m = 0; m < 4; ++m)
#pragma unroll
                for (int j = 0; j < 4; ++j) {
                    const int r = row0 + wr + m * 16 + (lane >> 4) * 4 + j;
#pragma unroll
                    for (int n = 0; n < 4; ++n) {
                        const int c = col0 + wc + n * 16 + fr;
                        ((u16*)Cout)[(size_t)r * 1024 + c] = f2b(acc[m][n][j] + bias[c]);
                    }
                }
        }
    }
    (void)ldc; (void)addsrc;
}

// ------- weight transpose+cast: W (K,M) f32 -> WT rows (m*rmul+roff) -------
__global__ __launch_bounds__(256)
void wtrans_kernel(const float* __restrict__ W, u16* __restrict__ WT, int K, int M,
                   int rmul, int roff)
{
    __shared__ float t[32][33];
    const int m0 = blockIdx.x * 32;
    const int k0 = blockIdx.y * 32;
    const int tx = threadIdx.x;
    const int ty = threadIdx.y;
#pragma unroll
    for (int i = 0; i < 4; ++i) {
        int k = ty * 4 + i;
        t[k][tx] = W[(size_t)(k0 + k) * M + m0 + tx];
    }
    __syncthreads();
#pragma unroll
    for (int i = 0; i < 4; ++i) {
        int m = ty * 4 + i;
        WT[(size_t)((m0 + m) * rmul + roff) * K + k0 + tx] = f2b(t[tx][m]);
    }
}

__global__ void cast_f2b_kernel(const float* __restrict__ in, u16* __restrict__ out, size_t n4)
{
    size_t i = (size_t)blockIdx.x * blockDim.x + threadIdx.x;
    if (i >= n4) return;
    float4 v = reinterpret_cast<const float4*>(in)[i];
    union { u16 u[4]; uint2 d; } p;
    p.u[0] = f2b(v.x); p.u[1] = f2b(v.y); p.u[2] = f2b(v.z); p.u[3] = f2b(v.w);
    reinterpret_cast<uint2*>(out)[i] = p.d;
}

__global__ void rope_table_kernel(float* __restrict__ tabc, float* __restrict__ tabs)
{
    int idx = blockIdx.x * blockDim.x + threadIdx.x;
    if (idx >= TT * 64) return;
    int t = idx >> 6, j = idx & 63;
    float invf = expf(-(float)j * (9.210340371976184f / 64.f));
    float ang  = (float)t * invf;
    tabc[idx] = cosf(ang);
    tabs[idx] = sinf(ang);
}

__global__ void bias_build_kernel(const float* qb, const float* kb, const float* vb,
                                  const float* gb, const float* db,
                                  float* qkvb, float* gdb)
{
    int i = blockIdx.x * blockDim.x + threadIdx.x;
    if (i >= 512) return;
    qkvb[i] = qb[i]; qkvb[512 + i] = kb[i]; qkvb[1024 + i] = vb[i];
    gdb[2 * i] = gb[i]; gdb[2 * i + 1] = db[i];
}

// ---------------- MFMA attention: one block per (b,h), RoPE inline ---------
__global__ __launch_bounds__(256)
void attn_mfma_kernel(const u16* __restrict__ QKg, const u16* __restrict__ VTg,
                      u16* __restrict__ Og,
                      const float* __restrict__ tabc, const float* __restrict__ tabs)
{
    __shared__ u16 SA[128 * 128];   // Q -> P
    __shared__ u16 SB[128 * 128];   // K -> V^T
    const int h = blockIdx.x, b = blockIdx.y;
    const int tid  = threadIdx.x;
    const int lane = tid & 63;
    const int w    = tid >> 6;
    const int fr   = lane & 15;
    const int kq   = lane >> 4;
    const size_t baseq = ((size_t)(b * TT)) * 1024 + (size_t)h * HDIM;
    const size_t baseo = ((size_t)(b * TT)) * DD + (size_t)h * HDIM;

    {
        const int tg = tid >> 4;
        const int dg = tid & 15;
        const int j0 = (dg & 7) * 8;
        const bool hi = (dg & 8) != 0;
        for (int r = 0; r < 8; ++r) {
            const int t = r * 16 + tg;
            uint4 qv = *(const uint4*)(QKg + baseq + (size_t)t * 1024 + dg * 8);
            uint4 kv = *(const uint4*)(QKg + baseq + 512 + (size_t)t * 1024 + dg * 8);
            unsigned qa[4] = {qv.x, qv.y, qv.z, qv.w};
            unsigned ka[4] = {kv.x, kv.y, kv.z, kv.w};
            unsigned qb[4], kb[4];
#pragma unroll
            for (int i = 0; i < 4; ++i) {
                qb[i] = __shfl_xor((int)qa[i], 8);
                kb[i] = __shfl_xor((int)ka[i], 8);
            }
            const float* cp = tabc + t * 64 + j0;
            const float* sp = tabs + t * 64 + j0;
            u16 oq[8], ok[8];
#pragma unroll
            for (int e = 0; e < 8; ++e) {
                float fq = b2f((u16)(qa[e >> 1] >> ((e & 1) * 16)));
                float gq = b2f((u16)(qb[e >> 1] >> ((e & 1) * 16)));
                float fk = b2f((u16)(ka[e >> 1] >> ((e & 1) * 16)));
                float gk = b2f((u16)(kb[e >> 1] >> ((e & 1) * 16)));
                float c = cp[e], s = sp[e];
                oq[e] = f2b(hi ? fq * c + gq * s : fq * c - gq * s);
                ok[e] = f2b(hi ? fk * c + gk * s : fk * c - gk * s);
            }
            const int cb = (dg * 16) ^ ((t & 7) << 4);
            *(uint4*)((char*)SA + t * 256 + cb) = *(const uint4*)oq;
            *(uint4*)((char*)SB + t * 256 + cb) = *(const uint4*)ok;
        }
    }
    __syncthreads();

    f32x4 acc[2][8];
#pragma unroll
    for (int m = 0; m < 2; ++m)
#pragma unroll
        for (int n = 0; n < 8; ++n) acc[m][n] = (f32x4){0.f, 0.f, 0.f, 0.f};

    for (int k0 = 0; k0 < 128; k0 += 32) {
        const int cb = (k0 + kq * 8) * 2;
        bf16x8 af[2];
#pragma unroll
        for (int m = 0; m < 2; ++m) {
            const int row = w * 32 + m * 16 + fr;
            af[m] = *(const bf16x8*)((char*)SA + row * 256 + (cb ^ ((row & 7) << 4)));
        }
#pragma unroll
        for (int n = 0; n < 8; ++n) {
            const int row = n * 16 + fr;
            bf16x8 bf = *(const bf16x8*)((char*)SB + row * 256 + (cb ^ ((row & 7) << 4)));
            acc[0][n] = __builtin_amdgcn_mfma_f32_16x16x32_bf16(af[0], bf, acc[0][n], 0, 0, 0);
            acc[1][n] = __builtin_amdgcn_mfma_f32_16x16x32_bf16(af[1], bf, acc[1][n], 0, 0, 0);
        }
    }
    __syncthreads();

    {
        const u16* vsrc = VTg + ((size_t)(b * HH + h) << 14);
#pragma unroll
        for (int i = 0; i < 8; ++i)
            glds16(vsrc + (size_t)(i * 256 + tid) * 8,
                   SB + (size_t)(i * 256 + tid) * 8);
    }

    const float SC = 0.08838834764831845f;
#pragma unroll
    for (int m = 0; m < 2; ++m) {
#pragma unroll
        for (int j = 0; j < 4; ++j) {
            const int t = w * 32 + m * 16 + kq * 4 + j;
            float mx = -3.0e38f;
#pragma unroll
            for (int n = 0; n < 8; ++n) {
                const int s = n * 16 + fr;
                float v = acc[m][n][j];
                v = (s <= t) ? v * SC : -3.0e38f;
                acc[m][n][j] = v;
                mx = fmaxf(mx, v);
            }
            mx = fmaxf(mx, __shfl_xor(mx, 1));
            mx = fmaxf(mx, __shfl_xor(mx, 2));
            mx = fmaxf(mx, __shfl_xor(mx, 4));
            mx = fmaxf(mx, __shfl_xor(mx, 8));
            float sum = 0.f;
#pragma unroll
            for (int n = 0; n < 8; ++n) {
                float e = __expf(acc[m][n][j] - mx);
                acc[m][n][j] = e; sum += e;
            }
            sum += __shfl_xor(sum, 1); sum += __shfl_xor(sum, 2);
            sum += __shfl_xor(sum, 4); sum += __shfl_xor(sum, 8);
            const float inv = 1.f / sum;
#pragma unroll
            for (int n = 0; n < 8; ++n) {
                const int s = n * 16 + fr;
                *(u16*)((char*)SA + t * 256 + ((s * 2) ^ ((t & 7) << 4))) =
                    f2b(acc[m][n][j] * inv);
            }
        }
    }
    __syncthreads();

    f32x4 oa[2][8];
#pragma unroll
    for (int m = 0; m < 2; ++m)
#pragma unroll
        for (int n = 0; n < 8; ++n) oa[m][n] = (f32x4){0.f, 0.f, 0.f, 0.f};

    for (int k0 = 0; k0 < 128; k0 += 32) {
        const int cb = (k0 + kq * 8) * 2;
        bf16x8 pa[2];
#pragma unroll
        for (int m = 0; m < 2; ++m) {
            const int row = w * 32 + m * 16 + fr;
            pa[m] = *(const bf16x8*)((char*)SA + row * 256 + (cb ^ ((row & 7) << 4)));
        }
#pragma unroll
        for (int n = 0; n < 8; ++n) {
            const int row = n * 16 + fr;
            bf16x8 vb = *(const bf16x8*)((char*)SB + row * 256 + (cb ^ ((row & 7) << 4)));
            oa[0][n] = __builtin_amdgcn_mfma_f32_16x16x32_bf16(pa[0], vb, oa[0][n], 0, 0, 0);
            oa[1][n] = __builtin_amdgcn_mfma_f32_16x16x32_bf16(pa[1], vb, oa[1][n], 0, 0, 0);
        }
    }

#pragma unroll
    for (int m = 0; m < 2; ++m)
#pragma unroll
        for (int j = 0; j < 4; ++j) {
            const int t = w * 32 + m * 16 + kq * 4 + j;
            u16* orow = Og + baseo + (size_t)t * DD;
#pragma unroll
            for (int n = 0; n < 8; ++n)
                orow[n * 16 + fr] = f2b(oa[m][j * 0 + n][j] * 0.f + oa[m][n][j]);
        }
}

// ---------------- block reduce over 512 threads (sum, sumsq) ---------------
__device__ __forceinline__ float2 blk_red512(float v, float (*red)[2], int tid)
{
    float s = v, ss = v * v;
#pragma unroll
    for (int off = 1; off < 64; off <<= 1) {
        s  += __shfl_xor(s, off);
        ss += __shfl_xor(ss, off);
    }
    if ((tid & 63) == 0) { red[tid >> 6][0] = s; red[tid >> 6][1] = ss; }
    __syncthreads();
    float S = 0.f, SS = 0.f;
#pragma unroll
    for (int w = 0; w < 8; ++w) { S += red[w][0]; SS += red[w][1]; }
    return make_float2(S, SS);
}

// ------- ln1_chain: per-batch serial LN1 + local conv + EMA ----------------
__global__ __launch_bounds__(512)
void ln1_chain_kernel(const float* __restrict__ x, const u16* __restrict__ oo,
                      const float* __restrict__ g, const float* __restrict__ bb,
                      const float* __restrict__ lw, const float* __restrict__ lb,
                      float* __restrict__ X1, u16* __restrict__ Cb)
{
    __shared__ float red[2][8][2];
    const int b = blockIdx.x, d = threadIdx.x;
    const float g_ = g[d], b_ = bb[d];
    const float w0 = lw[d * 4 + 0], w1 = lw[d * 4 + 1],
                w2 = lw[d * 4 + 2], w3 = lw[d * 4 + 3];
    const float lb_ = lb[d];
    const size_t rb = (size_t)b * TT;
    float h1 = 0.f, h2 = 0.f, h3 = 0.f, ema = 0.f;
    float v = x[(rb + 0) * DD + d] + b2f(oo[(rb + 0) * DD + d]);
    for (int t = 0; t < TT; ++t) {
        const int tn = (t < TT - 1) ? t + 1 : t;
        float vn = x[(rb + tn) * DD + d] + b2f(oo[(rb + tn) * DD + d]);
        float2 r = blk_red512(v, red[t & 1], d);
        float mu  = r.x * (1.f / DD);
        float var = r.y * (1.f / DD) - mu * mu;
        float x1v = (v - mu) * rsqrtf(var + 1e-5f) * g_ + b_;
        const size_t row = rb + t;
        X1[row * DD + d] = x1v;
        u16* crow = Cb + row * 1536;
        crow[d] = f2b(x1v);
        crow[512 + d]  = f2b(lb_ + w3 * x1v + w2 * h1 + w1 * h2 + w0 * h3);
        ema = 0.9f * ema + 0.1f * x1v;
        crow[1024 + d] = f2b(ema);
        h3 = h2; h2 = h1; h1 = x1v;
        v = vn;
    }
}

// ------- state_chain: per-batch serial LN(dn)+cumsum+LN3 (+LN4 at t=127) ---
__global__ __launch_bounds__(512)
void state_chain_kernel(const u16* __restrict__ deltasB, const float* __restrict__ seqst,
                        const float* __restrict__ dng, const float* __restrict__ dnb,
                        const float* __restrict__ g3, const float* __restrict__ b3,
                        const float* __restrict__ g4, const float* __restrict__ b4,
                        u16* __restrict__ statesb, float* __restrict__ fstate)
{
    __shared__ float red[2][8][2];
    const int b = blockIdx.x, d = threadIdx.x;
    const float gd_ = dng[d], bd_ = dnb[d], g3_ = g3[d], b3_ = b3[d];
    const float seq = seqst[(size_t)b * DD + d];
    const size_t rb = (size_t)b * TT;
    float cum = 0.f;
    float v = b2f(deltasB[(rb + 0) * DD + d]);
    for (int t = 0; t < TT; ++t) {
        const int tn = (t < TT - 1) ? t + 1 : t;
        float vn = b2f(deltasB[(rb + tn) * DD + d]);
        float2 r0 = blk_red512(v, red[0], d);
        float mu  = r0.x * (1.f / DD);
        float var = r0.y * (1.f / DD) - mu * mu;
        float nd  = (v - mu) * rsqrtf(var + 1e-5f) * gd_ + bd_;
        cum += nd;
        float sv = seq + cum * 0.25f;
        float2 r1 = blk_red512(sv, red[1], d);
        mu  = r1.x * (1.f / DD);
        var = r1.y * (1.f / DD) - mu * mu;
        float o = (sv - mu) * rsqrtf(var + 1e-5f) * g3_ + b3_;
        statesb[(rb + t) * DD + d] = f2b(o);
        if (t == TT - 1) {
            float2 r2 = blk_red512(o, red[0], d);
            float mu4  = r2.x * (1.f / DD);
            float var4 = r2.y * (1.f / DD) - mu4 * mu4;
            fstate[(size_t)b * DD + d] = (o - mu4) * rsqrtf(var4 + 1e-5f) * g4[d] + b4[d];
        }
        v = vn;
    }
}

// ---------------- final LN2 (row per block; bf16 row-add) ------------------
__global__ __launch_bounds__(256)
void ln2_kernel(const float* __restrict__ a, const u16* __restrict__ badd,
                const float* __restrict__ g, const float* __restrict__ bb,
                float* __restrict__ out)
{
    const int row = blockIdx.x;
    const int tid = threadIdx.x;
    const float* ap = a + (size_t)row * DD;
    const u16*   bp = badd + (size_t)row * DD;
    float v0 = ap[tid]       + b2f(bp[tid]);
    float v1 = ap[tid + 256] + b2f(bp[tid + 256]);
    float s  = v0 + v1;
    float ss = v0 * v0 + v1 * v1;
#pragma unroll
    for (int off = 1; off < 64; off <<= 1) {
        s  += __shfl_xor(s, off);
        ss += __shfl_xor(ss, off);
    }
    __shared__ float sm1[4], sm2[4];
    const int wid = tid >> 6;
    if ((tid & 63) == 0) { sm1[wid] = s; sm2[wid] = ss; }
    __syncthreads();
    s  = sm1[0] + sm1[1] + sm1[2] + sm1[3];
    ss = sm2[0] + sm2[1] + sm2[2] + sm2[3];
    const float mu  = s * (1.f / DD);
    const float var = ss * (1.f / DD) - mu * mu;
    const float r   = rsqrtf(var + 1e-5f);
    float* op = out + (size_t)row * DD;
    op[tid]       = (v0 - mu) * r * g[tid]       + bb[tid];
    op[tid + 256] = (v1 - mu) * r * g[tid + 256] + bb[tid + 256];
}

// ---------------------------------------------------------------------------
extern "C" void kernel_launch(void* const* d_in, const int* in_sizes, int n_in,
                              void* d_out, int out_size, void* d_ws, size_t ws_size,
                              hipStream_t stream)
{
    const float* x       = (const float*)d_in[0];
    const float* seqst   = (const float*)d_in[1];
    const float* q_w     = (const float*)d_in[2];
    const float* q_b     = (const float*)d_in[3];
    const float* k_w     = (const float*)d_in[4];
    const float* k_b     = (const float*)d_in[5];
    const float* v_w     = (const float*)d_in[6];
    const float* v_b     = (const float*)d_in[7];
    const float* o_w     = (const float*)d_in[8];
    const float* o_b     = (const float*)d_in[9];
    const float* local_w = (const float*)d_in[10];
    const float* local_b = (const float*)d_in[11];
    const float* delta_w = (const float*)d_in[12];
    const float* delta_b = (const float*)d_in[13];
    const float* gate_w  = (const float*)d_in[14];
    const float* gate_b  = (const float*)d_in[15];
    const float* dn_g    = (const float*)d_in[16];
    const float* dn_b    = (const float*)d_in[17];
    const float* ln1_g   = (const float*)d_in[18];
    const float* ln1_b   = (const float*)d_in[19];
    const float* ln2_g   = (const float*)d_in[20];
    const float* ln2_b   = (const float*)d_in[21];
    const float* ln3_g   = (const float*)d_in[22];
    const float* ln3_b   = (const float*)d_in[23];
    const float* ln4_g   = (const float*)d_in[24];
    const float* ln4_b   = (const float*)d_in[25];
    const float* seq_w   = (const float*)d_in[26];
    const float* seq_b   = (const float*)d_in[27];
    const float* ffn_w1  = (const float*)d_in[28];
    const float* ffn_b1  = (const float*)d_in[29];
    const float* ffn_w2  = (const float*)d_in[30];
    const float* ffn_b2  = (const float*)d_in[31];
    (void)in_sizes; (void)n_in; (void)out_size; (void)ws_size;

    float* out = (float*)d_out;
    char*  ws  = (char*)d_ws;
    const size_t MB = (size_t)1 << 20;

    // ---- region map (byte offsets in d_ws) ----
    u16*   xb      = (u16*)(ws + 0);          // [0,64M): x bf16 (dead after qkv)
    u16*   QKb     = (u16*)(ws + 64 * MB);    // [64,192M): (N,1024) q|k
    u16*   VTb     = (u16*)(ws + 192 * MB);   // [192,256M): V^T tiles
    u16*   attnb   = (u16*)(ws + 256 * MB);   // [256,320M)
    u16*   Oob     = (u16*)(ws + 0);          // [0,64M): o_out bf16 (over xb)
    u16*   Cb      = (u16*)(ws + 64 * MB);    // [64,256M): (N,1536) (over QK/VT)
    u16*   deltasB = (u16*)(ws + 256 * MB);   // [256,320M) (over attnb)
    u16*   statesb = (u16*)(ws + 320 * MB);   // [320,384M)
    u16*   ffn_inb = (u16*)(ws + 0);          // [0,64M) (over Oob)
    u16*   hb      = (u16*)(ws + 64 * MB);    // [64,320M): (N,2048) (over Cb+deltas)
    u16*   Fob     = (u16*)(ws + 320 * MB);   // [320,384M) (over statesb)
    u16*   WSq  = (u16*)(ws + 448 * MB);      // 1536x512  = 1.5M
    u16*   WSo  = (u16*)(ws + 450 * MB);      // 512x512   = 0.5M
    u16*   WSgd = (u16*)(ws + 451 * MB);      // 1024x1536 = 3M
    u16*   WSs  = (u16*)(ws + 455 * MB);      // 512x512
    u16*   WSf1 = (u16*)(ws + 456 * MB);      // 2048x512  = 2M
    u16*   WSf2 = (u16*)(ws + 458 * MB);      // 512x2048  = 2M
    float* qkvb = (float*)(ws + 460 * MB);    // 1536 f32
    float* gdb  = (float*)(ws + 461 * MB);    // 1024 f32

    float* X1     = out;
    float* tabc   = out + SLOT;
    float* tabs   = tabc + TT * 64;
    float* fstate = out + SLOT;

    const size_t NE = (size_t)NROWS * DD;

    // 0. tables, casts, weight prep (all independent)
    rope_table_kernel<<<(TT * 64 + 255) / 256, 256, 0, stream>>>(tabc, tabs);
    cast_f2b_kernel<<<(unsigned)((NE / 4 + 255) / 256), 256, 0, stream>>>(x, xb, NE / 4);
    bias_build_kernel<<<2, 256, 0, stream>>>(q_b, k_b, v_b, gate_b, delta_b, qkvb, gdb);
    auto wt = [&](const float* W, u16* WT, int K, int M, int rmul, int roff) {
        wtrans_kernel<<<dim3(M / 32, K / 32), dim3(32, 8), 0, stream>>>(W, WT, K, M, rmul, roff);
    };
    wt(q_w, WSq, DD, DD, 1, 0);
    wt(k_w, WSq + (size_t)512 * DD, DD, DD, 1, 0);
    wt(v_w, WSq + (size_t)1024 * DD, DD, DD, 1, 0);
    wt(o_w, WSo, DD, DD, 1, 0);
    wt(gate_w,  WSgd, 3 * DD, DD, 2, 0);
    wt(delta_w, WSgd, 3 * DD, DD, 2, 1);
    wt(seq_w, WSs, DD, DD, 1, 0);
    wt(ffn_w1, WSf1, DD, FFD, 1, 0);
    wt(ffn_w2, WSf2, FFD, DD, 1, 0);

    // 1. fused QKV GEMM (M=1536, 128^2 kernel): q|k -> QKb, v -> VTb tiles
    gemm_bf16<7><<<dim3(12, 512), 256, 0, stream>>>(
        xb, WSq, qkvb, QKb, 1024, nullptr, VTb, DD, 1536);

    // 2. fused MFMA attention (RoPE inline) -> attnb
    attn_mfma_kernel<<<dim3(HH, BB), 256, 0, stream>>>(QKb, VTb, attnb, tabc, tabs);

    // 3. o-proj -> Oob bf16 (256^2 8-phase)
    gemm256<4><<<dim3(2, 256), 512, 0, stream>>>(
        attnb, WSo, o_b, Oob, DD, nullptr, DD, DD);

    // 4. ln1_chain: x1 -> X1 f32 + Cb[:,0:512]; conv -> Cb[:,512:1024]; ema -> [:,1024:1536]
    ln1_chain_kernel<<<BB, 512, 0, stream>>>(x, Oob, ln1_g, ln1_b, local_w, local_b, X1, Cb);

    // 5. fused gate/delta GEMM (M=1024 interleaved) + act -> deltasB bf16
    gemm256<6><<<dim3(4, 256), 512, 0, stream>>>(
        Cb, WSgd, gdb, deltasB, DD, nullptr, 3 * DD, 1024);

    // 6. state_chain -> statesb bf16; LN4 -> fstate
    state_chain_kernel<<<BB, 512, 0, stream>>>(
        deltasB, seqst, dn_g, dn_b, ln3_g, ln3_b, ln4_g, ln4_b, statesb, fstate);

    // 7. ffn_in = x1 + 0.3*(states@seq_w + seq_b) -> ffn_inb bf16
    gemm256<2><<<dim3(2, 256), 512, 0, stream>>>(
        statesb, WSs, seq_b, ffn_inb, DD, X1, DD, DD);

    // 8. FFN: h = gelu(ffn_in@w1+b1) -> hb ; ffn_out = h@w2+b2 -> Fob bf16
    gemm256<3><<<dim3(8, 256), 512, 0, stream>>>(
        ffn_inb, WSf1, ffn_b1, hb, FFD, nullptr, DD, FFD);
    gemm256<4><<<dim3(2, 256), 512, 0, stream>>>(
        hb, WSf2, ffn_b2, Fob, DD, nullptr, FFD, DD);

    // 9. out = LN2(x1 + ffn_out) -> d_out (in place over X1)
    ln2_kernel<<<NROWS, 256, 0, stream>>>(X1, Fob, ln2_g, ln2_b, out);
}

// Round 7
// 1654.788 us; speedup vs baseline: 6.8052x; 1.0082x over previous
//
#include <hip/hip_runtime.h>
#include <cstddef>
#include <cstdint>

#define BB   512
#define TT   128
#define DD   512
#define HH   4
#define HDIM 128
#define FFD  2048
#define NROWS (BB * TT)                 // 65536 rows
#define SLOT ((size_t)NROWS * DD)       // 33554432 floats = 128 MiB

typedef unsigned short u16;
typedef __bf16 bf16x8 __attribute__((ext_vector_type(8)));
typedef float  f32x4  __attribute__((ext_vector_type(4)));

__device__ __forceinline__ u16 f2b(float x) {
    union { float f; unsigned u; } v; v.f = x;
    unsigned r = v.u + 0x7FFFu + ((v.u >> 16) & 1u);
    return (u16)(r >> 16);
}
__device__ __forceinline__ float b2f(u16 u) {
    union { unsigned u; float f; } v; v.u = (unsigned)u << 16; return v.f;
}
__device__ __forceinline__ float fast_gelu(float v) {
    float t = v * (0.7978845608028654f + 0.0356774081f * v * v);
    float e = __expf(2.f * t);
    float th = 1.f - 2.f / (e + 1.f);          // tanh(t)
    return 0.5f * v * (1.f + th);
}
__device__ __forceinline__ void glds16(const void* g, void* l) {
    __builtin_amdgcn_global_load_lds(
        (const __attribute__((address_space(1))) void*)g,
        (__attribute__((address_space(3))) void*)l, 16, 0, 0);
}

#define BAR() asm volatile("s_barrier" ::: "memory")
#define MM(ACC, AV, BV) \
    ACC = __builtin_amdgcn_mfma_f32_16x16x32_bf16(AV, BV, ACC, 0, 0, 0)

// ============ 256x256 quadrant-phase bf16 GEMM (T1+T2+T3+T4+T5) =============
// A: (N,K) bf16. BT: (M,K) bf16 (=B^T). bias f32 (M). 512 thr, 8 waves (2Mx4N),
// BK=64 (2 k-slabs of 32); LDS 128 KiB. st_16x32 swizzle, linear glds dest +
// inverse-swizzled global source. 4 phases/K-tile: (m0-3,n0-1),(m0-3,n2-3),
// (m4-7,n0-1),(m4-7,n2-3); B frags held across tile. Stages: A(kt+1,1)@ph1,
// B(kt+2,0)@ph3, B(kt+2,1)+A(kt+2,0)@ph4 (each after its slab's last reader
// is barrier-sealed). vmcnt(6) once per tile retires exactly tile kt+1.
// MODE 2: bf16 = addsrc + 0.3*C. MODE 3: bf16 gelu(C). MODE 4: bf16 C.
// MODE 6: gate/delta interleaved -> sigmoid*tanh -> bf16 at col c>>1.
template<int MODE>
__global__ __launch_bounds__(512, 2)
void gemm256(const u16* __restrict__ A, const u16* __restrict__ BT,
             const float* __restrict__ bias, void* __restrict__ Cout, int ldc,
             const float* __restrict__ addsrc, int K, int M)
{
    __shared__ u16 S[65536];   // 128 KiB
    const int tid = threadIdx.x;
    const int gx  = gridDim.x;               // M/256
    const int nwg = gx * gridDim.y;
    int orig = blockIdx.y * gx + blockIdx.x;
    orig = (orig & 7) * (nwg >> 3) + (orig >> 3);   // XCD swizzle (nwg%8==0)
    const int row0 = (orig / gx) * 256;
    const int col0 = (orig % gx) * 256;

    const int lane = tid & 63;
    const int wid  = tid >> 6;
    const int wm   = wid >> 2;       // row half (0/1)
    const int wn   = wid & 3;        // col quarter (0..3)
    const int fr   = lane & 15;
    const int kq   = lane >> 4;      // 0..3

    // staging: phys chunk c -> logical l = c ^ (((c>>5)&1)<<1)  (16B chunks)
    const int c0 = wid * 128 + lane;
    const int c1 = c0 + 64;
    const int l0 = c0 ^ (((c0 >> 5) & 1) << 1);
    const int l1 = c1 ^ (((c1 >> 5) & 1) << 1);
    const int sr0 = l0 >> 2, sk0 = (l0 & 3) * 8;
    const int sr1 = l1 >> 2, sk1 = (l1 & 3) * 8;
    const u16* ApG = A  + (size_t)row0 * K;
    const u16* BpG = BT + (size_t)col0 * K;

    auto stA = [&](int kt, int kh) {
        char* slot = (char*)S + ((((kt & 1) << 1) + kh) << 14);
        const u16* g = ApG + kt * 64 + kh * 32;
        glds16(g + (size_t)sr0 * K + sk0, slot + c0 * 16);
        glds16(g + (size_t)sr1 * K + sk1, slot + c1 * 16);
    };
    auto stB = [&](int kt, int kh) {
        char* slot = (char*)S + 65536 + ((((kt & 1) << 1) + kh) << 14);
        const u16* g = BpG + kt * 64 + kh * 32;
        glds16(g + (size_t)sr0 * K + sk0, slot + c0 * 16);
        glds16(g + (size_t)sr1 * K + sk1, slot + c1 * 16);
    };
    auto rdA = [&](int p, int kh, int m) -> bf16x8 {
        const int row = wm * 128 + m * 16 + fr;
        const int L = (row * 64 + kq * 16) ^ (((row >> 3) & 1) << 5);
        return *(const bf16x8*)((char*)S + (((p << 1) + kh) << 14) + L);
    };
    auto rdB = [&](int p, int kh, int n) -> bf16x8 {
        const int col = wn * 64 + n * 16 + fr;
        const int L = (col * 64 + kq * 16) ^ (((col >> 3) & 1) << 5);
        return *(const bf16x8*)((char*)S + 65536 + (((p << 1) + kh) << 14) + L);
    };

    f32x4 acc[8][4];
#pragma unroll
    for (int m = 0; m < 8; ++m)
#pragma unroll
        for (int n = 0; n < 4; ++n) acc[m][n] = (f32x4){0.f, 0.f, 0.f, 0.f};

    const int NKT = K >> 6;

    // prologue: tile0 (4 slabs) + B(1,0), B(1,1), A(1,0)
    stA(0, 0); stA(0, 1); stB(0, 0); stB(0, 1);
    stB(1, 0); stB(1, 1); stA(1, 0);
    asm volatile("s_waitcnt vmcnt(6)" ::: "memory");
    BAR();

    for (int kt = 0; kt < NKT; ++kt) {
        const int p = kt & 1;
        const bool s1 = (kt + 1 < NKT);
        const bool s2 = (kt + 2 < NKT);
        bf16x8 a0, a1, a2, a3, a4, a5, a6, a7;        // A frags [kh][m-quarter]
        bf16x8 b00, b01, b02, b03, b10, b11, b12, b13; // B frags [kh][n]

        // ---- ph1: (m0-3, n0-1); stage A(kt+1,1) -> slot p^1 (no conflict) --
        if (s1) stA(kt + 1, 1);
        a0 = rdA(p, 0, 0); a1 = rdA(p, 0, 1); a2 = rdA(p, 0, 2); a3 = rdA(p, 0, 3);
        a4 = rdA(p, 1, 0); a5 = rdA(p, 1, 1); a6 = rdA(p, 1, 2); a7 = rdA(p, 1, 3);
        b00 = rdB(p, 0, 0); b01 = rdB(p, 0, 1);
        b10 = rdB(p, 1, 0); b11 = rdB(p, 1, 1);
        BAR();
        __builtin_amdgcn_s_setprio(1);
        MM(acc[0][0], a0, b00); MM(acc[0][1], a0, b01);
        MM(acc[1][0], a1, b00); MM(acc[1][1], a1, b01);
        MM(acc[2][0], a2, b00); MM(acc[2][1], a2, b01);
        MM(acc[3][0], a3, b00); MM(acc[3][1], a3, b01);
        MM(acc[0][0], a4, b10); MM(acc[0][1], a4, b11);
        MM(acc[1][0], a5, b10); MM(acc[1][1], a5, b11);
        MM(acc[2][0], a6, b10); MM(acc[2][1], a6, b11);
        MM(acc[3][0], a7, b10); MM(acc[3][1], a7, b11);
        __builtin_amdgcn_s_setprio(0);
        BAR();

        // ---- ph2: (m0-3, n2-3); A held; read B n2-3 ----
        b02 = rdB(p, 0, 2); b03 = rdB(p, 0, 3);
        b12 = rdB(p, 1, 2); b13 = rdB(p, 1, 3);
        BAR();
        __builtin_amdgcn_s_setprio(1);
        MM(acc[0][2], a0, b02); MM(acc[0][3], a0, b03);
        MM(acc[1][2], a1, b02); MM(acc[1][3], a1, b03);
        MM(acc[2][2], a2, b02); MM(acc[2][3], a2, b03);
        MM(acc[3][2], a3, b02); MM(acc[3][3], a3, b03);
        MM(acc[0][2], a4, b12); MM(acc[0][3], a4, b13);
        MM(acc[1][2], a5, b12); MM(acc[1][3], a5, b13);
        MM(acc[2][2], a6, b12); MM(acc[2][3], a6, b13);
        MM(acc[3][2], a7, b12); MM(acc[3][3], a7, b13);
        __builtin_amdgcn_s_setprio(0);
        BAR();

        // ---- ph3: (m4-7, n0-1); stage B(kt+2,0) (B[p][k0] sealed @ph2) ----
        if (s2) stB(kt + 2, 0);
        a0 = rdA(p, 0, 4); a1 = rdA(p, 0, 5); a2 = rdA(p, 0, 6); a3 = rdA(p, 0, 7);
        a4 = rdA(p, 1, 4); a5 = rdA(p, 1, 5); a6 = rdA(p, 1, 6); a7 = rdA(p, 1, 7);
        BAR();
        __builtin_amdgcn_s_setprio(1);
        MM(acc[4][0], a0, b00); MM(acc[4][1], a0, b01);
        MM(acc[5][0], a1, b00); MM(acc[5][1], a1, b01);
        MM(acc[6][0], a2, b00); MM(acc[6][1], a2, b01);
        MM(acc[7][0], a3, b00); MM(acc[7][1], a3, b01);
        MM(acc[4][0], a4, b10); MM(acc[4][1], a4, b11);
        MM(acc[5][0], a5, b10); MM(acc[5][1], a5, b11);
        MM(acc[6][0], a6, b10); MM(acc[6][1], a6, b11);
        MM(acc[7][0], a7, b10); MM(acc[7][1], a7, b11);
        __builtin_amdgcn_s_setprio(0);
        BAR();

        // ---- ph4: (m4-7, n2-3); stage B(kt+2,1)+A(kt+2,0) (sealed @ph2/ph3)
        if (s2) { stB(kt + 2, 1); stA(kt + 2, 0); }
        __builtin_amdgcn_s_setprio(1);
        MM(acc[4][2], a0, b02); MM(acc[4][3], a0, b03);
        MM(acc[5][2], a1, b02); MM(acc[5][3], a1, b03);
        MM(acc[6][2], a2, b02); MM(acc[6][3], a2, b03);
        MM(acc[7][2], a3, b02); MM(acc[7][3], a3, b03);
        MM(acc[4][2], a4, b12); MM(acc[4][3], a4, b13);
        MM(acc[5][2], a5, b12); MM(acc[5][3], a5, b13);
        MM(acc[6][2], a6, b12); MM(acc[6][3], a6, b13);
        MM(acc[7][2], a7, b12); MM(acc[7][3], a7, b13);
        __builtin_amdgcn_s_setprio(0);
        if (s2)      asm volatile("s_waitcnt vmcnt(6)" ::: "memory");
        else if (s1) asm volatile("s_waitcnt vmcnt(0)" ::: "memory");
        if (s1) BAR();
    }

    // ---- epilogue ----
#pragma unroll
    for (int m = 0; m < 8; ++m) {
#pragma unroll
        for (int jj = 0; jj < 4; ++jj) {
            const int r = row0 + wm * 128 + m * 16 + kq * 4 + jj;
#pragma unroll
            for (int n = 0; n < 4; ++n) {
                const int c = col0 + wn * 64 + n * 16 + fr;
                float v = acc[m][n][jj] + bias[c];
                if constexpr (MODE == 2) {
                    ((u16*)Cout)[(size_t)r * ldc + c] =
                        f2b(addsrc[(size_t)r * M + c] + 0.3f * v);
                } else if constexpr (MODE == 3) {
                    ((u16*)Cout)[(size_t)r * ldc + c] = f2b(fast_gelu(v));
                } else if constexpr (MODE == 6) {
                    float pth = __shfl_xor(v, 1);
                    if ((fr & 1) == 0) {
                        float sg = 1.f / (1.f + __expf(-v));
                        float e  = __expf(2.f * pth);
                        float th = 1.f - 2.f / (e + 1.f);
                        ((u16*)Cout)[(size_t)r * ldc + (c >> 1)] = f2b(sg * th);
                    }
                } else {  // MODE 4
                    ((u16*)Cout)[(size_t)r * ldc + c] = f2b(v);
                }
            }
        }
    }
}

// ---------------- 128x128 bf16 GEMM (QKV only, MODE 7) ---------------------
template<int MODE>
__global__ __launch_bounds__(256)
void gemm_bf16(const u16* __restrict__ A, const u16* __restrict__ BT,
               const float* __restrict__ bias, void* __restrict__ Cout, int ldc,
               const float* __restrict__ addsrc, void* __restrict__ aux,
               int K, int M)
{
    __shared__ u16 smem[16384];
    const int tid = threadIdx.x;
    const int gx  = gridDim.x;
    const int nwg = gx * gridDim.y;
    int orig = blockIdx.y * gx + blockIdx.x;
    if ((nwg & 7) == 0) orig = (orig & 7) * (nwg >> 3) + (orig >> 3);
    const int row0 = (orig / gx) * 128;
    const int col0 = (orig % gx) * 128;

    const int lane = tid & 63;
    const int w    = tid >> 6;
    const int wr   = (w >> 1) * 64;
    const int wc   = (w & 1) * 64;
    const int fr   = lane & 15;
    const int kg   = (lane >> 4) * 8;

    f32x4 acc[4][4];
#pragma unroll
    for (int m = 0; m < 4; ++m)
#pragma unroll
        for (int n = 0; n < 4; ++n) acc[m][n] = (f32x4){0.f, 0.f, 0.f, 0.f};

    const int srow = tid >> 2;
    const int skb  = (tid & 3) * 8;
    const u16* Ag = A  + (size_t)(row0 + srow) * K + skb;
    const u16* Bg = BT + (size_t)(col0 + srow) * K + skb;
    const int soff = srow * 32 + skb;

    auto stage = [&](int kt, int buf) {
        const int ko = kt * 32;
        u16* as = smem + buf * 8192 + soff;
        u16* bs = smem + buf * 8192 + 4096 + soff;
        glds16(Ag + ko,                  as);
        glds16(Ag + (size_t)64 * K + ko, as + 2048);
        glds16(Bg + ko,                  bs);
        glds16(Bg + (size_t)64 * K + ko, bs + 2048);
    };

    const int nk = K >> 5;
    stage(0, 0);
    for (int k = 0; k < nk; ++k) {
        if (k + 1 < nk) {
            stage(k + 1, (k + 1) & 1);
            asm volatile("s_waitcnt vmcnt(4)" ::: "memory");
        } else {
            asm volatile("s_waitcnt vmcnt(0)" ::: "memory");
        }
        __syncthreads();
        const u16* As = smem + (k & 1) * 8192;
        const u16* Bs = As + 4096;
        bf16x8 af[4], bfr[4];
#pragma unroll
        for (int m = 0; m < 4; ++m)
            af[m] = *reinterpret_cast<const bf16x8*>(&As[(wr + m * 16 + fr) * 32 + kg]);
#pragma unroll
        for (int n = 0; n < 4; ++n)
            bfr[n] = *reinterpret_cast<const bf16x8*>(&Bs[(wc + n * 16 + fr) * 32 + kg]);
#pragma unroll
        for (int m = 0; m < 4; ++m)
#pragma unroll
            for (int n = 0; n < 4; ++n)
                acc[m][n] = __builtin_amdgcn_mfma_f32_16x16x32_bf16(af[m], bfr[n], acc[m][n], 0, 0, 0);
        __syncthreads();
    }

    if constexpr (MODE == 7) {
        if (col0 >= 1024) {
            // V^T swizzled tile: Ct[dc][t] rows of 256B, byte ^= ((dc&7)<<4)
#pragma unroll
            for (int m = 0; m < 4; ++m)
#pragma unroll
                for (int j = 0; j < 4; ++j) {
                    const int tl = wr + m * 16 + (lane >> 4) * 4 + j;
#pragma unroll
                    for (int n = 0; n < 4; ++n) {
                        const int dc = wc + n * 16 + fr;
                        float v = acc[m][n][j] + bias[col0 + dc];
                        *(u16*)((char*)smem + dc * 256 + ((tl * 2) ^ ((dc & 7) << 4))) = f2b(v);
                    }
                }
            __syncthreads();
            u16* dst = (u16*)aux + ((size_t)((row0 >> 7) * 4 + ((col0 - 1024) >> 7)) << 14);
#pragma unroll
            for (int i = 0; i < 8; ++i)
                *(uint4*)(dst + (size_t)(i * 256 + tid) * 8) =
                    *(const uint4*)((char*)smem + (size_t)(i * 256 + tid) * 16);
        } else {
#pragma unroll
            for (int m = 0; m < 4; ++m)
#pragma unroll
                for (int j = 0; j < 4; ++j) {
                    const int r = row0 + wr + m * 16 + (lane >> 4) * 4 + j;
#pragma unroll
                    for (int n = 0; n < 4; ++n) {
                        const int c = col0 + wc + n * 16 + fr;
                        ((u16*)Cout)[(size_t)r * 1024 + c] = f2b(acc[m][n][j] + bias[c]);
                    }
                }
        }
    }
    (void)ldc; (void)addsrc;
}

// ------- weight transpose+cast: W (K,M) f32 -> WT rows (m*rmul+roff) -------
__global__ __launch_bounds__(256)
void wtrans_kernel(const float* __restrict__ W, u16* __restrict__ WT, int K, int M,
                   int rmul, int roff)
{
    __shared__ float t[32][33];
    const int m0 = blockIdx.x * 32;
    const int k0 = blockIdx.y * 32;
    const int tx = threadIdx.x;
    const int ty = threadIdx.y;
#pragma unroll
    for (int i = 0; i < 4; ++i) {
        int k = ty * 4 + i;
        t[k][tx] = W[(size_t)(k0 + k) * M + m0 + tx];
    }
    __syncthreads();
#pragma unroll
    for (int i = 0; i < 4; ++i) {
        int m = ty * 4 + i;
        WT[(size_t)((m0 + m) * rmul + roff) * K + k0 + tx] = f2b(t[tx][m]);
    }
}

__global__ void cast_f2b_kernel(const float* __restrict__ in, u16* __restrict__ out, size_t n4)
{
    size_t i = (size_t)blockIdx.x * blockDim.x + threadIdx.x;
    if (i >= n4) return;
    float4 v = reinterpret_cast<const float4*>(in)[i];
    union { u16 u[4]; uint2 d; } p;
    p.u[0] = f2b(v.x); p.u[1] = f2b(v.y); p.u[2] = f2b(v.z); p.u[3] = f2b(v.w);
    reinterpret_cast<uint2*>(out)[i] = p.d;
}

__global__ void rope_table_kernel(float* __restrict__ tabc, float* __restrict__ tabs)
{
    int idx = blockIdx.x * blockDim.x + threadIdx.x;
    if (idx >= TT * 64) return;
    int t = idx >> 6, j = idx & 63;
    float invf = expf(-(float)j * (9.210340371976184f / 64.f));
    float ang  = (float)t * invf;
    tabc[idx] = cosf(ang);
    tabs[idx] = sinf(ang);
}

__global__ void bias_build_kernel(const float* qb, const float* kb, const float* vb,
                                  const float* gb, const float* db,
                                  float* qkvb, float* gdb)
{
    int i = blockIdx.x * blockDim.x + threadIdx.x;
    if (i >= 512) return;
    qkvb[i] = qb[i]; qkvb[512 + i] = kb[i]; qkvb[1024 + i] = vb[i];
    gdb[2 * i] = gb[i]; gdb[2 * i + 1] = db[i];
}

// ---------------- MFMA attention: one block per (b,h), RoPE inline ---------
__global__ __launch_bounds__(256)
void attn_mfma_kernel(const u16* __restrict__ QKg, const u16* __restrict__ VTg,
                      u16* __restrict__ Og,
                      const float* __restrict__ tabc, const float* __restrict__ tabs)
{
    __shared__ u16 SA[128 * 128];   // Q -> P
    __shared__ u16 SB[128 * 128];   // K -> V^T
    const int h = blockIdx.x, b = blockIdx.y;
    const int tid  = threadIdx.x;
    const int lane = tid & 63;
    const int w    = tid >> 6;
    const int fr   = lane & 15;
    const int kq   = lane >> 4;
    const size_t baseq = ((size_t)(b * TT)) * 1024 + (size_t)h * HDIM;
    const size_t baseo = ((size_t)(b * TT)) * DD + (size_t)h * HDIM;

    {
        const int tg = tid >> 4;
        const int dg = tid & 15;
        const int j0 = (dg & 7) * 8;
        const bool hi = (dg & 8) != 0;
        for (int r = 0; r < 8; ++r) {
            const int t = r * 16 + tg;
            uint4 qv = *(const uint4*)(QKg + baseq + (size_t)t * 1024 + dg * 8);
            uint4 kv = *(const uint4*)(QKg + baseq + 512 + (size_t)t * 1024 + dg * 8);
            unsigned qa[4] = {qv.x, qv.y, qv.z, qv.w};
            unsigned ka[4] = {kv.x, kv.y, kv.z, kv.w};
            unsigned qb[4], kb[4];
#pragma unroll
            for (int i = 0; i < 4; ++i) {
                qb[i] = __shfl_xor((int)qa[i], 8);
                kb[i] = __shfl_xor((int)ka[i], 8);
            }
            const float* cp = tabc + t * 64 + j0;
            const float* sp = tabs + t * 64 + j0;
            u16 oq[8], ok[8];
#pragma unroll
            for (int e = 0; e < 8; ++e) {
                float fq = b2f((u16)(qa[e >> 1] >> ((e & 1) * 16)));
                float gq = b2f((u16)(qb[e >> 1] >> ((e & 1) * 16)));
                float fk = b2f((u16)(ka[e >> 1] >> ((e & 1) * 16)));
                float gk = b2f((u16)(kb[e >> 1] >> ((e & 1) * 16)));
                float c = cp[e], s = sp[e];
                oq[e] = f2b(hi ? fq * c + gq * s : fq * c - gq * s);
                ok[e] = f2b(hi ? fk * c + gk * s : fk * c - gk * s);
            }
            const int cb = (dg * 16) ^ ((t & 7) << 4);
            *(uint4*)((char*)SA + t * 256 + cb) = *(const uint4*)oq;
            *(uint4*)((char*)SB + t * 256 + cb) = *(const uint4*)ok;
        }
    }
    __syncthreads();

    f32x4 acc[2][8];
#pragma unroll
    for (int m = 0; m < 2; ++m)
#pragma unroll
        for (int n = 0; n < 8; ++n) acc[m][n] = (f32x4){0.f, 0.f, 0.f, 0.f};

    for (int k0 = 0; k0 < 128; k0 += 32) {
        const int cb = (k0 + kq * 8) * 2;
        bf16x8 af[2];
#pragma unroll
        for (int m = 0; m < 2; ++m) {
            const int row = w * 32 + m * 16 + fr;
            af[m] = *(const bf16x8*)((char*)SA + row * 256 + (cb ^ ((row & 7) << 4)));
        }
#pragma unroll
        for (int n = 0; n < 8; ++n) {
            const int row = n * 16 + fr;
            bf16x8 bf = *(const bf16x8*)((char*)SB + row * 256 + (cb ^ ((row & 7) << 4)));
            acc[0][n] = __builtin_amdgcn_mfma_f32_16x16x32_bf16(af[0], bf, acc[0][n], 0, 0, 0);
            acc[1][n] = __builtin_amdgcn_mfma_f32_16x16x32_bf16(af[1], bf, acc[1][n], 0, 0, 0);
        }
    }
    __syncthreads();

    {
        const u16* vsrc = VTg + ((size_t)(b * HH + h) << 14);
#pragma unroll
        for (int i = 0; i < 8; ++i)
            glds16(vsrc + (size_t)(i * 256 + tid) * 8,
                   SB + (size_t)(i * 256 + tid) * 8);
    }

    const float SC = 0.08838834764831845f;
#pragma unroll
    for (int m = 0; m < 2; ++m) {
#pragma unroll
        for (int j = 0; j < 4; ++j) {
            const int t = w * 32 + m * 16 + kq * 4 + j;
            float mx = -3.0e38f;
#pragma unroll
            for (int n = 0; n < 8; ++n) {
                const int s = n * 16 + fr;
                float v = acc[m][n][j];
                v = (s <= t) ? v * SC : -3.0e38f;
                acc[m][n][j] = v;
                mx = fmaxf(mx, v);
            }
            mx = fmaxf(mx, __shfl_xor(mx, 1));
            mx = fmaxf(mx, __shfl_xor(mx, 2));
            mx = fmaxf(mx, __shfl_xor(mx, 4));
            mx = fmaxf(mx, __shfl_xor(mx, 8));
            float sum = 0.f;
#pragma unroll
            for (int n = 0; n < 8; ++n) {
                float e = __expf(acc[m][n][j] - mx);
                acc[m][n][j] = e; sum += e;
            }
            sum += __shfl_xor(sum, 1); sum += __shfl_xor(sum, 2);
            sum += __shfl_xor(sum, 4); sum += __shfl_xor(sum, 8);
            const float inv = 1.f / sum;
#pragma unroll
            for (int n = 0; n < 8; ++n) {
                const int s = n * 16 + fr;
                *(u16*)((char*)SA + t * 256 + ((s * 2) ^ ((t & 7) << 4))) =
                    f2b(acc[m][n][j] * inv);
            }
        }
    }
    __syncthreads();

    f32x4 oa[2][8];
#pragma unroll
    for (int m = 0; m < 2; ++m)
#pragma unroll
        for (int n = 0; n < 8; ++n) oa[m][n] = (f32x4){0.f, 0.f, 0.f, 0.f};

    for (int k0 = 0; k0 < 128; k0 += 32) {
        const int cb = (k0 + kq * 8) * 2;
        bf16x8 pa[2];
#pragma unroll
        for (int m = 0; m < 2; ++m) {
            const int row = w * 32 + m * 16 + fr;
            pa[m] = *(const bf16x8*)((char*)SA + row * 256 + (cb ^ ((row & 7) << 4)));
        }
#pragma unroll
        for (int n = 0; n < 8; ++n) {
            const int row = n * 16 + fr;
            bf16x8 vb = *(const bf16x8*)((char*)SB + row * 256 + (cb ^ ((row & 7) << 4)));
            oa[0][n] = __builtin_amdgcn_mfma_f32_16x16x32_bf16(pa[0], vb, oa[0][n], 0, 0, 0);
            oa[1][n] = __builtin_amdgcn_mfma_f32_16x16x32_bf16(pa[1], vb, oa[1][n], 0, 0, 0);
        }
    }

#pragma unroll
    for (int m = 0; m < 2; ++m)
#pragma unroll
        for (int j = 0; j < 4; ++j) {
            const int t = w * 32 + m * 16 + kq * 4 + j;
            u16* orow = Og + baseo + (size_t)t * DD;
#pragma unroll
            for (int n = 0; n < 8; ++n)
                orow[n * 16 + fr] = f2b(oa[m][n][j]);
        }
}

// ---------------- block reduce over 512 threads (sum, sumsq) ---------------
__device__ __forceinline__ float2 blk_red512(float v, float (*red)[2], int tid)
{
    float s = v, ss = v * v;
#pragma unroll
    for (int off = 1; off < 64; off <<= 1) {
        s  += __shfl_xor(s, off);
        ss += __shfl_xor(ss, off);
    }
    if ((tid & 63) == 0) { red[tid >> 6][0] = s; red[tid >> 6][1] = ss; }
    __syncthreads();
    float S = 0.f, SS = 0.f;
#pragma unroll
    for (int w = 0; w < 8; ++w) { S += red[w][0]; SS += red[w][1]; }
    return make_float2(S, SS);
}

// ------- ln1_chain: per-batch serial LN1 + local conv + EMA ----------------
__global__ __launch_bounds__(512)
void ln1_chain_kernel(const float* __restrict__ x, const u16* __restrict__ oo,
                      const float* __restrict__ g, const float* __restrict__ bb,
                      const float* __restrict__ lw, const float* __restrict__ lb,
                      float* __restrict__ X1, u16* __restrict__ Cb)
{
    __shared__ float red[2][8][2];
    const int b = blockIdx.x, d = threadIdx.x;
    const float g_ = g[d], b_ = bb[d];
    const float w0 = lw[d * 4 + 0], w1 = lw[d * 4 + 1],
                w2 = lw[d * 4 + 2], w3 = lw[d * 4 + 3];
    const float lb_ = lb[d];
    const size_t rb = (size_t)b * TT;
    float h1 = 0.f, h2 = 0.f, h3 = 0.f, ema = 0.f;
    float v = x[(rb + 0) * DD + d] + b2f(oo[(rb + 0) * DD + d]);
    for (int t = 0; t < TT; ++t) {
        const int tn = (t < TT - 1) ? t + 1 : t;
        float vn = x[(rb + tn) * DD + d] + b2f(oo[(rb + tn) * DD + d]);
        float2 r = blk_red512(v, red[t & 1], d);
        float mu  = r.x * (1.f / DD);
        float var = r.y * (1.f / DD) - mu * mu;
        float x1v = (v - mu) * rsqrtf(var + 1e-5f) * g_ + b_;
        const size_t row = rb + t;
        X1[row * DD + d] = x1v;
        u16* crow = Cb + row * 1536;
        crow[d] = f2b(x1v);
        crow[512 + d]  = f2b(lb_ + w3 * x1v + w2 * h1 + w1 * h2 + w0 * h3);
        ema = 0.9f * ema + 0.1f * x1v;
        crow[1024 + d] = f2b(ema);
        h3 = h2; h2 = h1; h1 = x1v;
        v = vn;
    }
}

// ------- state_chain: per-batch serial LN(dn)+cumsum+LN3 (+LN4 at t=127) ---
__global__ __launch_bounds__(512)
void state_chain_kernel(const u16* __restrict__ deltasB, const float* __restrict__ seqst,
                        const float* __restrict__ dng, const float* __restrict__ dnb,
                        const float* __restrict__ g3, const float* __restrict__ b3,
                        const float* __restrict__ g4, const float* __restrict__ b4,
                        u16* __restrict__ statesb, float* __restrict__ fstate)
{
    __shared__ float red[2][8][2];
    const int b = blockIdx.x, d = threadIdx.x;
    const float gd_ = dng[d], bd_ = dnb[d], g3_ = g3[d], b3_ = b3[d];
    const float seq = seqst[(size_t)b * DD + d];
    const size_t rb = (size_t)b * TT;
    float cum = 0.f;
    float v = b2f(deltasB[(rb + 0) * DD + d]);
    for (int t = 0; t < TT; ++t) {
        const int tn = (t < TT - 1) ? t + 1 : t;
        float vn = b2f(deltasB[(rb + tn) * DD + d]);
        float2 r0 = blk_red512(v, red[0], d);
        float mu  = r0.x * (1.f / DD);
        float var = r0.y * (1.f / DD) - mu * mu;
        float nd  = (v - mu) * rsqrtf(var + 1e-5f) * gd_ + bd_;
        cum += nd;
        float sv = seq + cum * 0.25f;
        float2 r1 = blk_red512(sv, red[1], d);
        mu  = r1.x * (1.f / DD);
        var = r1.y * (1.f / DD) - mu * mu;
        float o = (sv - mu) * rsqrtf(var + 1e-5f) * g3_ + b3_;
        statesb[(rb + t) * DD + d] = f2b(o);
        if (t == TT - 1) {
            float2 r2 = blk_red512(o, red[0], d);
            float mu4  = r2.x * (1.f / DD);
            float var4 = r2.y * (1.f / DD) - mu4 * mu4;
            fstate[(size_t)b * DD + d] = (o - mu4) * rsqrtf(var4 + 1e-5f) * g4[d] + b4[d];
        }
        v = vn;
    }
}

// ---------------- final LN2 (row per block; bf16 row-add) ------------------
__global__ __launch_bounds__(256)
void ln2_kernel(const float* __restrict__ a, const u16* __restrict__ badd,
                const float* __restrict__ g, const float* __restrict__ bb,
                float* __restrict__ out)
{
    const int row = blockIdx.x;
    const int tid = threadIdx.x;
    const float* ap = a + (size_t)row * DD;
    const u16*   bp = badd + (size_t)row * DD;
    float v0 = ap[tid]       + b2f(bp[tid]);
    float v1 = ap[tid + 256] + b2f(bp[tid + 256]);
    float s  = v0 + v1;
    float ss = v0 * v0 + v1 * v1;
#pragma unroll
    for (int off = 1; off < 64; off <<= 1) {
        s  += __shfl_xor(s, off);
        ss += __shfl_xor(ss, off);
    }
    __shared__ float sm1[4], sm2[4];
    const int wid = tid >> 6;
    if ((tid & 63) == 0) { sm1[wid] = s; sm2[wid] = ss; }
    __syncthreads();
    s  = sm1[0] + sm1[1] + sm1[2] + sm1[3];
    ss = sm2[0] + sm2[1] + sm2[2] + sm2[3];
    const float mu  = s * (1.f / DD);
    const float var = ss * (1.f / DD) - mu * mu;
    const float r   = rsqrtf(var + 1e-5f);
    float* op = out + (size_t)row * DD;
    op[tid]       = (v0 - mu) * r * g[tid]       + bb[tid];
    op[tid + 256] = (v1 - mu) * r * g[tid + 256] + bb[tid + 256];
}

// ---------------------------------------------------------------------------
extern "C" void kernel_launch(void* const* d_in, const int* in_sizes, int n_in,
                              void* d_out, int out_size, void* d_ws, size_t ws_size,
                              hipStream_t stream)
{
    const float* x       = (const float*)d_in[0];
    const float* seqst   = (const float*)d_in[1];
    const float* q_w     = (const float*)d_in[2];
    const float* q_b     = (const float*)d_in[3];
    const float* k_w     = (const float*)d_in[4];
    const float* k_b     = (const float*)d_in[5];
    const float* v_w     = (const float*)d_in[6];
    const float* v_b     = (const float*)d_in[7];
    const float* o_w     = (const float*)d_in[8];
    const float* o_b     = (const float*)d_in[9];
    const float* local_w = (const float*)d_in[10];
    const float* local_b = (const float*)d_in[11];
    const float* delta_w = (const float*)d_in[12];
    const float* delta_b = (const float*)d_in[13];
    const float* gate_w  = (const float*)d_in[14];
    const float* gate_b  = (const float*)d_in[15];
    const float* dn_g    = (const float*)d_in[16];
    const float* dn_b    = (const float*)d_in[17];
    const float* ln1_g   = (const float*)d_in[18];
    const float* ln1_b   = (const float*)d_in[19];
    const float* ln2_g   = (const float*)d_in[20];
    const float* ln2_b   = (const float*)d_in[21];
    const float* ln3_g   = (const float*)d_in[22];
    const float* ln3_b   = (const float*)d_in[23];
    const float* ln4_g   = (const float*)d_in[24];
    const float* ln4_b   = (const float*)d_in[25];
    const float* seq_w   = (const float*)d_in[26];
    const float* seq_b   = (const float*)d_in[27];
    const float* ffn_w1  = (const float*)d_in[28];
    const float* ffn_b1  = (const float*)d_in[29];
    const float* ffn_w2  = (const float*)d_in[30];
    const float* ffn_b2  = (const float*)d_in[31];
    (void)in_sizes; (void)n_in; (void)out_size; (void)ws_size;

    float* out = (float*)d_out;
    char*  ws  = (char*)d_ws;
    const size_t MB = (size_t)1 << 20;

    // ---- region map (byte offsets in d_ws) ----
    u16*   xb      = (u16*)(ws + 0);          // [0,64M): x bf16 (dead after qkv)
    u16*   QKb     = (u16*)(ws + 64 * MB);    // [64,192M): (N,1024) q|k
    u16*   VTb     = (u16*)(ws + 192 * MB);   // [192,256M): V^T tiles
    u16*   attnb   = (u16*)(ws + 256 * MB);   // [256,320M)
    u16*   Oob     = (u16*)(ws + 0);          // [0,64M): o_out bf16 (over xb)
    u16*   Cb      = (u16*)(ws + 64 * MB);    // [64,256M): (N,1536) (over QK/VT)
    u16*   deltasB = (u16*)(ws + 256 * MB);   // [256,320M) (over attnb)
    u16*   statesb = (u16*)(ws + 320 * MB);   // [320,384M)
    u16*   ffn_inb = (u16*)(ws + 0);          // [0,64M) (over Oob)
    u16*   hb      = (u16*)(ws + 64 * MB);    // [64,320M): (N,2048) (over Cb+deltas)
    u16*   Fob     = (u16*)(ws + 320 * MB);   // [320,384M) (over statesb)
    u16*   WSq  = (u16*)(ws + 448 * MB);      // 1536x512  = 1.5M
    u16*   WSo  = (u16*)(ws + 450 * MB);      // 512x512   = 0.5M
    u16*   WSgd = (u16*)(ws + 451 * MB);      // 1024x1536 = 3M
    u16*   WSs  = (u16*)(ws + 455 * MB);      // 512x512
    u16*   WSf1 = (u16*)(ws + 456 * MB);      // 2048x512  = 2M
    u16*   WSf2 = (u16*)(ws + 458 * MB);      // 512x2048  = 2M
    float* qkvb = (float*)(ws + 460 * MB);    // 1536 f32
    float* gdb  = (float*)(ws + 461 * MB);    // 1024 f32

    float* X1     = out;
    float* tabc   = out + SLOT;
    float* tabs   = tabc + TT * 64;
    float* fstate = out + SLOT;

    const size_t NE = (size_t)NROWS * DD;

    // 0. tables, casts, weight prep (all independent)
    rope_table_kernel<<<(TT * 64 + 255) / 256, 256, 0, stream>>>(tabc, tabs);
    cast_f2b_kernel<<<(unsigned)((NE / 4 + 255) / 256), 256, 0, stream>>>(x, xb, NE / 4);
    bias_build_kernel<<<2, 256, 0, stream>>>(q_b, k_b, v_b, gate_b, delta_b, qkvb, gdb);
    auto wt = [&](const float* W, u16* WT, int K, int M, int rmul, int roff) {
        wtrans_kernel<<<dim3(M / 32, K / 32), dim3(32, 8), 0, stream>>>(W, WT, K, M, rmul, roff);
    };
    wt(q_w, WSq, DD, DD, 1, 0);
    wt(k_w, WSq + (size_t)512 * DD, DD, DD, 1, 0);
    wt(v_w, WSq + (size_t)1024 * DD, DD, DD, 1, 0);
    wt(o_w, WSo, DD, DD, 1, 0);
    wt(gate_w,  WSgd, 3 * DD, DD, 2, 0);
    wt(delta_w, WSgd, 3 * DD, DD, 2, 1);
    wt(seq_w, WSs, DD, DD, 1, 0);
    wt(ffn_w1, WSf1, DD, FFD, 1, 0);
    wt(ffn_w2, WSf2, FFD, DD, 1, 0);

    // 1. fused QKV GEMM (M=1536, 128^2 kernel): q|k -> QKb, v -> VTb tiles
    gemm_bf16<7><<<dim3(12, 512), 256, 0, stream>>>(
        xb, WSq, qkvb, QKb, 1024, nullptr, VTb, DD, 1536);

    // 2. fused MFMA attention (RoPE inline) -> attnb
    attn_mfma_kernel<<<dim3(HH, BB), 256, 0, stream>>>(QKb, VTb, attnb, tabc, tabs);

    // 3. o-proj -> Oob bf16 (256^2 quadrant-phase)
    gemm256<4><<<dim3(2, 256), 512, 0, stream>>>(
        attnb, WSo, o_b, Oob, DD, nullptr, DD, DD);

    // 4. ln1_chain: x1 -> X1 f32 + Cb[:,0:512]; conv -> Cb[:,512:1024]; ema -> [:,1024:1536]
    ln1_chain_kernel<<<BB, 512, 0, stream>>>(x, Oob, ln1_g, ln1_b, local_w, local_b, X1, Cb);

    // 5. fused gate/delta GEMM (M=1024 interleaved) + act -> deltasB bf16
    gemm256<6><<<dim3(4, 256), 512, 0, stream>>>(
        Cb, WSgd, gdb, deltasB, DD, nullptr, 3 * DD, 1024);

    // 6. state_chain -> statesb bf16; LN4 -> fstate
    state_chain_kernel<<<BB, 512, 0, stream>>>(
        deltasB, seqst, dn_g, dn_b, ln3_g, ln3_b, ln4_g, ln4_b, statesb, fstate);

    // 7. ffn_in = x1 + 0.3*(states@seq_w + seq_b) -> ffn_inb bf16
    gemm256<2><<<dim3(2, 256), 512, 0, stream>>>(
        statesb, WSs, seq_b, ffn_inb, DD, X1, DD, DD);

    // 8. FFN: h = gelu(ffn_in@w1+b1) -> hb ; ffn_out = h@w2+b2 -> Fob bf16
    gemm256<3><<<dim3(8, 256), 512, 0, stream>>>(
        ffn_inb, WSf1, ffn_b1, hb, FFD, nullptr, DD, FFD);
    gemm256<4><<<dim3(2, 256), 512, 0, stream>>>(
        hb, WSf2, ffn_b2, Fob, DD, nullptr, FFD, DD);

    // 9. out = LN2(x1 + ffn_out) -> d_out (in place over X1)
    ln2_kernel<<<NROWS, 256, 0, stream>>>(X1, Fob, ln2_g, ln2_b, out);
}